// Round 12
// baseline (143.198 us; speedup 1.0000x reference)
//
#include <hip/hip_runtime.h>
#include <hip/hip_bf16.h>
#include <math.h>

#define DM    1024
#define DH    64
#define NCTX  4096
#define NCH   8        // key-chunks per q-group
#define NUNIT 2048     // 256 groups x 8 chunks

typedef __attribute__((ext_vector_type(8))) short bf16x8;
typedef __attribute__((ext_vector_type(4))) float f32x4;

// ---- ws (proven 4,456,448 B): f32 Q, K, UT, Y + counter in dead WK slot
#define WS_Q   0
#define WS_K   (NCTX*DH)
#define WS_U   (2*NCTX*DH)
#define WS_Y   (3*NCTX*DH)
#define WS_CNT_BYTE 4194304   // old WK slot (bytes 4194304..4456448 free)

// ---- d_out scratch (16 MiB, fully overwritten by out_kernel last)
#define D_QH   0
#define D_QM   524288
#define D_QL   1048576
#define D_KH   1572864
#define D_KM   2097152
#define D_KL   2621440
#define D_UTB  3145728
#define D_PY   3670016
#define D_PM   12058624
#define D_PL   12189696
#define D_WTH  12320768
#define D_WTM  12713984

__device__ __forceinline__ ushort f2bf(float x) {
  __hip_bfloat16 h = __float2bfloat16(x);
  return __builtin_bit_cast(ushort, h);
}
__device__ __forceinline__ float bf2f(ushort u) {
  __hip_bfloat16 h = __builtin_bit_cast(__hip_bfloat16, u);
  return __bfloat162float(h);
}

// ---------------- W -> WT digit split (validated, unchanged) ----------------
__global__ __launch_bounds__(256) void wsplit_kernel(
    const float* __restrict__ Wq, const float* __restrict__ WkT,
    const float* __restrict__ Wo,
    ushort* __restrict__ WTh, ushort* __restrict__ WTm)
{
  int gid = blockIdx.x * 256 + threadIdx.x;
  int mat = gid >> 16;
  int idx = gid & 65535;
  float v; int oidx;
  if (mat == 1) {
    v = WkT[idx];
    oidx = 65536 + idx;
  } else {
    int k = idx >> 6, h = idx & 63;
    v = (mat == 0 ? Wq : Wo)[idx];
    oidx = mat * 65536 + h * 1024 + k;
  }
  ushort h16 = f2bf(v);
  float rem = v - bf2f(h16);
  WTh[oidx] = h16;
  WTm[oidx] = f2bf(rem);
}

// ---------------- projections via MFMA (validated; +VGPR headroom, x prefetch) ----------------
__global__ __launch_bounds__(64, 1) void proj_mfma_kernel(
    const float* __restrict__ x,
    const ushort* __restrict__ WTh, const ushort* __restrict__ WTm,
    float* __restrict__ Q, float* __restrict__ Kc, float* __restrict__ UT)
{
  const int lane = threadIdx.x;
  const int q16  = lane & 15;
  const int grp  = lane >> 4;
  const int colb = grp * 8;
  const int r0   = blockIdx.x * 16;
  const int mat  = blockIdx.y;
  const ushort* __restrict__ wh = WTh + mat * 65536;
  const ushort* __restrict__ wm = WTm + mat * 65536;

  f32x4 acc[4] = {{0,0,0,0},{0,0,0,0},{0,0,0,0},{0,0,0,0}};

  const int xrow = (r0 + q16) * DM + colb;
  float4 a0 = *(const float4*)&x[xrow];
  float4 a1 = *(const float4*)&x[xrow + 4];

  for (int ks = 0; ks < 32; ++ks) {
    float4 n0, n1;
    if (ks < 31) {      // prefetch next x slice (hide HBM/L2 latency)
      n0 = *(const float4*)&x[xrow + 32*(ks+1)];
      n1 = *(const float4*)&x[xrow + 32*(ks+1) + 4];
    }
    float xv[8] = {a0.x, a0.y, a0.z, a0.w, a1.x, a1.y, a1.z, a1.w};
    bf16x8 xh8, xm8;
    #pragma unroll
    for (int e = 0; e < 8; ++e) {
      ushort h = f2bf(xv[e]);
      float rem = xv[e] - bf2f(h);
      xh8[e] = (short)h;
      xm8[e] = (short)f2bf(rem);
    }
    if (mat == 2) {
      #pragma unroll
      for (int ct = 0; ct < 4; ++ct) {
        const int wb = (16 * ct + q16) * DM + 32 * ks + colb;
        bf16x8 bh = *(const bf16x8*)&wh[wb];
        bf16x8 bm = *(const bf16x8*)&wm[wb];
        acc[ct] = __builtin_amdgcn_mfma_f32_16x16x32_bf16(bh, xh8, acc[ct], 0,0,0);
        acc[ct] = __builtin_amdgcn_mfma_f32_16x16x32_bf16(bh, xm8, acc[ct], 0,0,0);
        acc[ct] = __builtin_amdgcn_mfma_f32_16x16x32_bf16(bm, xh8, acc[ct], 0,0,0);
        acc[ct] = __builtin_amdgcn_mfma_f32_16x16x32_bf16(bm, xm8, acc[ct], 0,0,0);
      }
    } else {
      #pragma unroll
      for (int ct = 0; ct < 4; ++ct) {
        const int wb = (16 * ct + q16) * DM + 32 * ks + colb;
        bf16x8 bh = *(const bf16x8*)&wh[wb];
        bf16x8 bm = *(const bf16x8*)&wm[wb];
        acc[ct] = __builtin_amdgcn_mfma_f32_16x16x32_bf16(xh8, bh, acc[ct], 0,0,0);
        acc[ct] = __builtin_amdgcn_mfma_f32_16x16x32_bf16(xh8, bm, acc[ct], 0,0,0);
        acc[ct] = __builtin_amdgcn_mfma_f32_16x16x32_bf16(xm8, bh, acc[ct], 0,0,0);
        acc[ct] = __builtin_amdgcn_mfma_f32_16x16x32_bf16(xm8, bm, acc[ct], 0,0,0);
      }
    }
    a0 = n0; a1 = n1;
  }

  if (mat == 2) {
    #pragma unroll
    for (int ct = 0; ct < 4; ++ct)
      #pragma unroll
      for (int r = 0; r < 4; ++r)
        UT[(16*ct + 4*grp + r) * NCTX + r0 + q16] = acc[ct][r];
  } else {
    float* __restrict__ Out = (mat == 0) ? Q : Kc;
    #pragma unroll
    for (int ct = 0; ct < 4; ++ct)
      #pragma unroll
      for (int r = 0; r < 4; ++r)
        Out[(r0 + 4*grp + r) * DH + 16*ct + q16] = acc[ct][r];
  }
}

// ---------------- 3-way bf16 digit split (validated, unchanged) ----------------
__global__ __launch_bounds__(256) void split_kernel(
    const float* __restrict__ Q, const float* __restrict__ K, const float* __restrict__ UT,
    ushort* __restrict__ Qh, ushort* __restrict__ Qm, ushort* __restrict__ Ql,
    ushort* __restrict__ Kh, ushort* __restrict__ Km, ushort* __restrict__ Kl,
    ushort* __restrict__ UTb)
{
  int i = blockIdx.x * 256 + threadIdx.x;
  float q = Q[i];
  ushort h = f2bf(q); float fh = bf2f(h);
  ushort m = f2bf(q - fh); float fm = bf2f(m);
  ushort l = f2bf(q - fh - fm);
  Qh[i] = h; Qm[i] = m; Ql[i] = l;
  float k = K[i];
  h = f2bf(k); fh = bf2f(h);
  m = f2bf(k - fh); fm = bf2f(m);
  l = f2bf(k - fh - fm);
  Kh[i] = h; Km[i] = m; Kl[i] = l;
  UTb[i] = f2bf(UT[i]);
}

// ---------------- MFMA flash attention: validated body + work-stealing ----------------
// 384 blocks x 4 waves = 1536 waves pop units 0..2047 heavy-first (LPT).
// Output of each unit is wave-independent -> deterministic regardless of
// which wave processes it. All per-unit state declared inside the loop.
__global__ __launch_bounds__(256, 1) void attn_kernel(
    const ushort* __restrict__ Qh, const ushort* __restrict__ Qm, const ushort* __restrict__ Ql,
    const ushort* __restrict__ Kh, const ushort* __restrict__ Km, const ushort* __restrict__ Kl,
    const ushort* __restrict__ UTb, int* __restrict__ cnt,
    float* __restrict__ Pm, float* __restrict__ Pl, float* __restrict__ Py)
{
  __shared__ __align__(16) ushort ps[4][16*72];
  const int tid  = threadIdx.x;
  const int lane = tid & 63;
  const int w    = tid >> 6;
  ushort* psw = ps[w];
  const int q16  = lane & 15;
  const int grp  = lane >> 4;
  const int colb = grp * 8;

  while (true) {
    int n0;
    if (lane == 0) n0 = atomicAdd(cnt, 1);
    n0 = __shfl(n0, 0, 64);
    if (n0 >= NUNIT) break;

    const int g  = 255 - (n0 >> 3);          // heavy groups first (LPT)
    const int c  = n0 & 7;
    const int Tg = ((16*g + 15) >> 6) + 1;
    const int t0 = (c * Tg) >> 3, t1 = ((c+1) * Tg) >> 3;
    const int q0 = 16 * g;
    const int q  = q0 + q16;

    bf16x8 fqh[2], fqm[2], fql[2];
    #pragma unroll
    for (int ks = 0; ks < 2; ++ks) {
      int off = (q0 + q16)*DH + 32*ks + colb;
      fqh[ks] = *(const bf16x8*)&Qh[off];
      fqm[ks] = *(const bf16x8*)&Qm[off];
      fql[ks] = *(const bf16x8*)&Ql[off];
    }

    float mrun = -3.0e38f, lrun = 0.f;
    f32x4 yacc[4] = {{0,0,0,0},{0,0,0,0},{0,0,0,0},{0,0,0,0}};

    for (int t = t0; t < t1; ++t) {
      const int j0 = t * 64;
      f32x4 sa[4];
      #pragma unroll
      for (int st = 0; st < 4; ++st) {
        f32x4 acc = {0,0,0,0};
        #pragma unroll
        for (int ks = 0; ks < 2; ++ks) {
          int off = (j0 + 16*st + q16)*DH + 32*ks + colb;
          bf16x8 kh = *(const bf16x8*)&Kh[off];
          bf16x8 km = *(const bf16x8*)&Km[off];
          bf16x8 kl = *(const bf16x8*)&Kl[off];
          acc = __builtin_amdgcn_mfma_f32_16x16x32_bf16(kh, fqh[ks], acc, 0,0,0);
          acc = __builtin_amdgcn_mfma_f32_16x16x32_bf16(kh, fqm[ks], acc, 0,0,0);
          acc = __builtin_amdgcn_mfma_f32_16x16x32_bf16(km, fqh[ks], acc, 0,0,0);
          acc = __builtin_amdgcn_mfma_f32_16x16x32_bf16(km, fqm[ks], acc, 0,0,0);
          acc = __builtin_amdgcn_mfma_f32_16x16x32_bf16(kh, fql[ks], acc, 0,0,0);
          acc = __builtin_amdgcn_mfma_f32_16x16x32_bf16(kl, fqh[ks], acc, 0,0,0);
        }
        sa[st] = acc;
      }
      #pragma unroll
      for (int st = 0; st < 4; ++st)
        #pragma unroll
        for (int r = 0; r < 4; ++r) {
          int key = j0 + 16*st + 4*grp + r;
          if (key > q) sa[st][r] = -3.0e38f;
        }
      float mx = sa[0][0];
      #pragma unroll
      for (int st = 0; st < 4; ++st)
        #pragma unroll
        for (int r = 0; r < 4; ++r) mx = fmaxf(mx, sa[st][r]);
      mx = fmaxf(mx, __shfl_xor(mx, 16));
      mx = fmaxf(mx, __shfl_xor(mx, 32));
      float mnew  = fmaxf(mrun, mx);
      float alpha = __expf(mrun - mnew);
      float ts = 0.f;
      ushort pb[16];
      #pragma unroll
      for (int st = 0; st < 4; ++st)
        #pragma unroll
        for (int r = 0; r < 4; ++r) {
          float p = __expf(sa[st][r] - mnew);
          ts += p;
          pb[st*4 + r] = f2bf(p);
        }
      ts += __shfl_xor(ts, 16);
      ts += __shfl_xor(ts, 32);
      lrun = lrun * alpha + ts;
      mrun = mnew;
      float ar[4];
      #pragma unroll
      for (int r = 0; r < 4; ++r) ar[r] = __shfl(alpha, 4*grp + r, 64);
      #pragma unroll
      for (int dt = 0; dt < 4; ++dt) {
        yacc[dt][0] *= ar[0]; yacc[dt][1] *= ar[1];
        yacc[dt][2] *= ar[2]; yacc[dt][3] *= ar[3];
      }
      #pragma unroll
      for (int st = 0; st < 4; ++st) {
        uint2 v;
        v.x = (uint)pb[st*4+0] | ((uint)pb[st*4+1] << 16);
        v.y = (uint)pb[st*4+2] | ((uint)pb[st*4+3] << 16);
        *(uint2*)&psw[q16*72 + 16*st + 4*grp] = v;
      }
      __threadfence_block();
      __builtin_amdgcn_sched_barrier(0);
      #pragma unroll
      for (int ks = 0; ks < 2; ++ks) {
        bf16x8 pa = *(const bf16x8*)&psw[q16*72 + 32*ks + colb];
        #pragma unroll
        for (int dt = 0; dt < 4; ++dt) {
          bf16x8 ub = *(const bf16x8*)&UTb[(16*dt + q16)*NCTX + j0 + 32*ks + colb];
          yacc[dt] = __builtin_amdgcn_mfma_f32_16x16x32_bf16(pa, ub, yacc[dt], 0,0,0);
        }
      }
    }
    if (grp == 0) {
      Pm[c * NCTX + q] = mrun;
      Pl[c * NCTX + q] = lrun;
    }
    #pragma unroll
    for (int dt = 0; dt < 4; ++dt)
      #pragma unroll
      for (int r = 0; r < 4; ++r)
        Py[(c * NCTX + q0 + 4*grp + r) * DH + 16*dt + q16] = yacc[dt][r];
  }
}

// ---------------- combine (validated, unchanged) ----------------
__global__ __launch_bounds__(256) void combine_kernel(
    const float* __restrict__ Pm, const float* __restrict__ Pl,
    const float* __restrict__ Py, float* __restrict__ Y)
{
  int idx = blockIdx.x * 256 + threadIdx.x;
  int r = idx >> 6, d = idx & 63;
  float mv[NCH];
  float M = -3.0e38f;
  #pragma unroll
  for (int c = 0; c < NCH; ++c) {
    mv[c] = Pm[c*NCTX + r];
    M = fmaxf(M, mv[c]);
  }
  float num = 0.f, den = 0.f;
  #pragma unroll
  for (int c = 0; c < NCH; ++c) {
    float s = __expf(mv[c] - M);
    den += s * Pl[c*NCTX + r];
    num += s * Py[(c*NCTX + r)*DH + d];
  }
  Y[idx] = num / den;
}

// ---------------- epilogue: out = Y @ W_vT (validated, unchanged) ----------------
__global__ __launch_bounds__(256) void out_kernel(
    const float* __restrict__ Y, const float* __restrict__ Wv,
    float* __restrict__ out)
{
  __shared__ float Ws[64][256];
  __shared__ float YsT[64][64];
  const int tid = threadIdx.x;
  const int r0  = blockIdx.x * 64;
  const int cb  = blockIdx.y;
  const int c4  = tid & 63;
  const int rg  = __builtin_amdgcn_readfirstlane(tid >> 6);

  #pragma unroll
  for (int it = 0; it < 16; ++it) {
    int idx = it * 256 + tid;
    int h = idx >> 6, cc = idx & 63;
    *(float4*)&Ws[h][cc * 4] = *(const float4*)&Wv[h * DM + cb * 256 + cc * 4];
  }
  #pragma unroll
  for (int it = 0; it < 4; ++it) {
    int idx = it * 256 + tid;
    int h4 = idx & 15, rr = idx >> 4;
    float4 yv = *(const float4*)&Y[(r0 + rr) * DH + h4 * 4];
    YsT[h4*4+0][rr] = yv.x; YsT[h4*4+1][rr] = yv.y;
    YsT[h4*4+2][rr] = yv.z; YsT[h4*4+3][rr] = yv.w;
  }
  __syncthreads();

  float4 acc[16];
  #pragma unroll
  for (int i = 0; i < 16; ++i) acc[i] = make_float4(0.f, 0.f, 0.f, 0.f);

  #pragma unroll 8
  for (int h = 0; h < 64; ++h) {
    float4 w4 = *(const float4*)&Ws[h][c4 * 4];
    #pragma unroll
    for (int gq = 0; gq < 4; ++gq) {
      float4 y4 = *(const float4*)&YsT[h][rg * 16 + gq * 4];
      float ys[4] = {y4.x, y4.y, y4.z, y4.w};
      #pragma unroll
      for (int e = 0; e < 4; ++e) {
        acc[gq*4+e].x += ys[e] * w4.x;
        acc[gq*4+e].y += ys[e] * w4.y;
        acc[gq*4+e].z += ys[e] * w4.z;
        acc[gq*4+e].w += ys[e] * w4.w;
      }
    }
  }
  #pragma unroll
  for (int i = 0; i < 16; ++i)
    *(float4*)&out[(r0 + rg * 16 + i) * DM + cb * 256 + c4 * 4] = acc[i];
}

extern "C" void kernel_launch(void* const* d_in, const int* in_sizes, int n_in,
                              void* d_out, int out_size, void* d_ws, size_t ws_size,
                              hipStream_t stream) {
  const float* x   = (const float*)d_in[0];
  const float* Wq  = (const float*)d_in[1];
  const float* WkT = (const float*)d_in[2];
  const float* Wo  = (const float*)d_in[3];
  const float* Wv  = (const float*)d_in[4];
  float* out = (float*)d_out;
  float* ws  = (float*)d_ws;
  char*  ob  = (char*)d_out;   // scratch; fully overwritten by out_kernel

  float* Q   = ws + WS_Q;
  float* Kc  = ws + WS_K;
  float* UT  = ws + WS_U;
  float* Y   = ws + WS_Y;
  int*   cnt = (int*)((char*)d_ws + WS_CNT_BYTE);

  ushort* Qhp = (ushort*)(ob + D_QH);
  ushort* Qmp = (ushort*)(ob + D_QM);
  ushort* Qlp = (ushort*)(ob + D_QL);
  ushort* Khp = (ushort*)(ob + D_KH);
  ushort* Kmp = (ushort*)(ob + D_KM);
  ushort* Klp = (ushort*)(ob + D_KL);
  ushort* UTb = (ushort*)(ob + D_UTB);
  float*  Pyp = (float*)(ob + D_PY);
  float*  Pmp = (float*)(ob + D_PM);
  float*  Plp = (float*)(ob + D_PL);
  ushort* WTh = (ushort*)(ob + D_WTH);
  ushort* WTm = (ushort*)(ob + D_WTM);

  hipMemsetAsync(cnt, 0, 4, stream);   // reset steal counter (capture-legal)
  hipLaunchKernelGGL(wsplit_kernel, dim3(768), dim3(256), 0, stream,
                     Wq, WkT, Wo, WTh, WTm);
  hipLaunchKernelGGL(proj_mfma_kernel, dim3(256, 3), dim3(64), 0, stream,
                     x, WTh, WTm, Q, Kc, UT);
  hipLaunchKernelGGL(split_kernel, dim3(1024), dim3(256), 0, stream,
                     Q, Kc, UT, Qhp, Qmp, Qlp, Khp, Kmp, Klp, UTb);
  hipLaunchKernelGGL(attn_kernel, dim3(384), dim3(256), 0, stream,
                     Qhp, Qmp, Qlp, Khp, Kmp, Klp, UTb, cnt, Pmp, Plp, Pyp);
  hipLaunchKernelGGL(combine_kernel, dim3(1024), dim3(256), 0, stream,
                     Pmp, Plp, Pyp, Y);
  hipLaunchKernelGGL(out_kernel, dim3(64, 4), dim3(256), 0, stream, Y, Wv, out);
}

// Round 13
// 119.690 us; speedup vs baseline: 1.1964x; 1.1964x over previous
//
#include <hip/hip_runtime.h>
#include <hip/hip_bf16.h>
#include <math.h>

#define DM    1024
#define DH    64
#define NCTX  4096
#define NCH   8        // key-chunks per q-group
#define NUNIT 2048     // 256 groups x 8 chunks

typedef __attribute__((ext_vector_type(8))) short bf16x8;
typedef __attribute__((ext_vector_type(4))) float f32x4;

// ---- ws (proven 4,456,448 B): f32 Q, K, UT, Y
#define WS_Q   0
#define WS_K   (NCTX*DH)
#define WS_U   (2*NCTX*DH)
#define WS_Y   (3*NCTX*DH)

// ---- d_out scratch (16 MiB, fully overwritten by out_kernel last)
#define D_QH   0
#define D_QM   524288
#define D_QL   1048576
#define D_KH   1572864
#define D_KM   2097152
#define D_KL   2621440
#define D_UTB  3145728
#define D_PY   3670016
#define D_PM   12058624
#define D_PL   12189696
#define D_WTH  12320768
#define D_WTM  12713984

__device__ __forceinline__ ushort f2bf(float x) {
  __hip_bfloat16 h = __float2bfloat16(x);
  return __builtin_bit_cast(ushort, h);
}
__device__ __forceinline__ float bf2f(ushort u) {
  __hip_bfloat16 h = __builtin_bit_cast(__hip_bfloat16, u);
  return __bfloat162float(h);
}

// ---------------- W -> WT digit split (validated, unchanged) ----------------
__global__ __launch_bounds__(256) void wsplit_kernel(
    const float* __restrict__ Wq, const float* __restrict__ WkT,
    const float* __restrict__ Wo,
    ushort* __restrict__ WTh, ushort* __restrict__ WTm)
{
  int gid = blockIdx.x * 256 + threadIdx.x;
  int mat = gid >> 16;
  int idx = gid & 65535;
  float v; int oidx;
  if (mat == 1) {
    v = WkT[idx];
    oidx = 65536 + idx;
  } else {
    int k = idx >> 6, h = idx & 63;
    v = (mat == 0 ? Wq : Wo)[idx];
    oidx = mat * 65536 + h * 1024 + k;
  }
  ushort h16 = f2bf(v);
  float rem = v - bf2f(h16);
  WTh[oidx] = h16;
  WTm[oidx] = f2bf(rem);
}

// ---------------- projections via MFMA (validated r12, unchanged) ----------------
__global__ __launch_bounds__(64, 1) void proj_mfma_kernel(
    const float* __restrict__ x,
    const ushort* __restrict__ WTh, const ushort* __restrict__ WTm,
    float* __restrict__ Q, float* __restrict__ Kc, float* __restrict__ UT)
{
  const int lane = threadIdx.x;
  const int q16  = lane & 15;
  const int grp  = lane >> 4;
  const int colb = grp * 8;
  const int r0   = blockIdx.x * 16;
  const int mat  = blockIdx.y;
  const ushort* __restrict__ wh = WTh + mat * 65536;
  const ushort* __restrict__ wm = WTm + mat * 65536;

  f32x4 acc[4] = {{0,0,0,0},{0,0,0,0},{0,0,0,0},{0,0,0,0}};

  const int xrow = (r0 + q16) * DM + colb;
  float4 a0 = *(const float4*)&x[xrow];
  float4 a1 = *(const float4*)&x[xrow + 4];

  for (int ks = 0; ks < 32; ++ks) {
    float4 n0, n1;
    if (ks < 31) {
      n0 = *(const float4*)&x[xrow + 32*(ks+1)];
      n1 = *(const float4*)&x[xrow + 32*(ks+1) + 4];
    }
    float xv[8] = {a0.x, a0.y, a0.z, a0.w, a1.x, a1.y, a1.z, a1.w};
    bf16x8 xh8, xm8;
    #pragma unroll
    for (int e = 0; e < 8; ++e) {
      ushort h = f2bf(xv[e]);
      float rem = xv[e] - bf2f(h);
      xh8[e] = (short)h;
      xm8[e] = (short)f2bf(rem);
    }
    if (mat == 2) {
      #pragma unroll
      for (int ct = 0; ct < 4; ++ct) {
        const int wb = (16 * ct + q16) * DM + 32 * ks + colb;
        bf16x8 bh = *(const bf16x8*)&wh[wb];
        bf16x8 bm = *(const bf16x8*)&wm[wb];
        acc[ct] = __builtin_amdgcn_mfma_f32_16x16x32_bf16(bh, xh8, acc[ct], 0,0,0);
        acc[ct] = __builtin_amdgcn_mfma_f32_16x16x32_bf16(bh, xm8, acc[ct], 0,0,0);
        acc[ct] = __builtin_amdgcn_mfma_f32_16x16x32_bf16(bm, xh8, acc[ct], 0,0,0);
        acc[ct] = __builtin_amdgcn_mfma_f32_16x16x32_bf16(bm, xm8, acc[ct], 0,0,0);
      }
    } else {
      #pragma unroll
      for (int ct = 0; ct < 4; ++ct) {
        const int wb = (16 * ct + q16) * DM + 32 * ks + colb;
        bf16x8 bh = *(const bf16x8*)&wh[wb];
        bf16x8 bm = *(const bf16x8*)&wm[wb];
        acc[ct] = __builtin_amdgcn_mfma_f32_16x16x32_bf16(xh8, bh, acc[ct], 0,0,0);
        acc[ct] = __builtin_amdgcn_mfma_f32_16x16x32_bf16(xh8, bm, acc[ct], 0,0,0);
        acc[ct] = __builtin_amdgcn_mfma_f32_16x16x32_bf16(xm8, bh, acc[ct], 0,0,0);
        acc[ct] = __builtin_amdgcn_mfma_f32_16x16x32_bf16(xm8, bm, acc[ct], 0,0,0);
      }
    }
    a0 = n0; a1 = n1;
  }

  if (mat == 2) {
    #pragma unroll
    for (int ct = 0; ct < 4; ++ct)
      #pragma unroll
      for (int r = 0; r < 4; ++r)
        UT[(16*ct + 4*grp + r) * NCTX + r0 + q16] = acc[ct][r];
  } else {
    float* __restrict__ Out = (mat == 0) ? Q : Kc;
    #pragma unroll
    for (int ct = 0; ct < 4; ++ct)
      #pragma unroll
      for (int r = 0; r < 4; ++r)
        Out[(r0 + 4*grp + r) * DH + 16*ct + q16] = acc[ct][r];
  }
}

// ---------------- 3-way bf16 digit split (validated, unchanged) ----------------
__global__ __launch_bounds__(256) void split_kernel(
    const float* __restrict__ Q, const float* __restrict__ K, const float* __restrict__ UT,
    ushort* __restrict__ Qh, ushort* __restrict__ Qm, ushort* __restrict__ Ql,
    ushort* __restrict__ Kh, ushort* __restrict__ Km, ushort* __restrict__ Kl,
    ushort* __restrict__ UTb)
{
  int i = blockIdx.x * 256 + threadIdx.x;
  float q = Q[i];
  ushort h = f2bf(q); float fh = bf2f(h);
  ushort m = f2bf(q - fh); float fm = bf2f(m);
  ushort l = f2bf(q - fh - fm);
  Qh[i] = h; Qm[i] = m; Ql[i] = l;
  float k = K[i];
  h = f2bf(k); fh = bf2f(h);
  m = f2bf(k - fh); fm = bf2f(m);
  l = f2bf(k - fh - fm);
  Kh[i] = h; Km[i] = m; Kl[i] = l;
  UTb[i] = f2bf(UT[i]);
}

// ---------------- MFMA flash attention: r11 static scaffold + batched loads ----------
// 512 blocks x 4 waves, static unit map (r11-proven). ONLY change vs r11:
// tile body restructured into load-phase -> compute-phase register staging
// (8 U frags batched at tile start; 12 K-digit frags batched per ks-half)
// to raise memory-level parallelism ~4 -> 12-20 outstanding loads.
__global__ __launch_bounds__(256, 2) void attn_kernel(
    const ushort* __restrict__ Qh, const ushort* __restrict__ Qm, const ushort* __restrict__ Ql,
    const ushort* __restrict__ Kh, const ushort* __restrict__ Km, const ushort* __restrict__ Kl,
    const ushort* __restrict__ UTb,
    float* __restrict__ Pm, float* __restrict__ Pl, float* __restrict__ Py)
{
  __shared__ __align__(16) ushort ps[4][16*72];
  const int tid  = threadIdx.x;
  const int lane = tid & 63;
  const int w    = tid >> 6;
  ushort* psw = ps[w];
  const int q16  = lane & 15;
  const int grp  = lane >> 4;
  const int colb = grp * 8;

  const int u  = blockIdx.x * 4 + w;           // 0..2047
  const int g  = 255 - (u >> 3);               // heavy groups first
  const int c  = u & 7;
  const int Tg = ((16*g + 15) >> 6) + 1;
  const int t0 = (c * Tg) >> 3, t1 = ((c+1) * Tg) >> 3;
  const int q0 = 16 * g;
  const int q  = q0 + q16;

  bf16x8 fqh[2], fqm[2], fql[2];
  #pragma unroll
  for (int ks = 0; ks < 2; ++ks) {
    int off = (q0 + q16)*DH + 32*ks + colb;
    fqh[ks] = *(const bf16x8*)&Qh[off];
    fqm[ks] = *(const bf16x8*)&Qm[off];
    fql[ks] = *(const bf16x8*)&Ql[off];
  }

  float mrun = -3.0e38f, lrun = 0.f;
  f32x4 yacc[4] = {{0,0,0,0},{0,0,0,0},{0,0,0,0},{0,0,0,0}};

  for (int t = t0; t < t1; ++t) {
    const int j0 = t * 64;

    // ---- phase 0: batch the 8 U fragments (independent of P; hides under scores)
    bf16x8 ub[2][4];
    #pragma unroll
    for (int ks = 0; ks < 2; ++ks)
      #pragma unroll
      for (int dt = 0; dt < 4; ++dt)
        ub[ks][dt] = *(const bf16x8*)&UTb[(16*dt + q16)*NCTX + j0 + 32*ks + colb];

    // ---- scores: per ks-half, 12 batched K loads THEN 24 MFMAs
    f32x4 sa[4] = {{0,0,0,0},{0,0,0,0},{0,0,0,0},{0,0,0,0}};
    #pragma unroll
    for (int ks = 0; ks < 2; ++ks) {
      bf16x8 kb[4][3];
      #pragma unroll
      for (int st = 0; st < 4; ++st) {
        int off = (j0 + 16*st + q16)*DH + 32*ks + colb;
        kb[st][0] = *(const bf16x8*)&Kh[off];
        kb[st][1] = *(const bf16x8*)&Km[off];
        kb[st][2] = *(const bf16x8*)&Kl[off];
      }
      #pragma unroll
      for (int st = 0; st < 4; ++st) {
        sa[st] = __builtin_amdgcn_mfma_f32_16x16x32_bf16(kb[st][0], fqh[ks], sa[st], 0,0,0);
        sa[st] = __builtin_amdgcn_mfma_f32_16x16x32_bf16(kb[st][0], fqm[ks], sa[st], 0,0,0);
        sa[st] = __builtin_amdgcn_mfma_f32_16x16x32_bf16(kb[st][1], fqh[ks], sa[st], 0,0,0);
        sa[st] = __builtin_amdgcn_mfma_f32_16x16x32_bf16(kb[st][1], fqm[ks], sa[st], 0,0,0);
        sa[st] = __builtin_amdgcn_mfma_f32_16x16x32_bf16(kb[st][0], fql[ks], sa[st], 0,0,0);
        sa[st] = __builtin_amdgcn_mfma_f32_16x16x32_bf16(kb[st][2], fqh[ks], sa[st], 0,0,0);
      }
    }

    // ---- mask / softmax / alpha (validated, unchanged)
    #pragma unroll
    for (int st = 0; st < 4; ++st)
      #pragma unroll
      for (int r = 0; r < 4; ++r) {
        int key = j0 + 16*st + 4*grp + r;
        if (key > q) sa[st][r] = -3.0e38f;
      }
    float mx = sa[0][0];
    #pragma unroll
    for (int st = 0; st < 4; ++st)
      #pragma unroll
      for (int r = 0; r < 4; ++r) mx = fmaxf(mx, sa[st][r]);
    mx = fmaxf(mx, __shfl_xor(mx, 16));
    mx = fmaxf(mx, __shfl_xor(mx, 32));
    float mnew  = fmaxf(mrun, mx);
    float alpha = __expf(mrun - mnew);
    float ts = 0.f;
    ushort pb[16];
    #pragma unroll
    for (int st = 0; st < 4; ++st)
      #pragma unroll
      for (int r = 0; r < 4; ++r) {
        float p = __expf(sa[st][r] - mnew);
        ts += p;
        pb[st*4 + r] = f2bf(p);
      }
    ts += __shfl_xor(ts, 16);
    ts += __shfl_xor(ts, 32);
    lrun = lrun * alpha + ts;
    mrun = mnew;
    float ar[4];
    #pragma unroll
    for (int r = 0; r < 4; ++r) ar[r] = __shfl(alpha, 4*grp + r, 64);
    #pragma unroll
    for (int dt = 0; dt < 4; ++dt) {
      yacc[dt][0] *= ar[0]; yacc[dt][1] *= ar[1];
      yacc[dt][2] *= ar[2]; yacc[dt][3] *= ar[3];
    }

    // ---- P -> LDS roundtrip + PV (validated; PV uses pre-batched ub)
    #pragma unroll
    for (int st = 0; st < 4; ++st) {
      uint2 v;
      v.x = (uint)pb[st*4+0] | ((uint)pb[st*4+1] << 16);
      v.y = (uint)pb[st*4+2] | ((uint)pb[st*4+3] << 16);
      *(uint2*)&psw[q16*72 + 16*st + 4*grp] = v;
    }
    __threadfence_block();
    __builtin_amdgcn_sched_barrier(0);
    #pragma unroll
    for (int ks = 0; ks < 2; ++ks) {
      bf16x8 pa = *(const bf16x8*)&psw[q16*72 + 32*ks + colb];
      #pragma unroll
      for (int dt = 0; dt < 4; ++dt)
        yacc[dt] = __builtin_amdgcn_mfma_f32_16x16x32_bf16(pa, ub[ks][dt], yacc[dt], 0,0,0);
    }
  }
  if (grp == 0) {
    Pm[c * NCTX + q] = mrun;
    Pl[c * NCTX + q] = lrun;
  }
  #pragma unroll
  for (int dt = 0; dt < 4; ++dt)
    #pragma unroll
    for (int r = 0; r < 4; ++r)
      Py[(c * NCTX + q0 + 4*grp + r) * DH + 16*dt + q16] = yacc[dt][r];
}

// ---------------- combine (validated, unchanged) ----------------
__global__ __launch_bounds__(256) void combine_kernel(
    const float* __restrict__ Pm, const float* __restrict__ Pl,
    const float* __restrict__ Py, float* __restrict__ Y)
{
  int idx = blockIdx.x * 256 + threadIdx.x;
  int r = idx >> 6, d = idx & 63;
  float mv[NCH];
  float M = -3.0e38f;
  #pragma unroll
  for (int c = 0; c < NCH; ++c) {
    mv[c] = Pm[c*NCTX + r];
    M = fmaxf(M, mv[c]);
  }
  float num = 0.f, den = 0.f;
  #pragma unroll
  for (int c = 0; c < NCH; ++c) {
    float s = __expf(mv[c] - M);
    den += s * Pl[c*NCTX + r];
    num += s * Py[(c*NCTX + r)*DH + d];
  }
  Y[idx] = num / den;
}

// ---------------- epilogue: out = Y @ W_vT (validated, unchanged) ----------------
__global__ __launch_bounds__(256) void out_kernel(
    const float* __restrict__ Y, const float* __restrict__ Wv,
    float* __restrict__ out)
{
  __shared__ float Ws[64][256];
  __shared__ float YsT[64][64];
  const int tid = threadIdx.x;
  const int r0  = blockIdx.x * 64;
  const int cb  = blockIdx.y;
  const int c4  = tid & 63;
  const int rg  = __builtin_amdgcn_readfirstlane(tid >> 6);

  #pragma unroll
  for (int it = 0; it < 16; ++it) {
    int idx = it * 256 + tid;
    int h = idx >> 6, cc = idx & 63;
    *(float4*)&Ws[h][cc * 4] = *(const float4*)&Wv[h * DM + cb * 256 + cc * 4];
  }
  #pragma unroll
  for (int it = 0; it < 4; ++it) {
    int idx = it * 256 + tid;
    int h4 = idx & 15, rr = idx >> 4;
    float4 yv = *(const float4*)&Y[(r0 + rr) * DH + h4 * 4];
    YsT[h4*4+0][rr] = yv.x; YsT[h4*4+1][rr] = yv.y;
    YsT[h4*4+2][rr] = yv.z; YsT[h4*4+3][rr] = yv.w;
  }
  __syncthreads();

  float4 acc[16];
  #pragma unroll
  for (int i = 0; i < 16; ++i) acc[i] = make_float4(0.f, 0.f, 0.f, 0.f);

  #pragma unroll 8
  for (int h = 0; h < 64; ++h) {
    float4 w4 = *(const float4*)&Ws[h][c4 * 4];
    #pragma unroll
    for (int gq = 0; gq < 4; ++gq) {
      float4 y4 = *(const float4*)&YsT[h][rg * 16 + gq * 4];
      float ys[4] = {y4.x, y4.y, y4.z, y4.w};
      #pragma unroll
      for (int e = 0; e < 4; ++e) {
        acc[gq*4+e].x += ys[e] * w4.x;
        acc[gq*4+e].y += ys[e] * w4.y;
        acc[gq*4+e].z += ys[e] * w4.z;
        acc[gq*4+e].w += ys[e] * w4.w;
      }
    }
  }
  #pragma unroll
  for (int i = 0; i < 16; ++i)
    *(float4*)&out[(r0 + rg * 16 + i) * DM + cb * 256 + c4 * 4] = acc[i];
}

extern "C" void kernel_launch(void* const* d_in, const int* in_sizes, int n_in,
                              void* d_out, int out_size, void* d_ws, size_t ws_size,
                              hipStream_t stream) {
  const float* x   = (const float*)d_in[0];
  const float* Wq  = (const float*)d_in[1];
  const float* WkT = (const float*)d_in[2];
  const float* Wo  = (const float*)d_in[3];
  const float* Wv  = (const float*)d_in[4];
  float* out = (float*)d_out;
  float* ws  = (float*)d_ws;
  char*  ob  = (char*)d_out;   // scratch; fully overwritten by out_kernel

  float* Q   = ws + WS_Q;
  float* Kc  = ws + WS_K;
  float* UT  = ws + WS_U;
  float* Y   = ws + WS_Y;

  ushort* Qhp = (ushort*)(ob + D_QH);
  ushort* Qmp = (ushort*)(ob + D_QM);
  ushort* Qlp = (ushort*)(ob + D_QL);
  ushort* Khp = (ushort*)(ob + D_KH);
  ushort* Kmp = (ushort*)(ob + D_KM);
  ushort* Klp = (ushort*)(ob + D_KL);
  ushort* UTb = (ushort*)(ob + D_UTB);
  float*  Pyp = (float*)(ob + D_PY);
  float*  Pmp = (float*)(ob + D_PM);
  float*  Plp = (float*)(ob + D_PL);
  ushort* WTh = (ushort*)(ob + D_WTH);
  ushort* WTm = (ushort*)(ob + D_WTM);

  hipLaunchKernelGGL(wsplit_kernel, dim3(768), dim3(256), 0, stream,
                     Wq, WkT, Wo, WTh, WTm);
  hipLaunchKernelGGL(proj_mfma_kernel, dim3(256, 3), dim3(64), 0, stream,
                     x, WTh, WTm, Q, Kc, UT);
  hipLaunchKernelGGL(split_kernel, dim3(1024), dim3(256), 0, stream,
                     Q, Kc, UT, Qhp, Qmp, Qlp, Khp, Kmp, Klp, UTb);
  hipLaunchKernelGGL(attn_kernel, dim3(512), dim3(256), 0, stream,
                     Qhp, Qmp, Qlp, Khp, Kmp, Klp, UTb, Pmp, Plp, Pyp);
  hipLaunchKernelGGL(combine_kernel, dim3(1024), dim3(256), 0, stream,
                     Pmp, Plp, Pyp, Y);
  hipLaunchKernelGGL(out_kernel, dim3(64, 4), dim3(256), 0, stream, Y, Wv, out);
}

// Round 14
// 93.818 us; speedup vs baseline: 1.5263x; 1.2758x over previous
//
#include <hip/hip_runtime.h>
#include <hip/hip_bf16.h>
#include <math.h>

#define DM    1024
#define DH    64
#define NCTX  4096
#define NCH   8        // key-chunks per q-group

typedef __attribute__((ext_vector_type(8))) short bf16x8;
typedef __attribute__((ext_vector_type(4))) float f32x4;

// ---- ws (proven 4,456,448 B): f32 Q, K, UT, Y
#define WS_Q   0
#define WS_K   (NCTX*DH)
#define WS_U   (2*NCTX*DH)
#define WS_Y   (3*NCTX*DH)

// ---- d_out scratch (16 MiB, fully overwritten by out_kernel last)
#define D_QH   0
#define D_QM   524288
#define D_QL   1048576
#define D_KH   1572864
#define D_KM   2097152
#define D_KL   2621440
#define D_UTB  3145728
#define D_PY   3670016
#define D_PM   12058624
#define D_PL   12189696
#define D_WTH  12320768
#define D_WTM  12713984

__device__ __forceinline__ ushort f2bf(float x) {
  __hip_bfloat16 h = __float2bfloat16(x);
  return __builtin_bit_cast(ushort, h);
}
__device__ __forceinline__ float bf2f(ushort u) {
  __hip_bfloat16 h = __builtin_bit_cast(__hip_bfloat16, u);
  return __bfloat162float(h);
}

// ---------------- W -> WT digit split (validated, unchanged) ----------------
__global__ __launch_bounds__(256) void wsplit_kernel(
    const float* __restrict__ Wq, const float* __restrict__ WkT,
    const float* __restrict__ Wo,
    ushort* __restrict__ WTh, ushort* __restrict__ WTm)
{
  int gid = blockIdx.x * 256 + threadIdx.x;
  int mat = gid >> 16;
  int idx = gid & 65535;
  float v; int oidx;
  if (mat == 1) {
    v = WkT[idx];
    oidx = 65536 + idx;
  } else {
    int k = idx >> 6, h = idx & 63;
    v = (mat == 0 ? Wq : Wo)[idx];
    oidx = mat * 65536 + h * 1024 + k;
  }
  ushort h16 = f2bf(v);
  float rem = v - bf2f(h16);
  WTh[oidx] = h16;
  WTm[oidx] = f2bf(rem);
}

// ---------------- projections via MFMA (validated r13, unchanged this round) ----------------
__global__ __launch_bounds__(64, 1) void proj_mfma_kernel(
    const float* __restrict__ x,
    const ushort* __restrict__ WTh, const ushort* __restrict__ WTm,
    float* __restrict__ Q, float* __restrict__ Kc, float* __restrict__ UT)
{
  const int lane = threadIdx.x;
  const int q16  = lane & 15;
  const int grp  = lane >> 4;
  const int colb = grp * 8;
  const int r0   = blockIdx.x * 16;
  const int mat  = blockIdx.y;
  const ushort* __restrict__ wh = WTh + mat * 65536;
  const ushort* __restrict__ wm = WTm + mat * 65536;

  f32x4 acc[4] = {{0,0,0,0},{0,0,0,0},{0,0,0,0},{0,0,0,0}};

  const int xrow = (r0 + q16) * DM + colb;
  float4 a0 = *(const float4*)&x[xrow];
  float4 a1 = *(const float4*)&x[xrow + 4];

  for (int ks = 0; ks < 32; ++ks) {
    float4 n0, n1;
    if (ks < 31) {
      n0 = *(const float4*)&x[xrow + 32*(ks+1)];
      n1 = *(const float4*)&x[xrow + 32*(ks+1) + 4];
    }
    float xv[8] = {a0.x, a0.y, a0.z, a0.w, a1.x, a1.y, a1.z, a1.w};
    bf16x8 xh8, xm8;
    #pragma unroll
    for (int e = 0; e < 8; ++e) {
      ushort h = f2bf(xv[e]);
      float rem = xv[e] - bf2f(h);
      xh8[e] = (short)h;
      xm8[e] = (short)f2bf(rem);
    }
    if (mat == 2) {
      #pragma unroll
      for (int ct = 0; ct < 4; ++ct) {
        const int wb = (16 * ct + q16) * DM + 32 * ks + colb;
        bf16x8 bh = *(const bf16x8*)&wh[wb];
        bf16x8 bm = *(const bf16x8*)&wm[wb];
        acc[ct] = __builtin_amdgcn_mfma_f32_16x16x32_bf16(bh, xh8, acc[ct], 0,0,0);
        acc[ct] = __builtin_amdgcn_mfma_f32_16x16x32_bf16(bh, xm8, acc[ct], 0,0,0);
        acc[ct] = __builtin_amdgcn_mfma_f32_16x16x32_bf16(bm, xh8, acc[ct], 0,0,0);
        acc[ct] = __builtin_amdgcn_mfma_f32_16x16x32_bf16(bm, xm8, acc[ct], 0,0,0);
      }
    } else {
      #pragma unroll
      for (int ct = 0; ct < 4; ++ct) {
        const int wb = (16 * ct + q16) * DM + 32 * ks + colb;
        bf16x8 bh = *(const bf16x8*)&wh[wb];
        bf16x8 bm = *(const bf16x8*)&wm[wb];
        acc[ct] = __builtin_amdgcn_mfma_f32_16x16x32_bf16(xh8, bh, acc[ct], 0,0,0);
        acc[ct] = __builtin_amdgcn_mfma_f32_16x16x32_bf16(xh8, bm, acc[ct], 0,0,0);
        acc[ct] = __builtin_amdgcn_mfma_f32_16x16x32_bf16(xm8, bh, acc[ct], 0,0,0);
        acc[ct] = __builtin_amdgcn_mfma_f32_16x16x32_bf16(xm8, bm, acc[ct], 0,0,0);
      }
    }
    a0 = n0; a1 = n1;
  }

  if (mat == 2) {
    #pragma unroll
    for (int ct = 0; ct < 4; ++ct)
      #pragma unroll
      for (int r = 0; r < 4; ++r)
        UT[(16*ct + 4*grp + r) * NCTX + r0 + q16] = acc[ct][r];
  } else {
    float* __restrict__ Out = (mat == 0) ? Q : Kc;
    #pragma unroll
    for (int ct = 0; ct < 4; ++ct)
      #pragma unroll
      for (int r = 0; r < 4; ++r)
        Out[(r0 + 4*grp + r) * DH + 16*ct + q16] = acc[ct][r];
  }
}

// ---------------- 3-way bf16 digit split (validated, unchanged) ----------------
__global__ __launch_bounds__(256) void split_kernel(
    const float* __restrict__ Q, const float* __restrict__ K, const float* __restrict__ UT,
    ushort* __restrict__ Qh, ushort* __restrict__ Qm, ushort* __restrict__ Ql,
    ushort* __restrict__ Kh, ushort* __restrict__ Km, ushort* __restrict__ Kl,
    ushort* __restrict__ UTb)
{
  int i = blockIdx.x * 256 + threadIdx.x;
  float q = Q[i];
  ushort h = f2bf(q); float fh = bf2f(h);
  ushort m = f2bf(q - fh); float fm = bf2f(m);
  ushort l = f2bf(q - fh - fm);
  Qh[i] = h; Qm[i] = m; Ql[i] = l;
  float k = K[i];
  h = f2bf(k); fh = bf2f(h);
  m = f2bf(k - fh); fm = bf2f(m);
  l = f2bf(k - fh - fm);
  Kh[i] = h; Km[i] = m; Kl[i] = l;
  UTb[i] = f2bf(UT[i]);
}

// ---------------- MFMA flash attention: LDS-staged tiles (r8 pattern) ----------------
// Grid (64 quads, 8 chunks), 256 thr. Block = 4 consecutive q-groups
// (gbase=252-4*qq .. +3, heavy-first) x key-chunk c of the QUAD-MAX tile
// range. Per tile: coalesced cooperative stage of Kh/Km/Kl/U into
// XOR-swizzled LDS, barrier, then each wave runs the validated MFMA body
// for its own q-group (wave-uniform guard skips tiles past its causal
// range -- avoids the fully-masked exp(0)=1 trap; barriers block-uniform).
__global__ __launch_bounds__(256, 2) void attn_kernel(
    const ushort* __restrict__ Qh, const ushort* __restrict__ Qm, const ushort* __restrict__ Ql,
    const ushort* __restrict__ Kh, const ushort* __restrict__ Km, const ushort* __restrict__ Kl,
    const ushort* __restrict__ UTb,
    float* __restrict__ Pm, float* __restrict__ Pl, float* __restrict__ Py)
{
  __shared__ ushort Ksh[3][64*64];                 // 24 KiB, swizzled
  __shared__ ushort Ush[64*64];                    //  8 KiB, swizzled
  __shared__ __align__(16) ushort ps[4][16*72];    //  9 KiB (validated layout)

  const int tid  = threadIdx.x;
  const int lane = tid & 63;
  const int w    = tid >> 6;
  ushort* psw = ps[w];
  const int q16  = lane & 15;
  const int grp  = lane >> 4;
  const int colb = grp * 8;

  const int qq    = blockIdx.x;           // 0..63 quad (heavy first)
  const int c     = blockIdx.y;           // 0..7 chunk
  const int gbase = 252 - 4 * qq;
  const int g     = gbase + w;            // this wave's q-group
  const int gmax  = gbase + 3;
  const int T     = ((16*gmax + 15) >> 6) + 1;       // quad-max tiles
  const int t0 = (c * T) >> 3, t1 = ((c+1) * T) >> 3;
  const int Town = ((16*g + 15) >> 6) + 1;           // own causal tiles
  const int q0 = 16 * g;
  const int q  = q0 + q16;

  bf16x8 fqh[2], fqm[2], fql[2];
  #pragma unroll
  for (int ks = 0; ks < 2; ++ks) {
    int off = (q0 + q16)*DH + 32*ks + colb;
    fqh[ks] = *(const bf16x8*)&Qh[off];
    fqm[ks] = *(const bf16x8*)&Qm[off];
    fql[ks] = *(const bf16x8*)&Ql[off];
  }

  float mrun = -3.0e38f, lrun = 0.f;
  f32x4 yacc[4] = {{0,0,0,0},{0,0,0,0},{0,0,0,0},{0,0,0,0}};

  for (int t = t0; t < t1; ++t) {
    const int j0 = t * 64;
    __syncthreads();   // previous tile's LDS readers done
    // ---- cooperative coalesced stage (32 KiB), XOR-swizzled (slot ^= row&7)
    #pragma unroll
    for (int it = 0; it < 2; ++it) {
      int id  = it * 256 + tid;     // 0..511
      int row = id >> 3;            // 0..63
      int c8  = id & 7;             // 16B slot within row
      int dst = row * 64 + ((c8 ^ (row & 7)) << 3);   // ushort offset
      int src = (j0 + row) * DH + c8 * 8;
      *(bf16x8*)&Ksh[0][dst] = *(const bf16x8*)&Kh[src];
      *(bf16x8*)&Ksh[1][dst] = *(const bf16x8*)&Km[src];
      *(bf16x8*)&Ksh[2][dst] = *(const bf16x8*)&Kl[src];
      *(bf16x8*)&Ush[dst]    = *(const bf16x8*)&UTb[row * NCTX + j0 + c8 * 8];
    }
    __syncthreads();

    if (t < Town) {   // wave-uniform guard; no barriers inside
      // ---- scores from swizzled LDS (validated MFMA math)
      f32x4 sa[4] = {{0,0,0,0},{0,0,0,0},{0,0,0,0},{0,0,0,0}};
      #pragma unroll
      for (int ks = 0; ks < 2; ++ks) {
        #pragma unroll
        for (int st = 0; st < 4; ++st) {
          int row = 16*st + q16;
          int off = row * 64 + (((4*ks + grp) ^ (row & 7)) << 3);
          bf16x8 kh = *(const bf16x8*)&Ksh[0][off];
          bf16x8 km = *(const bf16x8*)&Ksh[1][off];
          bf16x8 kl = *(const bf16x8*)&Ksh[2][off];
          sa[st] = __builtin_amdgcn_mfma_f32_16x16x32_bf16(kh, fqh[ks], sa[st], 0,0,0);
          sa[st] = __builtin_amdgcn_mfma_f32_16x16x32_bf16(kh, fqm[ks], sa[st], 0,0,0);
          sa[st] = __builtin_amdgcn_mfma_f32_16x16x32_bf16(km, fqh[ks], sa[st], 0,0,0);
          sa[st] = __builtin_amdgcn_mfma_f32_16x16x32_bf16(km, fqm[ks], sa[st], 0,0,0);
          sa[st] = __builtin_amdgcn_mfma_f32_16x16x32_bf16(kh, fql[ks], sa[st], 0,0,0);
          sa[st] = __builtin_amdgcn_mfma_f32_16x16x32_bf16(kl, fqh[ks], sa[st], 0,0,0);
        }
      }
      // ---- mask / softmax / alpha (validated)
      #pragma unroll
      for (int st = 0; st < 4; ++st)
        #pragma unroll
        for (int r = 0; r < 4; ++r) {
          int key = j0 + 16*st + 4*grp + r;
          if (key > q) sa[st][r] = -3.0e38f;
        }
      float mx = sa[0][0];
      #pragma unroll
      for (int st = 0; st < 4; ++st)
        #pragma unroll
        for (int r = 0; r < 4; ++r) mx = fmaxf(mx, sa[st][r]);
      mx = fmaxf(mx, __shfl_xor(mx, 16));
      mx = fmaxf(mx, __shfl_xor(mx, 32));
      float mnew  = fmaxf(mrun, mx);
      float alpha = __expf(mrun - mnew);
      float ts = 0.f;
      ushort pb[16];
      #pragma unroll
      for (int st = 0; st < 4; ++st)
        #pragma unroll
        for (int r = 0; r < 4; ++r) {
          float p = __expf(sa[st][r] - mnew);
          ts += p;
          pb[st*4 + r] = f2bf(p);
        }
      ts += __shfl_xor(ts, 16);
      ts += __shfl_xor(ts, 32);
      lrun = lrun * alpha + ts;
      mrun = mnew;
      float ar[4];
      #pragma unroll
      for (int r = 0; r < 4; ++r) ar[r] = __shfl(alpha, 4*grp + r, 64);
      #pragma unroll
      for (int dt = 0; dt < 4; ++dt) {
        yacc[dt][0] *= ar[0]; yacc[dt][1] *= ar[1];
        yacc[dt][2] *= ar[2]; yacc[dt][3] *= ar[3];
      }
      // ---- P -> LDS roundtrip + PV from swizzled U (validated)
      #pragma unroll
      for (int st = 0; st < 4; ++st) {
        uint2 v;
        v.x = (uint)pb[st*4+0] | ((uint)pb[st*4+1] << 16);
        v.y = (uint)pb[st*4+2] | ((uint)pb[st*4+3] << 16);
        *(uint2*)&psw[q16*72 + 16*st + 4*grp] = v;
      }
      __threadfence_block();
      __builtin_amdgcn_sched_barrier(0);
      #pragma unroll
      for (int ks = 0; ks < 2; ++ks) {
        bf16x8 pa = *(const bf16x8*)&psw[q16*72 + 32*ks + colb];
        #pragma unroll
        for (int dt = 0; dt < 4; ++dt) {
          int row = 16*dt + q16;
          int off = row * 64 + (((4*ks + grp) ^ (row & 7)) << 3);
          bf16x8 ub = *(const bf16x8*)&Ush[off];
          yacc[dt] = __builtin_amdgcn_mfma_f32_16x16x32_bf16(pa, ub, yacc[dt], 0,0,0);
        }
      }
    }
  }
  // partials (units with empty effective range: m=-3e38, l=0, y=0)
  if (grp == 0) {
    Pm[c * NCTX + q] = mrun;
    Pl[c * NCTX + q] = lrun;
  }
  #pragma unroll
  for (int dt = 0; dt < 4; ++dt)
    #pragma unroll
    for (int r = 0; r < 4; ++r)
      Py[(c * NCTX + q0 + 4*grp + r) * DH + 16*dt + q16] = yacc[dt][r];
}

// ---------------- combine (validated, unchanged) ----------------
__global__ __launch_bounds__(256) void combine_kernel(
    const float* __restrict__ Pm, const float* __restrict__ Pl,
    const float* __restrict__ Py, float* __restrict__ Y)
{
  int idx = blockIdx.x * 256 + threadIdx.x;
  int r = idx >> 6, d = idx & 63;
  float mv[NCH];
  float M = -3.0e38f;
  #pragma unroll
  for (int c = 0; c < NCH; ++c) {
    mv[c] = Pm[c*NCTX + r];
    M = fmaxf(M, mv[c]);
  }
  float num = 0.f, den = 0.f;
  #pragma unroll
  for (int c = 0; c < NCH; ++c) {
    float s = __expf(mv[c] - M);
    den += s * Pl[c*NCTX + r];
    num += s * Py[(c*NCTX + r)*DH + d];
  }
  Y[idx] = num / den;
}

// ---------------- epilogue: out = Y @ W_vT (validated, unchanged) ----------------
__global__ __launch_bounds__(256) void out_kernel(
    const float* __restrict__ Y, const float* __restrict__ Wv,
    float* __restrict__ out)
{
  __shared__ float Ws[64][256];
  __shared__ float YsT[64][64];
  const int tid = threadIdx.x;
  const int r0  = blockIdx.x * 64;
  const int cb  = blockIdx.y;
  const int c4  = tid & 63;
  const int rg  = __builtin_amdgcn_readfirstlane(tid >> 6);

  #pragma unroll
  for (int it = 0; it < 16; ++it) {
    int idx = it * 256 + tid;
    int h = idx >> 6, cc = idx & 63;
    *(float4*)&Ws[h][cc * 4] = *(const float4*)&Wv[h * DM + cb * 256 + cc * 4];
  }
  #pragma unroll
  for (int it = 0; it < 4; ++it) {
    int idx = it * 256 + tid;
    int h4 = idx & 15, rr = idx >> 4;
    float4 yv = *(const float4*)&Y[(r0 + rr) * DH + h4 * 4];
    YsT[h4*4+0][rr] = yv.x; YsT[h4*4+1][rr] = yv.y;
    YsT[h4*4+2][rr] = yv.z; YsT[h4*4+3][rr] = yv.w;
  }
  __syncthreads();

  float4 acc[16];
  #pragma unroll
  for (int i = 0; i < 16; ++i) acc[i] = make_float4(0.f, 0.f, 0.f, 0.f);

  #pragma unroll 8
  for (int h = 0; h < 64; ++h) {
    float4 w4 = *(const float4*)&Ws[h][c4 * 4];
    #pragma unroll
    for (int gq = 0; gq < 4; ++gq) {
      float4 y4 = *(const float4*)&YsT[h][rg * 16 + gq * 4];
      float ys[4] = {y4.x, y4.y, y4.z, y4.w};
      #pragma unroll
      for (int e = 0; e < 4; ++e) {
        acc[gq*4+e].x += ys[e] * w4.x;
        acc[gq*4+e].y += ys[e] * w4.y;
        acc[gq*4+e].z += ys[e] * w4.z;
        acc[gq*4+e].w += ys[e] * w4.w;
      }
    }
  }
  #pragma unroll
  for (int i = 0; i < 16; ++i)
    *(float4*)&out[(r0 + rg * 16 + i) * DM + cb * 256 + c4 * 4] = acc[i];
}

extern "C" void kernel_launch(void* const* d_in, const int* in_sizes, int n_in,
                              void* d_out, int out_size, void* d_ws, size_t ws_size,
                              hipStream_t stream) {
  const float* x   = (const float*)d_in[0];
  const float* Wq  = (const float*)d_in[1];
  const float* WkT = (const float*)d_in[2];
  const float* Wo  = (const float*)d_in[3];
  const float* Wv  = (const float*)d_in[4];
  float* out = (float*)d_out;
  float* ws  = (float*)d_ws;
  char*  ob  = (char*)d_out;   // scratch; fully overwritten by out_kernel

  float* Q   = ws + WS_Q;
  float* Kc  = ws + WS_K;
  float* UT  = ws + WS_U;
  float* Y   = ws + WS_Y;

  ushort* Qhp = (ushort*)(ob + D_QH);
  ushort* Qmp = (ushort*)(ob + D_QM);
  ushort* Qlp = (ushort*)(ob + D_QL);
  ushort* Khp = (ushort*)(ob + D_KH);
  ushort* Kmp = (ushort*)(ob + D_KM);
  ushort* Klp = (ushort*)(ob + D_KL);
  ushort* UTb = (ushort*)(ob + D_UTB);
  float*  Pyp = (float*)(ob + D_PY);
  float*  Pmp = (float*)(ob + D_PM);
  float*  Plp = (float*)(ob + D_PL);
  ushort* WTh = (ushort*)(ob + D_WTH);
  ushort* WTm = (ushort*)(ob + D_WTM);

  hipLaunchKernelGGL(wsplit_kernel, dim3(768), dim3(256), 0, stream,
                     Wq, WkT, Wo, WTh, WTm);
  hipLaunchKernelGGL(proj_mfma_kernel, dim3(256, 3), dim3(64), 0, stream,
                     x, WTh, WTm, Q, Kc, UT);
  hipLaunchKernelGGL(split_kernel, dim3(1024), dim3(256), 0, stream,
                     Q, Kc, UT, Qhp, Qmp, Qlp, Khp, Kmp, Klp, UTb);
  hipLaunchKernelGGL(attn_kernel, dim3(64, 8), dim3(256), 0, stream,
                     Qhp, Qmp, Qlp, Khp, Kmp, Klp, UTb, Pmp, Plp, Pyp);
  hipLaunchKernelGGL(combine_kernel, dim3(1024), dim3(256), 0, stream,
                     Pmp, Plp, Pyp, Y);
  hipLaunchKernelGGL(out_kernel, dim3(64, 4), dim3(256), 0, stream, Y, Wv, out);
}

// Round 15
// 86.396 us; speedup vs baseline: 1.6575x; 1.0859x over previous
//
#include <hip/hip_runtime.h>
#include <hip/hip_bf16.h>
#include <math.h>

#define DM    1024
#define DH    64
#define NCTX  4096
#define NCH   8        // key-chunks per q-group

typedef __attribute__((ext_vector_type(8))) short bf16x8;
typedef __attribute__((ext_vector_type(4))) float f32x4;

// ---- ws (proven 4,456,448 B): f32 Q, K, UT, Y
#define WS_Q   0
#define WS_K   (NCTX*DH)
#define WS_U   (2*NCTX*DH)
#define WS_Y   (3*NCTX*DH)

// ---- d_out scratch (16 MiB, fully overwritten by out_kernel last)
#define D_QH   0
#define D_QM   524288
#define D_QL   1048576
#define D_KH   1572864
#define D_KM   2097152
#define D_KL   2621440
#define D_UTB  3145728
#define D_PY   3670016
#define D_PM   12058624
#define D_PL   12189696
#define D_WTH  12320768
#define D_WTM  12713984

__device__ __forceinline__ ushort f2bf(float x) {
  __hip_bfloat16 h = __float2bfloat16(x);
  return __builtin_bit_cast(ushort, h);
}
__device__ __forceinline__ float bf2f(ushort u) {
  __hip_bfloat16 h = __builtin_bit_cast(__hip_bfloat16, u);
  return __bfloat162float(h);
}

// ---------------- W -> WT digit split (validated, unchanged) ----------------
__global__ __launch_bounds__(256) void wsplit_kernel(
    const float* __restrict__ Wq, const float* __restrict__ WkT,
    const float* __restrict__ Wo,
    ushort* __restrict__ WTh, ushort* __restrict__ WTm)
{
  int gid = blockIdx.x * 256 + threadIdx.x;
  int mat = gid >> 16;
  int idx = gid & 65535;
  float v; int oidx;
  if (mat == 1) {
    v = WkT[idx];
    oidx = 65536 + idx;
  } else {
    int k = idx >> 6, h = idx & 63;
    v = (mat == 0 ? Wq : Wo)[idx];
    oidx = mat * 65536 + h * 1024 + k;
  }
  ushort h16 = f2bf(v);
  float rem = v - bf2f(h16);
  WTh[oidx] = h16;
  WTm[oidx] = f2bf(rem);
}

// ---------------- projections via MFMA, LDS-staged (r14-proven pattern) ----------------
// Grid (128 row-tiles, 3 mats), 256 thr (4 waves). Block = 32 x-rows x 64 W-cols.
// Per k-step(32): coop stage x->(h,m) and Wh/Wm into XOR-swizzled LDS
// (slot ^= row&3; read-back with same XOR => source slot == grp for all rows
// -> consistent lane->k map across A and B). Wave w: rows (w&1)*16,
// col-tiles {2*(w>>1), 2*(w>>1)+1}. Mat 2 swaps A/B (validated r13 pattern).
__global__ __launch_bounds__(256, 2) void proj_mfma_kernel(
    const float* __restrict__ x,
    const ushort* __restrict__ WTh, const ushort* __restrict__ WTm,
    float* __restrict__ Q, float* __restrict__ Kc, float* __restrict__ UT)
{
  __shared__ __align__(16) ushort xsh[32*32], xsm[32*32];   // 2 KiB each
  __shared__ __align__(16) ushort wsh[64*32], wsm[64*32];   // 4 KiB each

  const int tid  = threadIdx.x;
  const int lane = tid & 63;
  const int w    = tid >> 6;
  const int q16  = lane & 15;
  const int grp  = lane >> 4;
  const int r0   = blockIdx.x * 32;
  const int mat  = blockIdx.y;
  const ushort* __restrict__ wh = WTh + mat * 65536;
  const ushort* __restrict__ wm = WTm + mat * 65536;

  const int rw  = (w & 1) * 16;          // wave's local row base
  const int ct0 = (w >> 1) * 2;          // wave's first col-tile

  f32x4 acc[2] = {{0,0,0,0},{0,0,0,0}};

  for (int ks = 0; ks < 32; ++ks) {
    const int k0 = ks * 32;
    __syncthreads();   // previous step's LDS readers done
    // ---- stage x[32 rows][32 k] -> h/m digits (tid<128: 1 unit of 8 floats)
    if (tid < 128) {
      int row  = tid >> 2, slot = tid & 3;
      const float* src = &x[(r0 + row) * DM + k0 + slot * 8];
      float4 a0 = *(const float4*)&src[0];
      float4 a1 = *(const float4*)&src[4];
      float xv[8] = {a0.x, a0.y, a0.z, a0.w, a1.x, a1.y, a1.z, a1.w};
      bf16x8 hv, mv;
      #pragma unroll
      for (int e = 0; e < 8; ++e) {
        ushort hh = f2bf(xv[e]);
        hv[e] = (short)hh;
        mv[e] = (short)f2bf(xv[e] - bf2f(hh));
      }
      int dst = row * 32 + ((slot ^ (row & 3)) << 3);
      *(bf16x8*)&xsh[dst] = hv;
      *(bf16x8*)&xsm[dst] = mv;
    }
    // ---- stage W[64 cols][32 k] h+m (256 units of bf16x8)
    {
      int row = tid >> 2, slot = tid & 3;
      int src = row * DM + k0 + slot * 8;
      int dst = row * 32 + ((slot ^ (row & 3)) << 3);
      *(bf16x8*)&wsh[dst] = *(const bf16x8*)&wh[src];
      *(bf16x8*)&wsm[dst] = *(const bf16x8*)&wm[src];
    }
    __syncthreads();

    // ---- fragments from swizzled LDS (source slot == grp everywhere)
    int xrow = rw + q16;
    int xoff = xrow * 32 + ((grp ^ (xrow & 3)) << 3);
    bf16x8 xh8 = *(const bf16x8*)&xsh[xoff];
    bf16x8 xm8 = *(const bf16x8*)&xsm[xoff];
    #pragma unroll
    for (int i = 0; i < 2; ++i) {
      int wrow = (ct0 + i) * 16 + q16;
      int woff = wrow * 32 + ((grp ^ (wrow & 3)) << 3);
      bf16x8 bh = *(const bf16x8*)&wsh[woff];
      bf16x8 bm = *(const bf16x8*)&wsm[woff];
      if (mat == 2) {   // A = W, B = x  (validated r13 mat-2 pattern)
        acc[i] = __builtin_amdgcn_mfma_f32_16x16x32_bf16(bh, xh8, acc[i], 0,0,0);
        acc[i] = __builtin_amdgcn_mfma_f32_16x16x32_bf16(bh, xm8, acc[i], 0,0,0);
        acc[i] = __builtin_amdgcn_mfma_f32_16x16x32_bf16(bm, xh8, acc[i], 0,0,0);
        acc[i] = __builtin_amdgcn_mfma_f32_16x16x32_bf16(bm, xm8, acc[i], 0,0,0);
      } else {          // A = x, B = W
        acc[i] = __builtin_amdgcn_mfma_f32_16x16x32_bf16(xh8, bh, acc[i], 0,0,0);
        acc[i] = __builtin_amdgcn_mfma_f32_16x16x32_bf16(xh8, bm, acc[i], 0,0,0);
        acc[i] = __builtin_amdgcn_mfma_f32_16x16x32_bf16(xm8, bh, acc[i], 0,0,0);
        acc[i] = __builtin_amdgcn_mfma_f32_16x16x32_bf16(xm8, bm, acc[i], 0,0,0);
      }
    }
  }

  if (mat == 2) {
    // D[wcol = ct*16+4grp+r][xrow = r0+rw+q16] -> UT contiguous (validated)
    #pragma unroll
    for (int i = 0; i < 2; ++i)
      #pragma unroll
      for (int r = 0; r < 4; ++r)
        UT[((ct0 + i)*16 + 4*grp + r) * NCTX + r0 + rw + q16] = acc[i][r];
  } else {
    float* __restrict__ Out = (mat == 0) ? Q : Kc;
    // D[xrow = r0+rw+4grp+r][wcol = ct*16+q16] (validated)
    #pragma unroll
    for (int i = 0; i < 2; ++i)
      #pragma unroll
      for (int r = 0; r < 4; ++r)
        Out[(r0 + rw + 4*grp + r) * DH + (ct0 + i)*16 + q16] = acc[i][r];
  }
}

// ---------------- 3-way bf16 digit split (validated, unchanged) ----------------
__global__ __launch_bounds__(256) void split_kernel(
    const float* __restrict__ Q, const float* __restrict__ K, const float* __restrict__ UT,
    ushort* __restrict__ Qh, ushort* __restrict__ Qm, ushort* __restrict__ Ql,
    ushort* __restrict__ Kh, ushort* __restrict__ Km, ushort* __restrict__ Kl,
    ushort* __restrict__ UTb)
{
  int i = blockIdx.x * 256 + threadIdx.x;
  float q = Q[i];
  ushort h = f2bf(q); float fh = bf2f(h);
  ushort m = f2bf(q - fh); float fm = bf2f(m);
  ushort l = f2bf(q - fh - fm);
  Qh[i] = h; Qm[i] = m; Ql[i] = l;
  float k = K[i];
  h = f2bf(k); fh = bf2f(h);
  m = f2bf(k - fh); fm = bf2f(m);
  l = f2bf(k - fh - fm);
  Kh[i] = h; Km[i] = m; Kl[i] = l;
  UTb[i] = f2bf(UT[i]);
}

// ---------------- MFMA flash attention: LDS-staged (r14-validated, unchanged) ----------------
__global__ __launch_bounds__(256, 2) void attn_kernel(
    const ushort* __restrict__ Qh, const ushort* __restrict__ Qm, const ushort* __restrict__ Ql,
    const ushort* __restrict__ Kh, const ushort* __restrict__ Km, const ushort* __restrict__ Kl,
    const ushort* __restrict__ UTb,
    float* __restrict__ Pm, float* __restrict__ Pl, float* __restrict__ Py)
{
  __shared__ ushort Ksh[3][64*64];
  __shared__ ushort Ush[64*64];
  __shared__ __align__(16) ushort ps[4][16*72];

  const int tid  = threadIdx.x;
  const int lane = tid & 63;
  const int w    = tid >> 6;
  ushort* psw = ps[w];
  const int q16  = lane & 15;
  const int grp  = lane >> 4;
  const int colb = grp * 8;

  const int qq    = blockIdx.x;
  const int c     = blockIdx.y;
  const int gbase = 252 - 4 * qq;
  const int g     = gbase + w;
  const int gmax  = gbase + 3;
  const int T     = ((16*gmax + 15) >> 6) + 1;
  const int t0 = (c * T) >> 3, t1 = ((c+1) * T) >> 3;
  const int Town = ((16*g + 15) >> 6) + 1;
  const int q0 = 16 * g;
  const int q  = q0 + q16;

  bf16x8 fqh[2], fqm[2], fql[2];
  #pragma unroll
  for (int ks = 0; ks < 2; ++ks) {
    int off = (q0 + q16)*DH + 32*ks + colb;
    fqh[ks] = *(const bf16x8*)&Qh[off];
    fqm[ks] = *(const bf16x8*)&Qm[off];
    fql[ks] = *(const bf16x8*)&Ql[off];
  }

  float mrun = -3.0e38f, lrun = 0.f;
  f32x4 yacc[4] = {{0,0,0,0},{0,0,0,0},{0,0,0,0},{0,0,0,0}};

  for (int t = t0; t < t1; ++t) {
    const int j0 = t * 64;
    __syncthreads();
    #pragma unroll
    for (int it = 0; it < 2; ++it) {
      int id  = it * 256 + tid;
      int row = id >> 3;
      int c8  = id & 7;
      int dst = row * 64 + ((c8 ^ (row & 7)) << 3);
      int src = (j0 + row) * DH + c8 * 8;
      *(bf16x8*)&Ksh[0][dst] = *(const bf16x8*)&Kh[src];
      *(bf16x8*)&Ksh[1][dst] = *(const bf16x8*)&Km[src];
      *(bf16x8*)&Ksh[2][dst] = *(const bf16x8*)&Kl[src];
      *(bf16x8*)&Ush[dst]    = *(const bf16x8*)&UTb[row * NCTX + j0 + c8 * 8];
    }
    __syncthreads();

    if (t < Town) {
      f32x4 sa[4] = {{0,0,0,0},{0,0,0,0},{0,0,0,0},{0,0,0,0}};
      #pragma unroll
      for (int ks = 0; ks < 2; ++ks) {
        #pragma unroll
        for (int st = 0; st < 4; ++st) {
          int row = 16*st + q16;
          int off = row * 64 + (((4*ks + grp) ^ (row & 7)) << 3);
          bf16x8 kh = *(const bf16x8*)&Ksh[0][off];
          bf16x8 km = *(const bf16x8*)&Ksh[1][off];
          bf16x8 kl = *(const bf16x8*)&Ksh[2][off];
          sa[st] = __builtin_amdgcn_mfma_f32_16x16x32_bf16(kh, fqh[ks], sa[st], 0,0,0);
          sa[st] = __builtin_amdgcn_mfma_f32_16x16x32_bf16(kh, fqm[ks], sa[st], 0,0,0);
          sa[st] = __builtin_amdgcn_mfma_f32_16x16x32_bf16(km, fqh[ks], sa[st], 0,0,0);
          sa[st] = __builtin_amdgcn_mfma_f32_16x16x32_bf16(km, fqm[ks], sa[st], 0,0,0);
          sa[st] = __builtin_amdgcn_mfma_f32_16x16x32_bf16(kh, fql[ks], sa[st], 0,0,0);
          sa[st] = __builtin_amdgcn_mfma_f32_16x16x32_bf16(kl, fqh[ks], sa[st], 0,0,0);
        }
      }
      #pragma unroll
      for (int st = 0; st < 4; ++st)
        #pragma unroll
        for (int r = 0; r < 4; ++r) {
          int key = j0 + 16*st + 4*grp + r;
          if (key > q) sa[st][r] = -3.0e38f;
        }
      float mx = sa[0][0];
      #pragma unroll
      for (int st = 0; st < 4; ++st)
        #pragma unroll
        for (int r = 0; r < 4; ++r) mx = fmaxf(mx, sa[st][r]);
      mx = fmaxf(mx, __shfl_xor(mx, 16));
      mx = fmaxf(mx, __shfl_xor(mx, 32));
      float mnew  = fmaxf(mrun, mx);
      float alpha = __expf(mrun - mnew);
      float ts = 0.f;
      ushort pb[16];
      #pragma unroll
      for (int st = 0; st < 4; ++st)
        #pragma unroll
        for (int r = 0; r < 4; ++r) {
          float p = __expf(sa[st][r] - mnew);
          ts += p;
          pb[st*4 + r] = f2bf(p);
        }
      ts += __shfl_xor(ts, 16);
      ts += __shfl_xor(ts, 32);
      lrun = lrun * alpha + ts;
      mrun = mnew;
      float ar[4];
      #pragma unroll
      for (int r = 0; r < 4; ++r) ar[r] = __shfl(alpha, 4*grp + r, 64);
      #pragma unroll
      for (int dt = 0; dt < 4; ++dt) {
        yacc[dt][0] *= ar[0]; yacc[dt][1] *= ar[1];
        yacc[dt][2] *= ar[2]; yacc[dt][3] *= ar[3];
      }
      #pragma unroll
      for (int st = 0; st < 4; ++st) {
        uint2 v;
        v.x = (uint)pb[st*4+0] | ((uint)pb[st*4+1] << 16);
        v.y = (uint)pb[st*4+2] | ((uint)pb[st*4+3] << 16);
        *(uint2*)&psw[q16*72 + 16*st + 4*grp] = v;
      }
      __threadfence_block();
      __builtin_amdgcn_sched_barrier(0);
      #pragma unroll
      for (int ks = 0; ks < 2; ++ks) {
        bf16x8 pa = *(const bf16x8*)&psw[q16*72 + 32*ks + colb];
        #pragma unroll
        for (int dt = 0; dt < 4; ++dt) {
          int row = 16*dt + q16;
          int off = row * 64 + (((4*ks + grp) ^ (row & 7)) << 3);
          bf16x8 ub = *(const bf16x8*)&Ush[off];
          yacc[dt] = __builtin_amdgcn_mfma_f32_16x16x32_bf16(pa, ub, yacc[dt], 0,0,0);
        }
      }
    }
  }
  if (grp == 0) {
    Pm[c * NCTX + q] = mrun;
    Pl[c * NCTX + q] = lrun;
  }
  #pragma unroll
  for (int dt = 0; dt < 4; ++dt)
    #pragma unroll
    for (int r = 0; r < 4; ++r)
      Py[(c * NCTX + q0 + 4*grp + r) * DH + 16*dt + q16] = yacc[dt][r];
}

// ---------------- combine (validated, unchanged) ----------------
__global__ __launch_bounds__(256) void combine_kernel(
    const float* __restrict__ Pm, const float* __restrict__ Pl,
    const float* __restrict__ Py, float* __restrict__ Y)
{
  int idx = blockIdx.x * 256 + threadIdx.x;
  int r = idx >> 6, d = idx & 63;
  float mv[NCH];
  float M = -3.0e38f;
  #pragma unroll
  for (int c = 0; c < NCH; ++c) {
    mv[c] = Pm[c*NCTX + r];
    M = fmaxf(M, mv[c]);
  }
  float num = 0.f, den = 0.f;
  #pragma unroll
  for (int c = 0; c < NCH; ++c) {
    float s = __expf(mv[c] - M);
    den += s * Pl[c*NCTX + r];
    num += s * Py[(c*NCTX + r)*DH + d];
  }
  Y[idx] = num / den;
}

// ---------------- epilogue: out = Y @ W_vT (validated, unchanged) ----------------
__global__ __launch_bounds__(256) void out_kernel(
    const float* __restrict__ Y, const float* __restrict__ Wv,
    float* __restrict__ out)
{
  __shared__ float Ws[64][256];
  __shared__ float YsT[64][64];
  const int tid = threadIdx.x;
  const int r0  = blockIdx.x * 64;
  const int cb  = blockIdx.y;
  const int c4  = tid & 63;
  const int rg  = __builtin_amdgcn_readfirstlane(tid >> 6);

  #pragma unroll
  for (int it = 0; it < 16; ++it) {
    int idx = it * 256 + tid;
    int h = idx >> 6, cc = idx & 63;
    *(float4*)&Ws[h][cc * 4] = *(const float4*)&Wv[h * DM + cb * 256 + cc * 4];
  }
  #pragma unroll
  for (int it = 0; it < 4; ++it) {
    int idx = it * 256 + tid;
    int h4 = idx & 15, rr = idx >> 4;
    float4 yv = *(const float4*)&Y[(r0 + rr) * DH + h4 * 4];
    YsT[h4*4+0][rr] = yv.x; YsT[h4*4+1][rr] = yv.y;
    YsT[h4*4+2][rr] = yv.z; YsT[h4*4+3][rr] = yv.w;
  }
  __syncthreads();

  float4 acc[16];
  #pragma unroll
  for (int i = 0; i < 16; ++i) acc[i] = make_float4(0.f, 0.f, 0.f, 0.f);

  #pragma unroll 8
  for (int h = 0; h < 64; ++h) {
    float4 w4 = *(const float4*)&Ws[h][c4 * 4];
    #pragma unroll
    for (int gq = 0; gq < 4; ++gq) {
      float4 y4 = *(const float4*)&YsT[h][rg * 16 + gq * 4];
      float ys[4] = {y4.x, y4.y, y4.z, y4.w};
      #pragma unroll
      for (int e = 0; e < 4; ++e) {
        acc[gq*4+e].x += ys[e] * w4.x;
        acc[gq*4+e].y += ys[e] * w4.y;
        acc[gq*4+e].z += ys[e] * w4.z;
        acc[gq*4+e].w += ys[e] * w4.w;
      }
    }
  }
  #pragma unroll
  for (int i = 0; i < 16; ++i)
    *(float4*)&out[(r0 + rg * 16 + i) * DM + cb * 256 + c4 * 4] = acc[i];
}

extern "C" void kernel_launch(void* const* d_in, const int* in_sizes, int n_in,
                              void* d_out, int out_size, void* d_ws, size_t ws_size,
                              hipStream_t stream) {
  const float* x   = (const float*)d_in[0];
  const float* Wq  = (const float*)d_in[1];
  const float* WkT = (const float*)d_in[2];
  const float* Wo  = (const float*)d_in[3];
  const float* Wv  = (const float*)d_in[4];
  float* out = (float*)d_out;
  float* ws  = (float*)d_ws;
  char*  ob  = (char*)d_out;   // scratch; fully overwritten by out_kernel

  float* Q   = ws + WS_Q;
  float* Kc  = ws + WS_K;
  float* UT  = ws + WS_U;
  float* Y   = ws + WS_Y;

  ushort* Qhp = (ushort*)(ob + D_QH);
  ushort* Qmp = (ushort*)(ob + D_QM);
  ushort* Qlp = (ushort*)(ob + D_QL);
  ushort* Khp = (ushort*)(ob + D_KH);
  ushort* Kmp = (ushort*)(ob + D_KM);
  ushort* Klp = (ushort*)(ob + D_KL);
  ushort* UTb = (ushort*)(ob + D_UTB);
  float*  Pyp = (float*)(ob + D_PY);
  float*  Pmp = (float*)(ob + D_PM);
  float*  Plp = (float*)(ob + D_PL);
  ushort* WTh = (ushort*)(ob + D_WTH);
  ushort* WTm = (ushort*)(ob + D_WTM);

  hipLaunchKernelGGL(wsplit_kernel, dim3(768), dim3(256), 0, stream,
                     Wq, WkT, Wo, WTh, WTm);
  hipLaunchKernelGGL(proj_mfma_kernel, dim3(128, 3), dim3(256), 0, stream,
                     x, WTh, WTm, Q, Kc, UT);
  hipLaunchKernelGGL(split_kernel, dim3(1024), dim3(256), 0, stream,
                     Q, Kc, UT, Qhp, Qmp, Qlp, Khp, Kmp, Klp, UTb);
  hipLaunchKernelGGL(attn_kernel, dim3(64, 8), dim3(256), 0, stream,
                     Qhp, Qmp, Qlp, Khp, Kmp, Klp, UTb, Pmp, Plp, Pyp);
  hipLaunchKernelGGL(combine_kernel, dim3(1024), dim3(256), 0, stream,
                     Pmp, Plp, Pyp, Y);
  hipLaunchKernelGGL(out_kernel, dim3(64, 4), dim3(256), 0, stream, Y, Wv, out);
}

// Round 16
// 70.887 us; speedup vs baseline: 2.0201x; 1.2188x over previous
//
#include <hip/hip_runtime.h>
#include <hip/hip_bf16.h>
#include <math.h>

#define DM    1024
#define DH    64
#define NCTX  4096
#define NCH   8        // key-chunks per q-group

typedef __attribute__((ext_vector_type(8))) short bf16x8;
typedef __attribute__((ext_vector_type(4))) float f32x4;

// ---- ws (proven 4,456,448 B): only Y is still used (f32 [NCTX][DH])
#define WS_Y   (3*NCTX*DH)

// ---- d_out scratch (16 MiB, fully overwritten by out_kernel last)
#define D_QH   0
#define D_QM   524288
#define D_QL   1048576
#define D_KH   1572864
#define D_KM   2097152
#define D_KL   2621440
#define D_UTB  3145728
#define D_PY   3670016
#define D_PM   12058624
#define D_PL   12189696
#define D_WTH  12320768
#define D_WTM  12713984

__device__ __forceinline__ ushort f2bf(float x) {
  __hip_bfloat16 h = __float2bfloat16(x);
  return __builtin_bit_cast(ushort, h);
}
__device__ __forceinline__ float bf2f(ushort u) {
  __hip_bfloat16 h = __builtin_bit_cast(__hip_bfloat16, u);
  return __bfloat162float(h);
}

// ---------------- W -> WT digit split (validated, unchanged) ----------------
__global__ __launch_bounds__(256) void wsplit_kernel(
    const float* __restrict__ Wq, const float* __restrict__ WkT,
    const float* __restrict__ Wo,
    ushort* __restrict__ WTh, ushort* __restrict__ WTm)
{
  int gid = blockIdx.x * 256 + threadIdx.x;
  int mat = gid >> 16;
  int idx = gid & 65535;
  float v; int oidx;
  if (mat == 1) {
    v = WkT[idx];
    oidx = 65536 + idx;
  } else {
    int k = idx >> 6, h = idx & 63;
    v = (mat == 0 ? Wq : Wo)[idx];
    oidx = mat * 65536 + h * 1024 + k;
  }
  ushort h16 = f2bf(v);
  float rem = v - bf2f(h16);
  WTh[oidx] = h16;
  WTm[oidx] = f2bf(rem);
}

// ---------------- projections via MFMA: 128-deep K panels + fused digit split ----
// Grid (128 row-tiles, 3 mats), 256 thr (4 waves). Block = 32 x-rows x 64 W-cols.
// 8 stages of KP=128: coop stage x->(h,m) and Wh/Wm into XOR-swizzled LDS
// (slot ^= row&15, same involution on write and read), barrier, then each wave
// runs 32 MFMAs (2 col-tiles x 4 ksub x 4 digit-products, k ascending -- same
// accumulation order as r15, bitwise-identical results). Epilogue does the
// validated 3-way digit split in-register and writes Q/K digit arrays + UTb
// directly (split_kernel retired).
__global__ __launch_bounds__(256, 2) void proj_mfma_kernel(
    const float* __restrict__ x,
    const ushort* __restrict__ WTh, const ushort* __restrict__ WTm,
    ushort* __restrict__ Qh, ushort* __restrict__ Qm, ushort* __restrict__ Ql,
    ushort* __restrict__ Kh, ushort* __restrict__ Km, ushort* __restrict__ Kl,
    ushort* __restrict__ UTb)
{
  __shared__ __align__(16) ushort xsh[32*128], xsm[32*128];   // 8 KiB each
  __shared__ __align__(16) ushort wsh[64*128], wsm[64*128];   // 16 KiB each

  const int tid  = threadIdx.x;
  const int lane = tid & 63;
  const int w    = tid >> 6;
  const int q16  = lane & 15;
  const int grp  = lane >> 4;
  const int r0   = blockIdx.x * 32;
  const int mat  = blockIdx.y;
  const ushort* __restrict__ wh = WTh + mat * 65536;
  const ushort* __restrict__ wm = WTm + mat * 65536;

  const int rw  = (w & 1) * 16;          // wave's local row base
  const int ct0 = (w >> 1) * 2;          // wave's first col-tile

  f32x4 acc[2] = {{0,0,0,0},{0,0,0,0}};

  for (int stg = 0; stg < 8; ++stg) {
    const int kp0 = stg * 128;
    __syncthreads();   // previous stage's LDS readers done
    // ---- stage x[32 rows][128 k] -> h/m digits (2 units/thread)
    #pragma unroll
    for (int u = 0; u < 2; ++u) {
      int id  = u * 256 + tid;          // 0..511
      int row = id >> 4, slot = id & 15;
      const float* src = &x[(r0 + row) * DM + kp0 + slot * 8];
      float4 a0 = *(const float4*)&src[0];
      float4 a1 = *(const float4*)&src[4];
      float xv[8] = {a0.x, a0.y, a0.z, a0.w, a1.x, a1.y, a1.z, a1.w};
      bf16x8 hv, mv;
      #pragma unroll
      for (int e = 0; e < 8; ++e) {
        ushort hh = f2bf(xv[e]);
        hv[e] = (short)hh;
        mv[e] = (short)f2bf(xv[e] - bf2f(hh));
      }
      int dst = row * 128 + ((slot ^ (row & 15)) << 3);
      *(bf16x8*)&xsh[dst] = hv;
      *(bf16x8*)&xsm[dst] = mv;
    }
    // ---- stage W[64 cols][128 k] h+m (4 units/thread per digit)
    #pragma unroll
    for (int u = 0; u < 4; ++u) {
      int id  = u * 256 + tid;          // 0..1023
      int row = id >> 4, slot = id & 15;
      int src = row * DM + kp0 + slot * 8;
      int dst = row * 128 + ((slot ^ (row & 15)) << 3);
      *(bf16x8*)&wsh[dst] = *(const bf16x8*)&wh[src];
      *(bf16x8*)&wsm[dst] = *(const bf16x8*)&wm[src];
    }
    __syncthreads();

    // ---- 32 MFMAs per wave from swizzled LDS (consistent lane->k map)
    #pragma unroll
    for (int ksub = 0; ksub < 4; ++ksub) {
      const int s = ksub * 4 + grp;
      const int xrow = rw + q16;
      bf16x8 xh8 = *(const bf16x8*)&xsh[xrow * 128 + ((s ^ (xrow & 15)) << 3)];
      bf16x8 xm8 = *(const bf16x8*)&xsm[xrow * 128 + ((s ^ (xrow & 15)) << 3)];
      #pragma unroll
      for (int i = 0; i < 2; ++i) {
        const int wrow = (ct0 + i) * 16 + q16;
        const int woff = wrow * 128 + ((s ^ (wrow & 15)) << 3);
        bf16x8 bh = *(const bf16x8*)&wsh[woff];
        bf16x8 bm = *(const bf16x8*)&wsm[woff];
        if (mat == 2) {   // A = W, B = x (validated mat-2 pattern)
          acc[i] = __builtin_amdgcn_mfma_f32_16x16x32_bf16(bh, xh8, acc[i], 0,0,0);
          acc[i] = __builtin_amdgcn_mfma_f32_16x16x32_bf16(bh, xm8, acc[i], 0,0,0);
          acc[i] = __builtin_amdgcn_mfma_f32_16x16x32_bf16(bm, xh8, acc[i], 0,0,0);
          acc[i] = __builtin_amdgcn_mfma_f32_16x16x32_bf16(bm, xm8, acc[i], 0,0,0);
        } else {          // A = x, B = W
          acc[i] = __builtin_amdgcn_mfma_f32_16x16x32_bf16(xh8, bh, acc[i], 0,0,0);
          acc[i] = __builtin_amdgcn_mfma_f32_16x16x32_bf16(xh8, bm, acc[i], 0,0,0);
          acc[i] = __builtin_amdgcn_mfma_f32_16x16x32_bf16(xm8, bh, acc[i], 0,0,0);
          acc[i] = __builtin_amdgcn_mfma_f32_16x16x32_bf16(xm8, bm, acc[i], 0,0,0);
        }
      }
    }
  }

  // ---- epilogue: fused digit split (identical math to retired split_kernel)
  if (mat == 2) {
    // D[wcol][xrow] -> UTb[col][row] (validated write pattern)
    #pragma unroll
    for (int i = 0; i < 2; ++i)
      #pragma unroll
      for (int r = 0; r < 4; ++r)
        UTb[((ct0 + i)*16 + 4*grp + r) * NCTX + r0 + rw + q16] = f2bf(acc[i][r]);
  } else {
    ushort* __restrict__ Dh = (mat == 0) ? Qh : Kh;
    ushort* __restrict__ Dm = (mat == 0) ? Qm : Km;
    ushort* __restrict__ Dl = (mat == 0) ? Ql : Kl;
    #pragma unroll
    for (int i = 0; i < 2; ++i)
      #pragma unroll
      for (int r = 0; r < 4; ++r) {
        float v = acc[i][r];
        ushort h = f2bf(v); float fh = bf2f(h);
        ushort m = f2bf(v - fh); float fm = bf2f(m);
        ushort l = f2bf(v - fh - fm);
        int idx = (r0 + rw + 4*grp + r) * DH + (ct0 + i)*16 + q16;
        Dh[idx] = h; Dm[idx] = m; Dl[idx] = l;
      }
  }
}

// ---------------- MFMA flash attention: LDS-staged (r14-validated, unchanged) ----------------
__global__ __launch_bounds__(256, 2) void attn_kernel(
    const ushort* __restrict__ Qh, const ushort* __restrict__ Qm, const ushort* __restrict__ Ql,
    const ushort* __restrict__ Kh, const ushort* __restrict__ Km, const ushort* __restrict__ Kl,
    const ushort* __restrict__ UTb,
    float* __restrict__ Pm, float* __restrict__ Pl, float* __restrict__ Py)
{
  __shared__ ushort Ksh[3][64*64];
  __shared__ ushort Ush[64*64];
  __shared__ __align__(16) ushort ps[4][16*72];

  const int tid  = threadIdx.x;
  const int lane = tid & 63;
  const int w    = tid >> 6;
  ushort* psw = ps[w];
  const int q16  = lane & 15;
  const int grp  = lane >> 4;
  const int colb = grp * 8;

  const int qq    = blockIdx.x;
  const int c     = blockIdx.y;
  const int gbase = 252 - 4 * qq;
  const int g     = gbase + w;
  const int gmax  = gbase + 3;
  const int T     = ((16*gmax + 15) >> 6) + 1;
  const int t0 = (c * T) >> 3, t1 = ((c+1) * T) >> 3;
  const int Town = ((16*g + 15) >> 6) + 1;
  const int q0 = 16 * g;
  const int q  = q0 + q16;

  bf16x8 fqh[2], fqm[2], fql[2];
  #pragma unroll
  for (int ks = 0; ks < 2; ++ks) {
    int off = (q0 + q16)*DH + 32*ks + colb;
    fqh[ks] = *(const bf16x8*)&Qh[off];
    fqm[ks] = *(const bf16x8*)&Qm[off];
    fql[ks] = *(const bf16x8*)&Ql[off];
  }

  float mrun = -3.0e38f, lrun = 0.f;
  f32x4 yacc[4] = {{0,0,0,0},{0,0,0,0},{0,0,0,0},{0,0,0,0}};

  for (int t = t0; t < t1; ++t) {
    const int j0 = t * 64;
    __syncthreads();
    #pragma unroll
    for (int it = 0; it < 2; ++it) {
      int id  = it * 256 + tid;
      int row = id >> 3;
      int c8  = id & 7;
      int dst = row * 64 + ((c8 ^ (row & 7)) << 3);
      int src = (j0 + row) * DH + c8 * 8;
      *(bf16x8*)&Ksh[0][dst] = *(const bf16x8*)&Kh[src];
      *(bf16x8*)&Ksh[1][dst] = *(const bf16x8*)&Km[src];
      *(bf16x8*)&Ksh[2][dst] = *(const bf16x8*)&Kl[src];
      *(bf16x8*)&Ush[dst]    = *(const bf16x8*)&UTb[row * NCTX + j0 + c8 * 8];
    }
    __syncthreads();

    if (t < Town) {
      f32x4 sa[4] = {{0,0,0,0},{0,0,0,0},{0,0,0,0},{0,0,0,0}};
      #pragma unroll
      for (int ks = 0; ks < 2; ++ks) {
        #pragma unroll
        for (int st = 0; st < 4; ++st) {
          int row = 16*st + q16;
          int off = row * 64 + (((4*ks + grp) ^ (row & 7)) << 3);
          bf16x8 kh = *(const bf16x8*)&Ksh[0][off];
          bf16x8 km = *(const bf16x8*)&Ksh[1][off];
          bf16x8 kl = *(const bf16x8*)&Ksh[2][off];
          sa[st] = __builtin_amdgcn_mfma_f32_16x16x32_bf16(kh, fqh[ks], sa[st], 0,0,0);
          sa[st] = __builtin_amdgcn_mfma_f32_16x16x32_bf16(kh, fqm[ks], sa[st], 0,0,0);
          sa[st] = __builtin_amdgcn_mfma_f32_16x16x32_bf16(km, fqh[ks], sa[st], 0,0,0);
          sa[st] = __builtin_amdgcn_mfma_f32_16x16x32_bf16(km, fqm[ks], sa[st], 0,0,0);
          sa[st] = __builtin_amdgcn_mfma_f32_16x16x32_bf16(kh, fql[ks], sa[st], 0,0,0);
          sa[st] = __builtin_amdgcn_mfma_f32_16x16x32_bf16(kl, fqh[ks], sa[st], 0,0,0);
        }
      }
      #pragma unroll
      for (int st = 0; st < 4; ++st)
        #pragma unroll
        for (int r = 0; r < 4; ++r) {
          int key = j0 + 16*st + 4*grp + r;
          if (key > q) sa[st][r] = -3.0e38f;
        }
      float mx = sa[0][0];
      #pragma unroll
      for (int st = 0; st < 4; ++st)
        #pragma unroll
        for (int r = 0; r < 4; ++r) mx = fmaxf(mx, sa[st][r]);
      mx = fmaxf(mx, __shfl_xor(mx, 16));
      mx = fmaxf(mx, __shfl_xor(mx, 32));
      float mnew  = fmaxf(mrun, mx);
      float alpha = __expf(mrun - mnew);
      float ts = 0.f;
      ushort pb[16];
      #pragma unroll
      for (int st = 0; st < 4; ++st)
        #pragma unroll
        for (int r = 0; r < 4; ++r) {
          float p = __expf(sa[st][r] - mnew);
          ts += p;
          pb[st*4 + r] = f2bf(p);
        }
      ts += __shfl_xor(ts, 16);
      ts += __shfl_xor(ts, 32);
      lrun = lrun * alpha + ts;
      mrun = mnew;
      float ar[4];
      #pragma unroll
      for (int r = 0; r < 4; ++r) ar[r] = __shfl(alpha, 4*grp + r, 64);
      #pragma unroll
      for (int dt = 0; dt < 4; ++dt) {
        yacc[dt][0] *= ar[0]; yacc[dt][1] *= ar[1];
        yacc[dt][2] *= ar[2]; yacc[dt][3] *= ar[3];
      }
      #pragma unroll
      for (int st = 0; st < 4; ++st) {
        uint2 v;
        v.x = (uint)pb[st*4+0] | ((uint)pb[st*4+1] << 16);
        v.y = (uint)pb[st*4+2] | ((uint)pb[st*4+3] << 16);
        *(uint2*)&psw[q16*72 + 16*st + 4*grp] = v;
      }
      __threadfence_block();
      __builtin_amdgcn_sched_barrier(0);
      #pragma unroll
      for (int ks = 0; ks < 2; ++ks) {
        bf16x8 pa = *(const bf16x8*)&psw[q16*72 + 32*ks + colb];
        #pragma unroll
        for (int dt = 0; dt < 4; ++dt) {
          int row = 16*dt + q16;
          int off = row * 64 + (((4*ks + grp) ^ (row & 7)) << 3);
          bf16x8 ub = *(const bf16x8*)&Ush[off];
          yacc[dt] = __builtin_amdgcn_mfma_f32_16x16x32_bf16(pa, ub, yacc[dt], 0,0,0);
        }
      }
    }
  }
  if (grp == 0) {
    Pm[c * NCTX + q] = mrun;
    Pl[c * NCTX + q] = lrun;
  }
  #pragma unroll
  for (int dt = 0; dt < 4; ++dt)
    #pragma unroll
    for (int r = 0; r < 4; ++r)
      Py[(c * NCTX + q0 + 4*grp + r) * DH + 16*dt + q16] = yacc[dt][r];
}

// ---------------- combine (validated, unchanged) ----------------
__global__ __launch_bounds__(256) void combine_kernel(
    const float* __restrict__ Pm, const float* __restrict__ Pl,
    const float* __restrict__ Py, float* __restrict__ Y)
{
  int idx = blockIdx.x * 256 + threadIdx.x;
  int r = idx >> 6, d = idx & 63;
  float mv[NCH];
  float M = -3.0e38f;
  #pragma unroll
  for (int c = 0; c < NCH; ++c) {
    mv[c] = Pm[c*NCTX + r];
    M = fmaxf(M, mv[c]);
  }
  float num = 0.f, den = 0.f;
  #pragma unroll
  for (int c = 0; c < NCH; ++c) {
    float s = __expf(mv[c] - M);
    den += s * Pl[c*NCTX + r];
    num += s * Py[(c*NCTX + r)*DH + d];
  }
  Y[idx] = num / den;
}

// ---------------- epilogue: out = Y @ W_vT (validated, unchanged) ----------------
__global__ __launch_bounds__(256) void out_kernel(
    const float* __restrict__ Y, const float* __restrict__ Wv,
    float* __restrict__ out)
{
  __shared__ float Ws[64][256];
  __shared__ float YsT[64][64];
  const int tid = threadIdx.x;
  const int r0  = blockIdx.x * 64;
  const int cb  = blockIdx.y;
  const int c4  = tid & 63;
  const int rg  = __builtin_amdgcn_readfirstlane(tid >> 6);

  #pragma unroll
  for (int it = 0; it < 16; ++it) {
    int idx = it * 256 + tid;
    int h = idx >> 6, cc = idx & 63;
    *(float4*)&Ws[h][cc * 4] = *(const float4*)&Wv[h * DM + cb * 256 + cc * 4];
  }
  #pragma unroll
  for (int it = 0; it < 4; ++it) {
    int idx = it * 256 + tid;
    int h4 = idx & 15, rr = idx >> 4;
    float4 yv = *(const float4*)&Y[(r0 + rr) * DH + h4 * 4];
    YsT[h4*4+0][rr] = yv.x; YsT[h4*4+1][rr] = yv.y;
    YsT[h4*4+2][rr] = yv.z; YsT[h4*4+3][rr] = yv.w;
  }
  __syncthreads();

  float4 acc[16];
  #pragma unroll
  for (int i = 0; i < 16; ++i) acc[i] = make_float4(0.f, 0.f, 0.f, 0.f);

  #pragma unroll 8
  for (int h = 0; h < 64; ++h) {
    float4 w4 = *(const float4*)&Ws[h][c4 * 4];
    #pragma unroll
    for (int gq = 0; gq < 4; ++gq) {
      float4 y4 = *(const float4*)&YsT[h][rg * 16 + gq * 4];
      float ys[4] = {y4.x, y4.y, y4.z, y4.w};
      #pragma unroll
      for (int e = 0; e < 4; ++e) {
        acc[gq*4+e].x += ys[e] * w4.x;
        acc[gq*4+e].y += ys[e] * w4.y;
        acc[gq*4+e].z += ys[e] * w4.z;
        acc[gq*4+e].w += ys[e] * w4.w;
      }
    }
  }
  #pragma unroll
  for (int i = 0; i < 16; ++i)
    *(float4*)&out[(r0 + rg * 16 + i) * DM + cb * 256 + c4 * 4] = acc[i];
}

extern "C" void kernel_launch(void* const* d_in, const int* in_sizes, int n_in,
                              void* d_out, int out_size, void* d_ws, size_t ws_size,
                              hipStream_t stream) {
  const float* x   = (const float*)d_in[0];
  const float* Wq  = (const float*)d_in[1];
  const float* WkT = (const float*)d_in[2];
  const float* Wo  = (const float*)d_in[3];
  const float* Wv  = (const float*)d_in[4];
  float* out = (float*)d_out;
  float* ws  = (float*)d_ws;
  char*  ob  = (char*)d_out;   // scratch; fully overwritten by out_kernel

  float* Y   = ws + WS_Y;

  ushort* Qhp = (ushort*)(ob + D_QH);
  ushort* Qmp = (ushort*)(ob + D_QM);
  ushort* Qlp = (ushort*)(ob + D_QL);
  ushort* Khp = (ushort*)(ob + D_KH);
  ushort* Kmp = (ushort*)(ob + D_KM);
  ushort* Klp = (ushort*)(ob + D_KL);
  ushort* UTb = (ushort*)(ob + D_UTB);
  float*  Pyp = (float*)(ob + D_PY);
  float*  Pmp = (float*)(ob + D_PM);
  float*  Plp = (float*)(ob + D_PL);
  ushort* WTh = (ushort*)(ob + D_WTH);
  ushort* WTm = (ushort*)(ob + D_WTM);

  hipLaunchKernelGGL(wsplit_kernel, dim3(768), dim3(256), 0, stream,
                     Wq, WkT, Wo, WTh, WTm);
  hipLaunchKernelGGL(proj_mfma_kernel, dim3(128, 3), dim3(256), 0, stream,
                     x, WTh, WTm, Qhp, Qmp, Qlp, Khp, Kmp, Klp, UTb);
  hipLaunchKernelGGL(attn_kernel, dim3(64, 8), dim3(256), 0, stream,
                     Qhp, Qmp, Qlp, Khp, Kmp, Klp, UTb, Pmp, Plp, Pyp);
  hipLaunchKernelGGL(combine_kernel, dim3(1024), dim3(256), 0, stream,
                     Pmp, Plp, Pyp, Y);
  hipLaunchKernelGGL(out_kernel, dim3(64, 4), dim3(256), 0, stream, Y, Wv, out);
}

// Round 17
// 69.975 us; speedup vs baseline: 2.0464x; 1.0130x over previous
//
#include <hip/hip_runtime.h>
#include <hip/hip_bf16.h>
#include <math.h>

#define DM    1024
#define DH    64
#define NCTX  4096
#define NCH   8        // key-chunks per q-group

typedef __attribute__((ext_vector_type(8))) short bf16x8;
typedef __attribute__((ext_vector_type(4))) float f32x4;

// ---- ws (proven 4,456,448 B): only Y is still used (f32 [NCTX][DH])
#define WS_Y   (3*NCTX*DH)

// ---- d_out scratch (16 MiB, fully overwritten by out_kernel last)
#define D_QH   0
#define D_QM   524288
#define D_QL   1048576
#define D_KH   1572864
#define D_KM   2097152
#define D_KL   2621440
#define D_UTB  3145728
#define D_PY   3670016
#define D_PM   12058624
#define D_PL   12189696
#define D_WTH  12320768
#define D_WTM  12713984

__device__ __forceinline__ ushort f2bf(float x) {
  __hip_bfloat16 h = __float2bfloat16(x);
  return __builtin_bit_cast(ushort, h);
}
__device__ __forceinline__ float bf2f(ushort u) {
  __hip_bfloat16 h = __builtin_bit_cast(__hip_bfloat16, u);
  return __bfloat162float(h);
}

// async global->LDS, 16B per lane: LDS dest = wave-uniform base + lane*16,
// global src is PER-LANE (pre-swizzled source, linear LDS dst -- rule #21).
typedef __attribute__((address_space(1))) const unsigned int gas_u32;
typedef __attribute__((address_space(3))) unsigned int las_u32;
__device__ __forceinline__ void gload_lds16(const void* g, void* l) {
  __builtin_amdgcn_global_load_lds((gas_u32*)g, (las_u32*)l, 16, 0, 0);
}

// ---------------- W -> WT digit split (validated, unchanged) ----------------
__global__ __launch_bounds__(256) void wsplit_kernel(
    const float* __restrict__ Wq, const float* __restrict__ WkT,
    const float* __restrict__ Wo,
    ushort* __restrict__ WTh, ushort* __restrict__ WTm)
{
  int gid = blockIdx.x * 256 + threadIdx.x;
  int mat = gid >> 16;
  int idx = gid & 65535;
  float v; int oidx;
  if (mat == 1) {
    v = WkT[idx];
    oidx = 65536 + idx;
  } else {
    int k = idx >> 6, h = idx & 63;
    v = (mat == 0 ? Wq : Wo)[idx];
    oidx = mat * 65536 + h * 1024 + k;
  }
  ushort h16 = f2bf(v);
  float rem = v - bf2f(h16);
  WTh[oidx] = h16;
  WTm[oidx] = f2bf(rem);
}

// ---------------- projections via MFMA: 128-deep K panels + fused digit split ----
// r16 structure; ONLY change: W staging now uses global_load_lds with
// pre-swizzled per-lane global source and linear LDS dest. The resulting
// LDS image is bit-identical to r16's (s_lds = s_src ^ (row&15) involution).
__global__ __launch_bounds__(256, 2) void proj_mfma_kernel(
    const float* __restrict__ x,
    const ushort* __restrict__ WTh, const ushort* __restrict__ WTm,
    ushort* __restrict__ Qh, ushort* __restrict__ Qm, ushort* __restrict__ Ql,
    ushort* __restrict__ Kh, ushort* __restrict__ Km, ushort* __restrict__ Kl,
    ushort* __restrict__ UTb)
{
  __shared__ __align__(16) ushort xsh[32*128], xsm[32*128];   // 8 KiB each
  __shared__ __align__(16) ushort wsh[64*128], wsm[64*128];   // 16 KiB each

  const int tid  = threadIdx.x;
  const int lane = tid & 63;
  const int w    = tid >> 6;
  const int q16  = lane & 15;
  const int grp  = lane >> 4;
  const int r0   = blockIdx.x * 32;
  const int mat  = blockIdx.y;
  const ushort* __restrict__ wh = WTh + mat * 65536;
  const ushort* __restrict__ wm = WTm + mat * 65536;

  const int rw  = (w & 1) * 16;          // wave's local row base
  const int ct0 = (w >> 1) * 2;          // wave's first col-tile

  f32x4 acc[2] = {{0,0,0,0},{0,0,0,0}};

  for (int stg = 0; stg < 8; ++stg) {
    const int kp0 = stg * 128;
    __syncthreads();   // previous stage's LDS readers done
    // ---- stage x[32 rows][128 k] -> h/m digits (register path: needs split)
    #pragma unroll
    for (int u = 0; u < 2; ++u) {
      int id  = u * 256 + tid;          // 0..511
      int row = id >> 4, slot = id & 15;
      const float* src = &x[(r0 + row) * DM + kp0 + slot * 8];
      float4 a0 = *(const float4*)&src[0];
      float4 a1 = *(const float4*)&src[4];
      float xv[8] = {a0.x, a0.y, a0.z, a0.w, a1.x, a1.y, a1.z, a1.w};
      bf16x8 hv, mv;
      #pragma unroll
      for (int e = 0; e < 8; ++e) {
        ushort hh = f2bf(xv[e]);
        hv[e] = (short)hh;
        mv[e] = (short)f2bf(xv[e] - bf2f(hh));
      }
      int dst = row * 128 + ((slot ^ (row & 15)) << 3);
      *(bf16x8*)&xsh[dst] = hv;
      *(bf16x8*)&xsm[dst] = mv;
    }
    // ---- stage W[64 cols][128 k] h+m via global_load_lds (async, no VGPR trip)
    #pragma unroll
    for (int u = 0; u < 4; ++u) {
      int ubase = u * 256 + w * 64;     // wave-uniform linear unit base
      int unit  = ubase + lane;
      int row   = unit >> 4, slotp = unit & 15;
      int ssrc  = slotp ^ (row & 15);   // pre-swizzled source slot
      int gsrc  = row * DM + kp0 + ssrc * 8;
      gload_lds16(&wh[gsrc], &wsh[ubase * 8]);
      gload_lds16(&wm[gsrc], &wsm[ubase * 8]);
    }
    __syncthreads();   // drains vmcnt (async LDS writes) + lgkmcnt

    // ---- 32 MFMAs per wave from swizzled LDS (consistent lane->k map)
    #pragma unroll
    for (int ksub = 0; ksub < 4; ++ksub) {
      const int s = ksub * 4 + grp;
      const int xrow = rw + q16;
      bf16x8 xh8 = *(const bf16x8*)&xsh[xrow * 128 + ((s ^ (xrow & 15)) << 3)];
      bf16x8 xm8 = *(const bf16x8*)&xsm[xrow * 128 + ((s ^ (xrow & 15)) << 3)];
      #pragma unroll
      for (int i = 0; i < 2; ++i) {
        const int wrow = (ct0 + i) * 16 + q16;
        const int woff = wrow * 128 + ((s ^ (wrow & 15)) << 3);
        bf16x8 bh = *(const bf16x8*)&wsh[woff];
        bf16x8 bm = *(const bf16x8*)&wsm[woff];
        if (mat == 2) {   // A = W, B = x (validated mat-2 pattern)
          acc[i] = __builtin_amdgcn_mfma_f32_16x16x32_bf16(bh, xh8, acc[i], 0,0,0);
          acc[i] = __builtin_amdgcn_mfma_f32_16x16x32_bf16(bh, xm8, acc[i], 0,0,0);
          acc[i] = __builtin_amdgcn_mfma_f32_16x16x32_bf16(bm, xh8, acc[i], 0,0,0);
          acc[i] = __builtin_amdgcn_mfma_f32_16x16x32_bf16(bm, xm8, acc[i], 0,0,0);
        } else {          // A = x, B = W
          acc[i] = __builtin_amdgcn_mfma_f32_16x16x32_bf16(xh8, bh, acc[i], 0,0,0);
          acc[i] = __builtin_amdgcn_mfma_f32_16x16x32_bf16(xh8, bm, acc[i], 0,0,0);
          acc[i] = __builtin_amdgcn_mfma_f32_16x16x32_bf16(xm8, bh, acc[i], 0,0,0);
          acc[i] = __builtin_amdgcn_mfma_f32_16x16x32_bf16(xm8, bm, acc[i], 0,0,0);
        }
      }
    }
  }

  // ---- epilogue: fused digit split (validated, unchanged)
  if (mat == 2) {
    #pragma unroll
    for (int i = 0; i < 2; ++i)
      #pragma unroll
      for (int r = 0; r < 4; ++r)
        UTb[((ct0 + i)*16 + 4*grp + r) * NCTX + r0 + rw + q16] = f2bf(acc[i][r]);
  } else {
    ushort* __restrict__ Dh = (mat == 0) ? Qh : Kh;
    ushort* __restrict__ Dm = (mat == 0) ? Qm : Km;
    ushort* __restrict__ Dl = (mat == 0) ? Ql : Kl;
    #pragma unroll
    for (int i = 0; i < 2; ++i)
      #pragma unroll
      for (int r = 0; r < 4; ++r) {
        float v = acc[i][r];
        ushort h = f2bf(v); float fh = bf2f(h);
        ushort m = f2bf(v - fh); float fm = bf2f(m);
        ushort l = f2bf(v - fh - fm);
        int idx = (r0 + rw + 4*grp + r) * DH + (ct0 + i)*16 + q16;
        Dh[idx] = h; Dm[idx] = m; Dl[idx] = l;
      }
  }
}

// ---------------- MFMA flash attention: LDS-staged; staging via global_load_lds ----
// r16 structure; ONLY change: K/U tile staging uses global_load_lds with
// pre-swizzled per-lane source + linear LDS dest (bit-identical LDS image).
__global__ __launch_bounds__(256, 2) void attn_kernel(
    const ushort* __restrict__ Qh, const ushort* __restrict__ Qm, const ushort* __restrict__ Ql,
    const ushort* __restrict__ Kh, const ushort* __restrict__ Km, const ushort* __restrict__ Kl,
    const ushort* __restrict__ UTb,
    float* __restrict__ Pm, float* __restrict__ Pl, float* __restrict__ Py)
{
  __shared__ ushort Ksh[3][64*64];
  __shared__ ushort Ush[64*64];
  __shared__ __align__(16) ushort ps[4][16*72];

  const int tid  = threadIdx.x;
  const int lane = tid & 63;
  const int w    = tid >> 6;
  ushort* psw = ps[w];
  const int q16  = lane & 15;
  const int grp  = lane >> 4;
  const int colb = grp * 8;

  const int qq    = blockIdx.x;
  const int c     = blockIdx.y;
  const int gbase = 252 - 4 * qq;
  const int g     = gbase + w;
  const int gmax  = gbase + 3;
  const int T     = ((16*gmax + 15) >> 6) + 1;
  const int t0 = (c * T) >> 3, t1 = ((c+1) * T) >> 3;
  const int Town = ((16*g + 15) >> 6) + 1;
  const int q0 = 16 * g;
  const int q  = q0 + q16;

  bf16x8 fqh[2], fqm[2], fql[2];
  #pragma unroll
  for (int ks = 0; ks < 2; ++ks) {
    int off = (q0 + q16)*DH + 32*ks + colb;
    fqh[ks] = *(const bf16x8*)&Qh[off];
    fqm[ks] = *(const bf16x8*)&Qm[off];
    fql[ks] = *(const bf16x8*)&Ql[off];
  }

  float mrun = -3.0e38f, lrun = 0.f;
  f32x4 yacc[4] = {{0,0,0,0},{0,0,0,0},{0,0,0,0},{0,0,0,0}};

  for (int t = t0; t < t1; ++t) {
    const int j0 = t * 64;
    __syncthreads();
    // ---- staging via global_load_lds: linear LDS dest, pre-swizzled source
    #pragma unroll
    for (int it = 0; it < 2; ++it) {
      int ubase = it * 256 + w * 64;    // wave-uniform
      int unit  = ubase + lane;
      int row   = unit >> 3, slotp = unit & 7;
      int c8    = slotp ^ (row & 7);    // pre-swizzled source slot
      int src   = (j0 + row) * DH + c8 * 8;
      gload_lds16(&Kh[src], &Ksh[0][ubase * 8]);
      gload_lds16(&Km[src], &Ksh[1][ubase * 8]);
      gload_lds16(&Kl[src], &Ksh[2][ubase * 8]);
      gload_lds16(&UTb[row * NCTX + j0 + c8 * 8], &Ush[ubase * 8]);
    }
    __syncthreads();   // drains vmcnt before any wave reads the tiles

    if (t < Town) {
      f32x4 sa[4] = {{0,0,0,0},{0,0,0,0},{0,0,0,0},{0,0,0,0}};
      #pragma unroll
      for (int ks = 0; ks < 2; ++ks) {
        #pragma unroll
        for (int st = 0; st < 4; ++st) {
          int row = 16*st + q16;
          int off = row * 64 + (((4*ks + grp) ^ (row & 7)) << 3);
          bf16x8 kh = *(const bf16x8*)&Ksh[0][off];
          bf16x8 km = *(const bf16x8*)&Ksh[1][off];
          bf16x8 kl = *(const bf16x8*)&Ksh[2][off];
          sa[st] = __builtin_amdgcn_mfma_f32_16x16x32_bf16(kh, fqh[ks], sa[st], 0,0,0);
          sa[st] = __builtin_amdgcn_mfma_f32_16x16x32_bf16(kh, fqm[ks], sa[st], 0,0,0);
          sa[st] = __builtin_amdgcn_mfma_f32_16x16x32_bf16(km, fqh[ks], sa[st], 0,0,0);
          sa[st] = __builtin_amdgcn_mfma_f32_16x16x32_bf16(km, fqm[ks], sa[st], 0,0,0);
          sa[st] = __builtin_amdgcn_mfma_f32_16x16x32_bf16(kh, fql[ks], sa[st], 0,0,0);
          sa[st] = __builtin_amdgcn_mfma_f32_16x16x32_bf16(kl, fqh[ks], sa[st], 0,0,0);
        }
      }
      #pragma unroll
      for (int st = 0; st < 4; ++st)
        #pragma unroll
        for (int r = 0; r < 4; ++r) {
          int key = j0 + 16*st + 4*grp + r;
          if (key > q) sa[st][r] = -3.0e38f;
        }
      float mx = sa[0][0];
      #pragma unroll
      for (int st = 0; st < 4; ++st)
        #pragma unroll
        for (int r = 0; r < 4; ++r) mx = fmaxf(mx, sa[st][r]);
      mx = fmaxf(mx, __shfl_xor(mx, 16));
      mx = fmaxf(mx, __shfl_xor(mx, 32));
      float mnew  = fmaxf(mrun, mx);
      float alpha = __expf(mrun - mnew);
      float ts = 0.f;
      ushort pb[16];
      #pragma unroll
      for (int st = 0; st < 4; ++st)
        #pragma unroll
        for (int r = 0; r < 4; ++r) {
          float p = __expf(sa[st][r] - mnew);
          ts += p;
          pb[st*4 + r] = f2bf(p);
        }
      ts += __shfl_xor(ts, 16);
      ts += __shfl_xor(ts, 32);
      lrun = lrun * alpha + ts;
      mrun = mnew;
      float ar[4];
      #pragma unroll
      for (int r = 0; r < 4; ++r) ar[r] = __shfl(alpha, 4*grp + r, 64);
      #pragma unroll
      for (int dt = 0; dt < 4; ++dt) {
        yacc[dt][0] *= ar[0]; yacc[dt][1] *= ar[1];
        yacc[dt][2] *= ar[2]; yacc[dt][3] *= ar[3];
      }
      #pragma unroll
      for (int st = 0; st < 4; ++st) {
        uint2 v;
        v.x = (uint)pb[st*4+0] | ((uint)pb[st*4+1] << 16);
        v.y = (uint)pb[st*4+2] | ((uint)pb[st*4+3] << 16);
        *(uint2*)&psw[q16*72 + 16*st + 4*grp] = v;
      }
      __threadfence_block();
      __builtin_amdgcn_sched_barrier(0);
      #pragma unroll
      for (int ks = 0; ks < 2; ++ks) {
        bf16x8 pa = *(const bf16x8*)&psw[q16*72 + 32*ks + colb];
        #pragma unroll
        for (int dt = 0; dt < 4; ++dt) {
          int row = 16*dt + q16;
          int off = row * 64 + (((4*ks + grp) ^ (row & 7)) << 3);
          bf16x8 ub = *(const bf16x8*)&Ush[off];
          yacc[dt] = __builtin_amdgcn_mfma_f32_16x16x32_bf16(pa, ub, yacc[dt], 0,0,0);
        }
      }
    }
  }
  if (grp == 0) {
    Pm[c * NCTX + q] = mrun;
    Pl[c * NCTX + q] = lrun;
  }
  #pragma unroll
  for (int dt = 0; dt < 4; ++dt)
    #pragma unroll
    for (int r = 0; r < 4; ++r)
      Py[(c * NCTX + q0 + 4*grp + r) * DH + 16*dt + q16] = yacc[dt][r];
}

// ---------------- combine (validated, unchanged) ----------------
__global__ __launch_bounds__(256) void combine_kernel(
    const float* __restrict__ Pm, const float* __restrict__ Pl,
    const float* __restrict__ Py, float* __restrict__ Y)
{
  int idx = blockIdx.x * 256 + threadIdx.x;
  int r = idx >> 6, d = idx & 63;
  float mv[NCH];
  float M = -3.0e38f;
  #pragma unroll
  for (int c = 0; c < NCH; ++c) {
    mv[c] = Pm[c*NCTX + r];
    M = fmaxf(M, mv[c]);
  }
  float num = 0.f, den = 0.f;
  #pragma unroll
  for (int c = 0; c < NCH; ++c) {
    float s = __expf(mv[c] - M);
    den += s * Pl[c*NCTX + r];
    num += s * Py[(c*NCTX + r)*DH + d];
  }
  Y[idx] = num / den;
}

// ---------------- epilogue: out = Y @ W_vT (validated, unchanged) ----------------
__global__ __launch_bounds__(256) void out_kernel(
    const float* __restrict__ Y, const float* __restrict__ Wv,
    float* __restrict__ out)
{
  __shared__ float Ws[64][256];
  __shared__ float YsT[64][64];
  const int tid = threadIdx.x;
  const int r0  = blockIdx.x * 64;
  const int cb  = blockIdx.y;
  const int c4  = tid & 63;
  const int rg  = __builtin_amdgcn_readfirstlane(tid >> 6);

  #pragma unroll
  for (int it = 0; it < 16; ++it) {
    int idx = it * 256 + tid;
    int h = idx >> 6, cc = idx & 63;
    *(float4*)&Ws[h][cc * 4] = *(const float4*)&Wv[h * DM + cb * 256 + cc * 4];
  }
  #pragma unroll
  for (int it = 0; it < 4; ++it) {
    int idx = it * 256 + tid;
    int h4 = idx & 15, rr = idx >> 4;
    float4 yv = *(const float4*)&Y[(r0 + rr) * DH + h4 * 4];
    YsT[h4*4+0][rr] = yv.x; YsT[h4*4+1][rr] = yv.y;
    YsT[h4*4+2][rr] = yv.z; YsT[h4*4+3][rr] = yv.w;
  }
  __syncthreads();

  float4 acc[16];
  #pragma unroll
  for (int i = 0; i < 16; ++i) acc[i] = make_float4(0.f, 0.f, 0.f, 0.f);

  #pragma unroll 8
  for (int h = 0; h < 64; ++h) {
    float4 w4 = *(const float4*)&Ws[h][c4 * 4];
    #pragma unroll
    for (int gq = 0; gq < 4; ++gq) {
      float4 y4 = *(const float4*)&YsT[h][rg * 16 + gq * 4];
      float ys[4] = {y4.x, y4.y, y4.z, y4.w};
      #pragma unroll
      for (int e = 0; e < 4; ++e) {
        acc[gq*4+e].x += ys[e] * w4.x;
        acc[gq*4+e].y += ys[e] * w4.y;
        acc[gq*4+e].z += ys[e] * w4.z;
        acc[gq*4+e].w += ys[e] * w4.w;
      }
    }
  }
  #pragma unroll
  for (int i = 0; i < 16; ++i)
    *(float4*)&out[(r0 + rg * 16 + i) * DM + cb * 256 + c4 * 4] = acc[i];
}

extern "C" void kernel_launch(void* const* d_in, const int* in_sizes, int n_in,
                              void* d_out, int out_size, void* d_ws, size_t ws_size,
                              hipStream_t stream) {
  const float* x   = (const float*)d_in[0];
  const float* Wq  = (const float*)d_in[1];
  const float* WkT = (const float*)d_in[2];
  const float* Wo  = (const float*)d_in[3];
  const float* Wv  = (const float*)d_in[4];
  float* out = (float*)d_out;
  float* ws  = (float*)d_ws;
  char*  ob  = (char*)d_out;   // scratch; fully overwritten by out_kernel

  float* Y   = ws + WS_Y;

  ushort* Qhp = (ushort*)(ob + D_QH);
  ushort* Qmp = (ushort*)(ob + D_QM);
  ushort* Qlp = (ushort*)(ob + D_QL);
  ushort* Khp = (ushort*)(ob + D_KH);
  ushort* Kmp = (ushort*)(ob + D_KM);
  ushort* Klp = (ushort*)(ob + D_KL);
  ushort* UTb = (ushort*)(ob + D_UTB);
  float*  Pyp = (float*)(ob + D_PY);
  float*  Pmp = (float*)(ob + D_PM);
  float*  Plp = (float*)(ob + D_PL);
  ushort* WTh = (ushort*)(ob + D_WTH);
  ushort* WTm = (ushort*)(ob + D_WTM);

  hipLaunchKernelGGL(wsplit_kernel, dim3(768), dim3(256), 0, stream,
                     Wq, WkT, Wo, WTh, WTm);
  hipLaunchKernelGGL(proj_mfma_kernel, dim3(128, 3), dim3(256), 0, stream,
                     x, WTh, WTm, Qhp, Qmp, Qlp, Khp, Kmp, Klp, UTb);
  hipLaunchKernelGGL(attn_kernel, dim3(64, 8), dim3(256), 0, stream,
                     Qhp, Qmp, Qlp, Khp, Kmp, Klp, UTb, Pmp, Plp, Pyp);
  hipLaunchKernelGGL(combine_kernel, dim3(1024), dim3(256), 0, stream,
                     Pmp, Plp, Pyp, Y);
  hipLaunchKernelGGL(out_kernel, dim3(64, 4), dim3(256), 0, stream, Y, Wv, out);
}

// Round 18
// 67.332 us; speedup vs baseline: 2.1267x; 1.0392x over previous
//
#include <hip/hip_runtime.h>
#include <hip/hip_bf16.h>
#include <math.h>

#define DM    1024
#define DH    64
#define NCTX  4096
#define NCH   8        // key-chunks per q-group

typedef __attribute__((ext_vector_type(8))) short bf16x8;
typedef __attribute__((ext_vector_type(4))) float f32x4;

// ---- d_out scratch (16 MiB, fully overwritten by out_kernel last)
#define D_QH   0
#define D_QM   524288
#define D_QL   1048576
#define D_KH   1572864
#define D_KM   2097152
#define D_KL   2621440
#define D_UTB  3145728
#define D_PY   3670016
#define D_PM   12058624
#define D_PL   12189696
#define D_WTH  12320768
#define D_WTM  12713984

__device__ __forceinline__ ushort f2bf(float x) {
  __hip_bfloat16 h = __float2bfloat16(x);
  return __builtin_bit_cast(ushort, h);
}
__device__ __forceinline__ float bf2f(ushort u) {
  __hip_bfloat16 h = __builtin_bit_cast(__hip_bfloat16, u);
  return __bfloat162float(h);
}

// async global->LDS, 16B/lane: LDS dest wave-uniform base + lane*16;
// global src per-lane (pre-swizzled source, linear LDS dest -- rule #21).
typedef __attribute__((address_space(1))) const unsigned int gas_u32;
typedef __attribute__((address_space(3))) unsigned int las_u32;
__device__ __forceinline__ void gload_lds16(const void* g, void* l) {
  __builtin_amdgcn_global_load_lds((gas_u32*)g, (las_u32*)l, 16, 0, 0);
}

// ---------------- W -> WT digit split (validated, unchanged) ----------------
__global__ __launch_bounds__(256) void wsplit_kernel(
    const float* __restrict__ Wq, const float* __restrict__ WkT,
    const float* __restrict__ Wo,
    ushort* __restrict__ WTh, ushort* __restrict__ WTm)
{
  int gid = blockIdx.x * 256 + threadIdx.x;
  int mat = gid >> 16;
  int idx = gid & 65535;
  float v; int oidx;
  if (mat == 1) {
    v = WkT[idx];
    oidx = 65536 + idx;
  } else {
    int k = idx >> 6, h = idx & 63;
    v = (mat == 0 ? Wq : Wo)[idx];
    oidx = mat * 65536 + h * 1024 + k;
  }
  ushort h16 = f2bf(v);
  float rem = v - bf2f(h16);
  WTh[oidx] = h16;
  WTm[oidx] = f2bf(rem);
}

// ---------------- projections via MFMA: 2-phase pipelined K panels -------------
// r17 math verbatim; schedule change only: W double-buffered via global_load_lds
// issued BEFORE compute (latency hidden under 32 MFMAs); x global loads issued
// at loop top into regs (T14 issue-early), split+ds_write after barrier.
// LDS image per stage is bit-identical to r17's.
__global__ __launch_bounds__(256, 2) void proj_mfma_kernel(
    const float* __restrict__ x,
    const ushort* __restrict__ WTh, const ushort* __restrict__ WTm,
    ushort* __restrict__ Qh, ushort* __restrict__ Qm, ushort* __restrict__ Ql,
    ushort* __restrict__ Kh, ushort* __restrict__ Km, ushort* __restrict__ Kl,
    ushort* __restrict__ UTb)
{
  __shared__ __align__(16) ushort xsh[32*128], xsm[32*128];        // 8 KiB each
  __shared__ __align__(16) ushort wsh[2][64*128], wsm[2][64*128];  // 16 KiB each buf

  const int tid  = threadIdx.x;
  const int lane = tid & 63;
  const int w    = tid >> 6;
  const int q16  = lane & 15;
  const int grp  = lane >> 4;
  const int r0   = blockIdx.x * 32;
  const int mat  = blockIdx.y;
  const ushort* __restrict__ wh = WTh + mat * 65536;
  const ushort* __restrict__ wm = WTm + mat * 65536;

  const int rw  = (w & 1) * 16;          // wave's local row base
  const int ct0 = (w >> 1) * 2;          // wave's first col-tile

  const int xrowl = tid >> 4, xslot = tid & 15;   // x-staging coords (rows xrowl, xrowl+16)

  auto stage_w = [&](int b, int s) {
    const int kp0 = s * 128;
    #pragma unroll
    for (int u = 0; u < 4; ++u) {
      int ubase = u * 256 + w * 64;     // wave-uniform
      int unit  = ubase + lane;
      int row   = unit >> 4, slotp = unit & 15;
      int ssrc  = slotp ^ (row & 15);   // pre-swizzled source slot
      int gsrc  = row * DM + kp0 + ssrc * 8;
      gload_lds16(&wh[gsrc], &wsh[b][ubase * 8]);
      gload_lds16(&wm[gsrc], &wsm[b][ubase * 8]);
    }
  };
  auto xload = [&](int s, float4& a0, float4& a1, float4& b0, float4& b1) {
    const int kp0 = s * 128;
    const float* s0 = &x[(r0 + xrowl) * DM + kp0 + xslot * 8];
    const float* s1 = &x[(r0 + xrowl + 16) * DM + kp0 + xslot * 8];
    a0 = *(const float4*)&s0[0]; a1 = *(const float4*)&s0[4];
    b0 = *(const float4*)&s1[0]; b1 = *(const float4*)&s1[4];
  };
  auto xsplit_write = [&](float4 a0, float4 a1, float4 b0, float4 b1) {
    float xv0[8] = {a0.x,a0.y,a0.z,a0.w,a1.x,a1.y,a1.z,a1.w};
    float xv1[8] = {b0.x,b0.y,b0.z,b0.w,b1.x,b1.y,b1.z,b1.w};
    bf16x8 hv0, mv0, hv1, mv1;
    #pragma unroll
    for (int e = 0; e < 8; ++e) {
      ushort h0 = f2bf(xv0[e]);
      hv0[e] = (short)h0;  mv0[e] = (short)f2bf(xv0[e] - bf2f(h0));
      ushort h1 = f2bf(xv1[e]);
      hv1[e] = (short)h1;  mv1[e] = (short)f2bf(xv1[e] - bf2f(h1));
    }
    int d0 = xrowl * 128 + ((xslot ^ (xrowl & 15)) << 3);
    int r1 = xrowl + 16;
    int d1 = r1 * 128 + ((xslot ^ (r1 & 15)) << 3);
    *(bf16x8*)&xsh[d0] = hv0;  *(bf16x8*)&xsm[d0] = mv0;
    *(bf16x8*)&xsh[d1] = hv1;  *(bf16x8*)&xsm[d1] = mv1;
  };

  f32x4 acc[2] = {{0,0,0,0},{0,0,0,0}};

  // prologue: stage x(0) + W(buf0, 0)
  {
    float4 a0, a1, b0, b1;
    xload(0, a0, a1, b0, b1);
    xsplit_write(a0, a1, b0, b1);
    stage_w(0, 0);
  }
  __syncthreads();

  int cur = 0;
  for (int stg = 0; stg < 8; ++stg) {
    // issue next-stage loads BEFORE compute (latency hides under MFMAs)
    float4 na0, na1, nb0, nb1;
    if (stg < 7) {
      xload(stg + 1, na0, na1, nb0, nb1);
      stage_w(cur ^ 1, stg + 1);
    }
    // ---- 32 MFMAs per wave from swizzled LDS (validated math)
    #pragma unroll
    for (int ksub = 0; ksub < 4; ++ksub) {
      const int s = ksub * 4 + grp;
      const int xrow = rw + q16;
      bf16x8 xh8 = *(const bf16x8*)&xsh[xrow * 128 + ((s ^ (xrow & 15)) << 3)];
      bf16x8 xm8 = *(const bf16x8*)&xsm[xrow * 128 + ((s ^ (xrow & 15)) << 3)];
      #pragma unroll
      for (int i = 0; i < 2; ++i) {
        const int wrow = (ct0 + i) * 16 + q16;
        const int woff = wrow * 128 + ((s ^ (wrow & 15)) << 3);
        bf16x8 bh = *(const bf16x8*)&wsh[cur][woff];
        bf16x8 bm = *(const bf16x8*)&wsm[cur][woff];
        if (mat == 2) {   // A = W, B = x (validated mat-2 pattern)
          acc[i] = __builtin_amdgcn_mfma_f32_16x16x32_bf16(bh, xh8, acc[i], 0,0,0);
          acc[i] = __builtin_amdgcn_mfma_f32_16x16x32_bf16(bh, xm8, acc[i], 0,0,0);
          acc[i] = __builtin_amdgcn_mfma_f32_16x16x32_bf16(bm, xh8, acc[i], 0,0,0);
          acc[i] = __builtin_amdgcn_mfma_f32_16x16x32_bf16(bm, xm8, acc[i], 0,0,0);
        } else {          // A = x, B = W
          acc[i] = __builtin_amdgcn_mfma_f32_16x16x32_bf16(xh8, bh, acc[i], 0,0,0);
          acc[i] = __builtin_amdgcn_mfma_f32_16x16x32_bf16(xh8, bm, acc[i], 0,0,0);
          acc[i] = __builtin_amdgcn_mfma_f32_16x16x32_bf16(xm8, bh, acc[i], 0,0,0);
          acc[i] = __builtin_amdgcn_mfma_f32_16x16x32_bf16(xm8, bm, acc[i], 0,0,0);
        }
      }
    }
    __syncthreads();   // xsh readers done; W[next] drained (covered by compute)
    if (stg < 7) xsplit_write(na0, na1, nb0, nb1);
    __syncthreads();   // xsh[next] visible
    cur ^= 1;
  }

  // ---- epilogue: fused digit split (validated, unchanged)
  if (mat == 2) {
    #pragma unroll
    for (int i = 0; i < 2; ++i)
      #pragma unroll
      for (int r = 0; r < 4; ++r)
        UTb[((ct0 + i)*16 + 4*grp + r) * NCTX + r0 + rw + q16] = f2bf(acc[i][r]);
  } else {
    ushort* __restrict__ Dh = (mat == 0) ? Qh : Kh;
    ushort* __restrict__ Dm = (mat == 0) ? Qm : Km;
    ushort* __restrict__ Dl = (mat == 0) ? Ql : Kl;
    #pragma unroll
    for (int i = 0; i < 2; ++i)
      #pragma unroll
      for (int r = 0; r < 4; ++r) {
        float v = acc[i][r];
        ushort h = f2bf(v); float fh = bf2f(h);
        ushort m = f2bf(v - fh); float fm = bf2f(m);
        ushort l = f2bf(v - fh - fm);
        int idx = (r0 + rw + 4*grp + r) * DH + (ct0 + i)*16 + q16;
        Dh[idx] = h; Dm[idx] = m; Dl[idx] = l;
      }
  }
}

// ---------------- MFMA flash attention: 2-phase double-buffered tiles ----------
// r17 math verbatim; schedule change only: K/U tiles double-buffered, next tile
// staged (async gload_lds) BEFORE computing current; ONE barrier per tile.
__global__ __launch_bounds__(256, 2) void attn_kernel(
    const ushort* __restrict__ Qh, const ushort* __restrict__ Qm, const ushort* __restrict__ Ql,
    const ushort* __restrict__ Kh, const ushort* __restrict__ Km, const ushort* __restrict__ Kl,
    const ushort* __restrict__ UTb,
    float* __restrict__ Pm, float* __restrict__ Pl, float* __restrict__ Py)
{
  __shared__ ushort Ksh[2][3][64*64];
  __shared__ ushort Ush[2][64*64];
  __shared__ __align__(16) ushort ps[4][16*72];

  const int tid  = threadIdx.x;
  const int lane = tid & 63;
  const int w    = tid >> 6;
  ushort* psw = ps[w];
  const int q16  = lane & 15;
  const int grp  = lane >> 4;
  const int colb = grp * 8;

  const int qq    = blockIdx.x;
  const int c     = blockIdx.y;
  const int gbase = 252 - 4 * qq;
  const int g     = gbase + w;
  const int gmax  = gbase + 3;
  const int T     = ((16*gmax + 15) >> 6) + 1;
  const int t0 = (c * T) >> 3, t1 = ((c+1) * T) >> 3;
  const int Town = ((16*g + 15) >> 6) + 1;
  const int q0 = 16 * g;
  const int q  = q0 + q16;

  auto stage = [&](int b, int t) {
    const int j0 = t * 64;
    #pragma unroll
    for (int it = 0; it < 2; ++it) {
      int ubase = it * 256 + w * 64;    // wave-uniform
      int unit  = ubase + lane;
      int row   = unit >> 3, slotp = unit & 7;
      int c8    = slotp ^ (row & 7);    // pre-swizzled source slot
      int src   = (j0 + row) * DH + c8 * 8;
      gload_lds16(&Kh[src], &Ksh[b][0][ubase * 8]);
      gload_lds16(&Km[src], &Ksh[b][1][ubase * 8]);
      gload_lds16(&Kl[src], &Ksh[b][2][ubase * 8]);
      gload_lds16(&UTb[row * NCTX + j0 + c8 * 8], &Ush[b][ubase * 8]);
    }
  };

  bf16x8 fqh[2], fqm[2], fql[2];
  #pragma unroll
  for (int ks = 0; ks < 2; ++ks) {
    int off = (q0 + q16)*DH + 32*ks + colb;
    fqh[ks] = *(const bf16x8*)&Qh[off];
    fqm[ks] = *(const bf16x8*)&Qm[off];
    fql[ks] = *(const bf16x8*)&Ql[off];
  }

  float mrun = -3.0e38f, lrun = 0.f;
  f32x4 yacc[4] = {{0,0,0,0},{0,0,0,0},{0,0,0,0},{0,0,0,0}};

  if (t0 < t1) stage(0, t0);
  __syncthreads();

  int cur = 0;
  for (int t = t0; t < t1; ++t) {
    if (t + 1 < t1) stage(cur ^ 1, t + 1);   // prefetch next tile (async)
    if (t < Town) {
      const int j0 = t * 64;
      f32x4 sa[4] = {{0,0,0,0},{0,0,0,0},{0,0,0,0},{0,0,0,0}};
      #pragma unroll
      for (int ks = 0; ks < 2; ++ks) {
        #pragma unroll
        for (int st = 0; st < 4; ++st) {
          int row = 16*st + q16;
          int off = row * 64 + (((4*ks + grp) ^ (row & 7)) << 3);
          bf16x8 kh = *(const bf16x8*)&Ksh[cur][0][off];
          bf16x8 km = *(const bf16x8*)&Ksh[cur][1][off];
          bf16x8 kl = *(const bf16x8*)&Ksh[cur][2][off];
          sa[st] = __builtin_amdgcn_mfma_f32_16x16x32_bf16(kh, fqh[ks], sa[st], 0,0,0);
          sa[st] = __builtin_amdgcn_mfma_f32_16x16x32_bf16(kh, fqm[ks], sa[st], 0,0,0);
          sa[st] = __builtin_amdgcn_mfma_f32_16x16x32_bf16(km, fqh[ks], sa[st], 0,0,0);
          sa[st] = __builtin_amdgcn_mfma_f32_16x16x32_bf16(km, fqm[ks], sa[st], 0,0,0);
          sa[st] = __builtin_amdgcn_mfma_f32_16x16x32_bf16(kh, fql[ks], sa[st], 0,0,0);
          sa[st] = __builtin_amdgcn_mfma_f32_16x16x32_bf16(kl, fqh[ks], sa[st], 0,0,0);
        }
      }
      #pragma unroll
      for (int st = 0; st < 4; ++st)
        #pragma unroll
        for (int r = 0; r < 4; ++r) {
          int key = j0 + 16*st + 4*grp + r;
          if (key > q) sa[st][r] = -3.0e38f;
        }
      float mx = sa[0][0];
      #pragma unroll
      for (int st = 0; st < 4; ++st)
        #pragma unroll
        for (int r = 0; r < 4; ++r) mx = fmaxf(mx, sa[st][r]);
      mx = fmaxf(mx, __shfl_xor(mx, 16));
      mx = fmaxf(mx, __shfl_xor(mx, 32));
      float mnew  = fmaxf(mrun, mx);
      float alpha = __expf(mrun - mnew);
      float ts = 0.f;
      ushort pb[16];
      #pragma unroll
      for (int st = 0; st < 4; ++st)
        #pragma unroll
        for (int r = 0; r < 4; ++r) {
          float p = __expf(sa[st][r] - mnew);
          ts += p;
          pb[st*4 + r] = f2bf(p);
        }
      ts += __shfl_xor(ts, 16);
      ts += __shfl_xor(ts, 32);
      lrun = lrun * alpha + ts;
      mrun = mnew;
      float ar[4];
      #pragma unroll
      for (int r = 0; r < 4; ++r) ar[r] = __shfl(alpha, 4*grp + r, 64);
      #pragma unroll
      for (int dt = 0; dt < 4; ++dt) {
        yacc[dt][0] *= ar[0]; yacc[dt][1] *= ar[1];
        yacc[dt][2] *= ar[2]; yacc[dt][3] *= ar[3];
      }
      #pragma unroll
      for (int st = 0; st < 4; ++st) {
        uint2 v;
        v.x = (uint)pb[st*4+0] | ((uint)pb[st*4+1] << 16);
        v.y = (uint)pb[st*4+2] | ((uint)pb[st*4+3] << 16);
        *(uint2*)&psw[q16*72 + 16*st + 4*grp] = v;
      }
      __threadfence_block();
      __builtin_amdgcn_sched_barrier(0);
      #pragma unroll
      for (int ks = 0; ks < 2; ++ks) {
        bf16x8 pa = *(const bf16x8*)&psw[q16*72 + 32*ks + colb];
        #pragma unroll
        for (int dt = 0; dt < 4; ++dt) {
          int row = 16*dt + q16;
          int off = row * 64 + (((4*ks + grp) ^ (row & 7)) << 3);
          bf16x8 ub = *(const bf16x8*)&Ush[cur][off];
          yacc[dt] = __builtin_amdgcn_mfma_f32_16x16x32_bf16(pa, ub, yacc[dt], 0,0,0);
        }
      }
    }
    __syncthreads();   // drains next-tile loads (covered by compute); tile swap
    cur ^= 1;
  }
  if (grp == 0) {
    Pm[c * NCTX + q] = mrun;
    Pl[c * NCTX + q] = lrun;
  }
  #pragma unroll
  for (int dt = 0; dt < 4; ++dt)
    #pragma unroll
    for (int r = 0; r < 4; ++r)
      Py[(c * NCTX + q0 + 4*grp + r) * DH + 16*dt + q16] = yacc[dt][r];
}

// ---------------- epilogue: combine fused + out = Y @ W_vT --------------------
// combine math identical (same c-order accumulation; final *1/den vs /den <=1ulp).
__global__ __launch_bounds__(256) void out_kernel(
    const float* __restrict__ Pm, const float* __restrict__ Pl,
    const float* __restrict__ Py, const float* __restrict__ Wv,
    float* __restrict__ out)
{
  __shared__ float Ws[64][256];
  __shared__ float YsT[64][64];
  __shared__ float sden[NCH][64];
  __shared__ float invd[64];
  const int tid = threadIdx.x;
  const int r0  = blockIdx.x * 64;
  const int cb  = blockIdx.y;
  const int c4  = tid & 63;
  const int rg  = __builtin_amdgcn_readfirstlane(tid >> 6);

  // phase A: per-row combine scales (validated combine math)
  if (tid < 64) {
    int rrow = r0 + tid;
    float mv[NCH]; float M = -3.0e38f;
    #pragma unroll
    for (int c = 0; c < NCH; ++c) {
      mv[c] = Pm[c*NCTX + rrow];
      M = fmaxf(M, mv[c]);
    }
    float den = 0.f;
    #pragma unroll
    for (int c = 0; c < NCH; ++c) {
      float s = __expf(mv[c] - M);
      sden[c][tid] = s;
      den += s * Pl[c*NCTX + rrow];
    }
    invd[tid] = 1.0f / den;
  }
  #pragma unroll
  for (int it = 0; it < 16; ++it) {
    int idx = it * 256 + tid;
    int h = idx >> 6, cc = idx & 63;
    *(float4*)&Ws[h][cc * 4] = *(const float4*)&Wv[h * DM + cb * 256 + cc * 4];
  }
  __syncthreads();

  // build Y tile from split-K partials
  #pragma unroll
  for (int it = 0; it < 4; ++it) {
    int idx = it * 256 + tid;
    int h4 = idx & 15, rr = idx >> 4;
    int rrow = r0 + rr;
    float nx = 0.f, ny = 0.f, nz = 0.f, nw = 0.f;
    #pragma unroll
    for (int c = 0; c < NCH; ++c) {
      float s = sden[c][rr];
      float4 p4 = *(const float4*)&Py[(c*NCTX + rrow)*DH + h4*4];
      nx += s*p4.x; ny += s*p4.y; nz += s*p4.z; nw += s*p4.w;
    }
    float inv = invd[rr];
    YsT[h4*4+0][rr] = nx*inv; YsT[h4*4+1][rr] = ny*inv;
    YsT[h4*4+2][rr] = nz*inv; YsT[h4*4+3][rr] = nw*inv;
  }
  __syncthreads();

  float4 acc[16];
  #pragma unroll
  for (int i = 0; i < 16; ++i) acc[i] = make_float4(0.f, 0.f, 0.f, 0.f);

  #pragma unroll 8
  for (int h = 0; h < 64; ++h) {
    float4 w4 = *(const float4*)&Ws[h][c4 * 4];
    #pragma unroll
    for (int gq = 0; gq < 4; ++gq) {
      float4 y4 = *(const float4*)&YsT[h][rg * 16 + gq * 4];
      float ys[4] = {y4.x, y4.y, y4.z, y4.w};
      #pragma unroll
      for (int e = 0; e < 4; ++e) {
        acc[gq*4+e].x += ys[e] * w4.x;
        acc[gq*4+e].y += ys[e] * w4.y;
        acc[gq*4+e].z += ys[e] * w4.z;
        acc[gq*4+e].w += ys[e] * w4.w;
      }
    }
  }
  #pragma unroll
  for (int i = 0; i < 16; ++i)
    *(float4*)&out[(r0 + rg * 16 + i) * DM + cb * 256 + c4 * 4] = acc[i];
}

extern "C" void kernel_launch(void* const* d_in, const int* in_sizes, int n_in,
                              void* d_out, int out_size, void* d_ws, size_t ws_size,
                              hipStream_t stream) {
  const float* x   = (const float*)d_in[0];
  const float* Wq  = (const float*)d_in[1];
  const float* WkT = (const float*)d_in[2];
  const float* Wo  = (const float*)d_in[3];
  const float* Wv  = (const float*)d_in[4];
  float* out = (float*)d_out;
  char*  ob  = (char*)d_out;   // scratch; fully overwritten by out_kernel

  ushort* Qhp = (ushort*)(ob + D_QH);
  ushort* Qmp = (ushort*)(ob + D_QM);
  ushort* Qlp = (ushort*)(ob + D_QL);
  ushort* Khp = (ushort*)(ob + D_KH);
  ushort* Kmp = (ushort*)(ob + D_KM);
  ushort* Klp = (ushort*)(ob + D_KL);
  ushort* UTb = (ushort*)(ob + D_UTB);
  float*  Pyp = (float*)(ob + D_PY);
  float*  Pmp = (float*)(ob + D_PM);
  float*  Plp = (float*)(ob + D_PL);
  ushort* WTh = (ushort*)(ob + D_WTH);
  ushort* WTm = (ushort*)(ob + D_WTM);

  hipLaunchKernelGGL(wsplit_kernel, dim3(768), dim3(256), 0, stream,
                     Wq, WkT, Wo, WTh, WTm);
  hipLaunchKernelGGL(proj_mfma_kernel, dim3(128, 3), dim3(256), 0, stream,
                     x, WTh, WTm, Qhp, Qmp, Qlp, Khp, Kmp, Klp, UTb);
  hipLaunchKernelGGL(attn_kernel, dim3(64, 8), dim3(256), 0, stream,
                     Qhp, Qmp, Qlp, Khp, Kmp, Klp, UTb, Pmp, Plp, Pyp);
  hipLaunchKernelGGL(out_kernel, dim3(64, 4), dim3(256), 0, stream,
                     Pmp, Plp, Pyp, Wv, out);
}

// Round 20
// 62.623 us; speedup vs baseline: 2.2867x; 1.0752x over previous
//
#include <hip/hip_runtime.h>
#include <hip/hip_bf16.h>
#include <math.h>

#define DM    1024
#define DH    64
#define NCTX  4096
#define NCH   8        // key-chunks per q-group

typedef __attribute__((ext_vector_type(8))) short bf16x8;
typedef __attribute__((ext_vector_type(4))) float f32x4;

// ---- d_out scratch (16 MiB): written by wsplit/proj/attn, all consumed before
// out_mfma runs; out_mfma reads ONLY d_ws (race-free) and overwrites d_out.
#define D_QH   0
#define D_QM   524288
#define D_QL   1048576
#define D_KH   1572864
#define D_KM   2097152
#define D_KL   2621440
#define D_UTB  3145728
#define D_PY   3670016
#define D_PM   12058624
#define D_PL   12189696
#define D_WTH  12320768
#define D_WTM  12713984   // end 13107200

// ---- d_ws (proven 4,456,448 B): ONLY memory the final kernel reads.
#define S_YH   0          // 512 KiB bf16 Y high digit [NCTX][DH]
#define S_YM   524288     // 512 KiB bf16 Y mid digit
#define S_WVH  1048576    // 128 KiB bf16 WvT^t high [1024][64]
#define S_WVM  1179648    // 128 KiB (end 1310720 < 4456448)

__device__ __forceinline__ ushort f2bf(float x) {
  __hip_bfloat16 h = __float2bfloat16(x);
  return __builtin_bit_cast(ushort, h);
}
__device__ __forceinline__ float bf2f(ushort u) {
  __hip_bfloat16 h = __builtin_bit_cast(__hip_bfloat16, u);
  return __bfloat162float(h);
}

// async global->LDS, 16B/lane: LDS dest wave-uniform base + lane*16;
// global src per-lane (pre-swizzled source, linear LDS dest -- rule #21).
typedef __attribute__((address_space(1))) const unsigned int gas_u32;
typedef __attribute__((address_space(3))) unsigned int las_u32;
__device__ __forceinline__ void gload_lds16(const void* g, void* l) {
  __builtin_amdgcn_global_load_lds((gas_u32*)g, (las_u32*)l, 16, 0, 0);
}

// ---------------- W -> WT digit split (validated; mat3 = Wv -> ws) ----------------
__global__ __launch_bounds__(256) void wsplit_kernel(
    const float* __restrict__ Wq, const float* __restrict__ WkT,
    const float* __restrict__ Wo, const float* __restrict__ Wv,
    ushort* __restrict__ WTh, ushort* __restrict__ WTm,
    ushort* __restrict__ WvTh, ushort* __restrict__ WvTm)
{
  int gid = blockIdx.x * 256 + threadIdx.x;
  int mat = gid >> 16;
  int idx = gid & 65535;
  if (mat == 3) {
    float v = Wv[idx];                 // Wv[h][c], coalesced read
    int h = idx >> 10, c = idx & 1023;
    int oidx = c * 64 + h;             // WvT^t[c][h]
    ushort h16 = f2bf(v);
    WvTh[oidx] = h16;
    WvTm[oidx] = f2bf(v - bf2f(h16));
    return;
  }
  float v; int oidx;
  if (mat == 1) {
    v = WkT[idx];
    oidx = 65536 + idx;
  } else {
    int k = idx >> 6, h = idx & 63;
    v = (mat == 0 ? Wq : Wo)[idx];
    oidx = mat * 65536 + h * 1024 + k;
  }
  ushort h16 = f2bf(v);
  float rem = v - bf2f(h16);
  WTh[oidx] = h16;
  WTm[oidx] = f2bf(rem);
}

// ---------------- projections via MFMA: 2-phase pipelined (r18-validated) ------
__global__ __launch_bounds__(256, 2) void proj_mfma_kernel(
    const float* __restrict__ x,
    const ushort* __restrict__ WTh, const ushort* __restrict__ WTm,
    ushort* __restrict__ Qh, ushort* __restrict__ Qm, ushort* __restrict__ Ql,
    ushort* __restrict__ Kh, ushort* __restrict__ Km, ushort* __restrict__ Kl,
    ushort* __restrict__ UTb)
{
  __shared__ __align__(16) ushort xsh[32*128], xsm[32*128];
  __shared__ __align__(16) ushort wsh[2][64*128], wsm[2][64*128];

  const int tid  = threadIdx.x;
  const int lane = tid & 63;
  const int w    = tid >> 6;
  const int q16  = lane & 15;
  const int grp  = lane >> 4;
  const int r0   = blockIdx.x * 32;
  const int mat  = blockIdx.y;
  const ushort* __restrict__ wh = WTh + mat * 65536;
  const ushort* __restrict__ wm = WTm + mat * 65536;

  const int rw  = (w & 1) * 16;
  const int ct0 = (w >> 1) * 2;

  const int xrowl = tid >> 4, xslot = tid & 15;

  auto stage_w = [&](int b, int s) {
    const int kp0 = s * 128;
    #pragma unroll
    for (int u = 0; u < 4; ++u) {
      int ubase = u * 256 + w * 64;
      int unit  = ubase + lane;
      int row   = unit >> 4, slotp = unit & 15;
      int ssrc  = slotp ^ (row & 15);
      int gsrc  = row * DM + kp0 + ssrc * 8;
      gload_lds16(&wh[gsrc], &wsh[b][ubase * 8]);
      gload_lds16(&wm[gsrc], &wsm[b][ubase * 8]);
    }
  };
  auto xload = [&](int s, float4& a0, float4& a1, float4& b0, float4& b1) {
    const int kp0 = s * 128;
    const float* s0 = &x[(r0 + xrowl) * DM + kp0 + xslot * 8];
    const float* s1 = &x[(r0 + xrowl + 16) * DM + kp0 + xslot * 8];
    a0 = *(const float4*)&s0[0]; a1 = *(const float4*)&s0[4];
    b0 = *(const float4*)&s1[0]; b1 = *(const float4*)&s1[4];
  };
  auto xsplit_write = [&](float4 a0, float4 a1, float4 b0, float4 b1) {
    float xv0[8] = {a0.x,a0.y,a0.z,a0.w,a1.x,a1.y,a1.z,a1.w};
    float xv1[8] = {b0.x,b0.y,b0.z,b0.w,b1.x,b1.y,b1.z,b1.w};
    bf16x8 hv0, mv0, hv1, mv1;
    #pragma unroll
    for (int e = 0; e < 8; ++e) {
      ushort h0 = f2bf(xv0[e]);
      hv0[e] = (short)h0;  mv0[e] = (short)f2bf(xv0[e] - bf2f(h0));
      ushort h1 = f2bf(xv1[e]);
      hv1[e] = (short)h1;  mv1[e] = (short)f2bf(xv1[e] - bf2f(h1));
    }
    int d0 = xrowl * 128 + ((xslot ^ (xrowl & 15)) << 3);
    int r1 = xrowl + 16;
    int d1 = r1 * 128 + ((xslot ^ (r1 & 15)) << 3);
    *(bf16x8*)&xsh[d0] = hv0;  *(bf16x8*)&xsm[d0] = mv0;
    *(bf16x8*)&xsh[d1] = hv1;  *(bf16x8*)&xsm[d1] = mv1;
  };

  f32x4 acc[2] = {{0,0,0,0},{0,0,0,0}};

  {
    float4 a0, a1, b0, b1;
    xload(0, a0, a1, b0, b1);
    xsplit_write(a0, a1, b0, b1);
    stage_w(0, 0);
  }
  __syncthreads();

  int cur = 0;
  for (int stg = 0; stg < 8; ++stg) {
    float4 na0, na1, nb0, nb1;
    if (stg < 7) {
      xload(stg + 1, na0, na1, nb0, nb1);
      stage_w(cur ^ 1, stg + 1);
    }
    #pragma unroll
    for (int ksub = 0; ksub < 4; ++ksub) {
      const int s = ksub * 4 + grp;
      const int xrow = rw + q16;
      bf16x8 xh8 = *(const bf16x8*)&xsh[xrow * 128 + ((s ^ (xrow & 15)) << 3)];
      bf16x8 xm8 = *(const bf16x8*)&xsm[xrow * 128 + ((s ^ (xrow & 15)) << 3)];
      #pragma unroll
      for (int i = 0; i < 2; ++i) {
        const int wrow = (ct0 + i) * 16 + q16;
        const int woff = wrow * 128 + ((s ^ (wrow & 15)) << 3);
        bf16x8 bh = *(const bf16x8*)&wsh[cur][woff];
        bf16x8 bm = *(const bf16x8*)&wsm[cur][woff];
        if (mat == 2) {
          acc[i] = __builtin_amdgcn_mfma_f32_16x16x32_bf16(bh, xh8, acc[i], 0,0,0);
          acc[i] = __builtin_amdgcn_mfma_f32_16x16x32_bf16(bh, xm8, acc[i], 0,0,0);
          acc[i] = __builtin_amdgcn_mfma_f32_16x16x32_bf16(bm, xh8, acc[i], 0,0,0);
          acc[i] = __builtin_amdgcn_mfma_f32_16x16x32_bf16(bm, xm8, acc[i], 0,0,0);
        } else {
          acc[i] = __builtin_amdgcn_mfma_f32_16x16x32_bf16(xh8, bh, acc[i], 0,0,0);
          acc[i] = __builtin_amdgcn_mfma_f32_16x16x32_bf16(xh8, bm, acc[i], 0,0,0);
          acc[i] = __builtin_amdgcn_mfma_f32_16x16x32_bf16(xm8, bh, acc[i], 0,0,0);
          acc[i] = __builtin_amdgcn_mfma_f32_16x16x32_bf16(xm8, bm, acc[i], 0,0,0);
        }
      }
    }
    __syncthreads();
    if (stg < 7) xsplit_write(na0, na1, nb0, nb1);
    __syncthreads();
    cur ^= 1;
  }

  if (mat == 2) {
    #pragma unroll
    for (int i = 0; i < 2; ++i)
      #pragma unroll
      for (int r = 0; r < 4; ++r)
        UTb[((ct0 + i)*16 + 4*grp + r) * NCTX + r0 + rw + q16] = f2bf(acc[i][r]);
  } else {
    ushort* __restrict__ Dh = (mat == 0) ? Qh : Kh;
    ushort* __restrict__ Dm = (mat == 0) ? Qm : Km;
    ushort* __restrict__ Dl = (mat == 0) ? Ql : Kl;
    #pragma unroll
    for (int i = 0; i < 2; ++i)
      #pragma unroll
      for (int r = 0; r < 4; ++r) {
        float v = acc[i][r];
        ushort h = f2bf(v); float fh = bf2f(h);
        ushort m = f2bf(v - fh); float fm = bf2f(m);
        ushort l = f2bf(v - fh - fm);
        int idx = (r0 + rw + 4*grp + r) * DH + (ct0 + i)*16 + q16;
        Dh[idx] = h; Dm[idx] = m; Dl[idx] = l;
      }
  }
}

// ---------------- MFMA flash attention: 2-phase double-buffered (r18-validated) --
__global__ __launch_bounds__(256, 2) void attn_kernel(
    const ushort* __restrict__ Qh, const ushort* __restrict__ Qm, const ushort* __restrict__ Ql,
    const ushort* __restrict__ Kh, const ushort* __restrict__ Km, const ushort* __restrict__ Kl,
    const ushort* __restrict__ UTb,
    float* __restrict__ Pm, float* __restrict__ Pl, float* __restrict__ Py)
{
  __shared__ ushort Ksh[2][3][64*64];
  __shared__ ushort Ush[2][64*64];
  __shared__ __align__(16) ushort ps[4][16*72];

  const int tid  = threadIdx.x;
  const int lane = tid & 63;
  const int w    = tid >> 6;
  ushort* psw = ps[w];
  const int q16  = lane & 15;
  const int grp  = lane >> 4;
  const int colb = grp * 8;

  const int qq    = blockIdx.x;
  const int c     = blockIdx.y;
  const int gbase = 252 - 4 * qq;
  const int g     = gbase + w;
  const int gmax  = gbase + 3;
  const int T     = ((16*gmax + 15) >> 6) + 1;
  const int t0 = (c * T) >> 3, t1 = ((c+1) * T) >> 3;
  const int Town = ((16*g + 15) >> 6) + 1;
  const int q0 = 16 * g;
  const int q  = q0 + q16;

  auto stage = [&](int b, int t) {
    const int j0 = t * 64;
    #pragma unroll
    for (int it = 0; it < 2; ++it) {
      int ubase = it * 256 + w * 64;
      int unit  = ubase + lane;
      int row   = unit >> 3, slotp = unit & 7;
      int c8    = slotp ^ (row & 7);
      int src   = (j0 + row) * DH + c8 * 8;
      gload_lds16(&Kh[src], &Ksh[b][0][ubase * 8]);
      gload_lds16(&Km[src], &Ksh[b][1][ubase * 8]);
      gload_lds16(&Kl[src], &Ksh[b][2][ubase * 8]);
      gload_lds16(&UTb[row * NCTX + j0 + c8 * 8], &Ush[b][ubase * 8]);
    }
  };

  bf16x8 fqh[2], fqm[2], fql[2];
  #pragma unroll
  for (int ks = 0; ks < 2; ++ks) {
    int off = (q0 + q16)*DH + 32*ks + colb;
    fqh[ks] = *(const bf16x8*)&Qh[off];
    fqm[ks] = *(const bf16x8*)&Qm[off];
    fql[ks] = *(const bf16x8*)&Ql[off];
  }

  float mrun = -3.0e38f, lrun = 0.f;
  f32x4 yacc[4] = {{0,0,0,0},{0,0,0,0},{0,0,0,0},{0,0,0,0}};

  if (t0 < t1) stage(0, t0);
  __syncthreads();

  int cur = 0;
  for (int t = t0; t < t1; ++t) {
    if (t + 1 < t1) stage(cur ^ 1, t + 1);
    if (t < Town) {
      const int j0 = t * 64;
      f32x4 sa[4] = {{0,0,0,0},{0,0,0,0},{0,0,0,0},{0,0,0,0}};
      #pragma unroll
      for (int ks = 0; ks < 2; ++ks) {
        #pragma unroll
        for (int st = 0; st < 4; ++st) {
          int row = 16*st + q16;
          int off = row * 64 + (((4*ks + grp) ^ (row & 7)) << 3);
          bf16x8 kh = *(const bf16x8*)&Ksh[cur][0][off];
          bf16x8 km = *(const bf16x8*)&Ksh[cur][1][off];
          bf16x8 kl = *(const bf16x8*)&Ksh[cur][2][off];
          sa[st] = __builtin_amdgcn_mfma_f32_16x16x32_bf16(kh, fqh[ks], sa[st], 0,0,0);
          sa[st] = __builtin_amdgcn_mfma_f32_16x16x32_bf16(kh, fqm[ks], sa[st], 0,0,0);
          sa[st] = __builtin_amdgcn_mfma_f32_16x16x32_bf16(km, fqh[ks], sa[st], 0,0,0);
          sa[st] = __builtin_amdgcn_mfma_f32_16x16x32_bf16(km, fqm[ks], sa[st], 0,0,0);
          sa[st] = __builtin_amdgcn_mfma_f32_16x16x32_bf16(kh, fql[ks], sa[st], 0,0,0);
          sa[st] = __builtin_amdgcn_mfma_f32_16x16x32_bf16(kl, fqh[ks], sa[st], 0,0,0);
        }
      }
      #pragma unroll
      for (int st = 0; st < 4; ++st)
        #pragma unroll
        for (int r = 0; r < 4; ++r) {
          int key = j0 + 16*st + 4*grp + r;
          if (key > q) sa[st][r] = -3.0e38f;
        }
      float mx = sa[0][0];
      #pragma unroll
      for (int st = 0; st < 4; ++st)
        #pragma unroll
        for (int r = 0; r < 4; ++r) mx = fmaxf(mx, sa[st][r]);
      mx = fmaxf(mx, __shfl_xor(mx, 16));
      mx = fmaxf(mx, __shfl_xor(mx, 32));
      float mnew  = fmaxf(mrun, mx);
      float alpha = __expf(mrun - mnew);
      float ts = 0.f;
      ushort pb[16];
      #pragma unroll
      for (int st = 0; st < 4; ++st)
        #pragma unroll
        for (int r = 0; r < 4; ++r) {
          float p = __expf(sa[st][r] - mnew);
          ts += p;
          pb[st*4 + r] = f2bf(p);
        }
      ts += __shfl_xor(ts, 16);
      ts += __shfl_xor(ts, 32);
      lrun = lrun * alpha + ts;
      mrun = mnew;
      float ar[4];
      #pragma unroll
      for (int r = 0; r < 4; ++r) ar[r] = __shfl(alpha, 4*grp + r, 64);
      #pragma unroll
      for (int dt = 0; dt < 4; ++dt) {
        yacc[dt][0] *= ar[0]; yacc[dt][1] *= ar[1];
        yacc[dt][2] *= ar[2]; yacc[dt][3] *= ar[3];
      }
      #pragma unroll
      for (int st = 0; st < 4; ++st) {
        uint2 v;
        v.x = (uint)pb[st*4+0] | ((uint)pb[st*4+1] << 16);
        v.y = (uint)pb[st*4+2] | ((uint)pb[st*4+3] << 16);
        *(uint2*)&psw[q16*72 + 16*st + 4*grp] = v;
      }
      __threadfence_block();
      __builtin_amdgcn_sched_barrier(0);
      #pragma unroll
      for (int ks = 0; ks < 2; ++ks) {
        bf16x8 pa = *(const bf16x8*)&psw[q16*72 + 32*ks + colb];
        #pragma unroll
        for (int dt = 0; dt < 4; ++dt) {
          int row = 16*dt + q16;
          int off = row * 64 + (((4*ks + grp) ^ (row & 7)) << 3);
          bf16x8 ub = *(const bf16x8*)&Ush[cur][off];
          yacc[dt] = __builtin_amdgcn_mfma_f32_16x16x32_bf16(pa, ub, yacc[dt], 0,0,0);
        }
      }
    }
    __syncthreads();
    cur ^= 1;
  }
  if (grp == 0) {
    Pm[c * NCTX + q] = mrun;
    Pl[c * NCTX + q] = lrun;
  }
  #pragma unroll
  for (int dt = 0; dt < 4; ++dt)
    #pragma unroll
    for (int r = 0; r < 4; ++r)
      Py[(c * NCTX + q0 + 4*grp + r) * DH + 16*dt + q16] = yacc[dt][r];
}

// ---------------- combine: partials -> Y digit arrays in ws (race-free) --------
// Math = r9-r17-validated combine + proj-validated 2-digit split.
// Reads d_out scratch, writes ONLY ws.
__global__ __launch_bounds__(256) void combine_kernel(
    const float* __restrict__ Pm, const float* __restrict__ Pl,
    const float* __restrict__ Py,
    ushort* __restrict__ Yh, ushort* __restrict__ Ym)
{
  int idx = blockIdx.x * 256 + threadIdx.x;   // 0..262143
  int r = idx >> 6, d = idx & 63;
  float mv[NCH];
  float M = -3.0e38f;
  #pragma unroll
  for (int c = 0; c < NCH; ++c) {
    mv[c] = Pm[c*NCTX + r];
    M = fmaxf(M, mv[c]);
  }
  float num = 0.f, den = 0.f;
  #pragma unroll
  for (int c = 0; c < NCH; ++c) {
    float s = __expf(mv[c] - M);
    den += s * Pl[c*NCTX + r];
    num += s * Py[(c*NCTX + r)*DH + d];
  }
  float y = num / den;
  ushort h = f2bf(y);
  Yh[idx] = h;
  Ym[idx] = f2bf(y - bf2f(h));
}

// ---------------- epilogue: out = Y @ W_vT via MFMA (reads ws ONLY) ------------
// Grid (64 row-tiles, 8 col-tiles of 128), 256 thr. MFMA phase identical to the
// r19 version whose launch_once output was correct (absmax 20.25).
__global__ __launch_bounds__(256, 3) void out_mfma_kernel(
    const ushort* __restrict__ Yh_g, const ushort* __restrict__ Ym_g,
    const ushort* __restrict__ WvTh, const ushort* __restrict__ WvTm,
    float* __restrict__ out)
{
  __shared__ __align__(16) ushort Yh[64*64], Ym[64*64];     // 8 KiB each
  __shared__ __align__(16) ushort Wsh[128*64], Wsm[128*64]; // 16 KiB each

  const int tid  = threadIdx.x;
  const int lane = tid & 63;
  const int w    = tid >> 6;
  const int q16  = lane & 15;
  const int grp  = lane >> 4;
  const int r0   = blockIdx.x * 64;
  const int cb   = blockIdx.y;          // 0..7 (128 cols each)

  // stage Y digit tile [64 rows][64 h] (pre-swizzled source, linear dest)
  #pragma unroll
  for (int it = 0; it < 2; ++it) {
    int ubase = it * 256 + w * 64;      // wave-uniform
    int unit  = ubase + lane;
    int row   = unit >> 3, slotp = unit & 7;
    int c8    = slotp ^ (row & 7);
    int src   = (r0 + row) * 64 + c8 * 8;
    gload_lds16(&Yh_g[src], &Yh[ubase * 8]);
    gload_lds16(&Ym_g[src], &Ym[ubase * 8]);
  }
  // stage WvT^t[cb*128 .. +127][64] digits
  #pragma unroll
  for (int u = 0; u < 4; ++u) {
    int ubase = u * 256 + w * 64;
    int unit  = ubase + lane;
    int row   = unit >> 3, slotp = unit & 7;
    int c8    = slotp ^ (row & 7);
    int src   = (cb * 128 + row) * 64 + c8 * 8;
    gload_lds16(&WvTh[src], &Wsh[ubase * 8]);
    gload_lds16(&WvTm[src], &Wsm[ubase * 8]);
  }
  __syncthreads();   // drains all async LDS writes

  // MFMA: D[row = 16rt+4grp+r][col = w*32 + lt*16 + q16] (r19-validated phase)
  f32x4 acc[4][2] = {};
  #pragma unroll
  for (int ks = 0; ks < 2; ++ks) {
    bf16x8 ah[4], am[4];
    #pragma unroll
    for (int rt = 0; rt < 4; ++rt) {
      int row = 16*rt + q16;
      int off = row*64 + (((4*ks + grp) ^ (row & 7)) << 3);
      ah[rt] = *(const bf16x8*)&Yh[off];
      am[rt] = *(const bf16x8*)&Ym[off];
    }
    #pragma unroll
    for (int lt = 0; lt < 2; ++lt) {
      int crow = w*32 + lt*16 + q16;    // local col 0..127
      int off  = crow*64 + (((4*ks + grp) ^ (crow & 7)) << 3);
      bf16x8 bh = *(const bf16x8*)&Wsh[off];
      bf16x8 bm = *(const bf16x8*)&Wsm[off];
      #pragma unroll
      for (int rt = 0; rt < 4; ++rt) {
        acc[rt][lt] = __builtin_amdgcn_mfma_f32_16x16x32_bf16(ah[rt], bh, acc[rt][lt], 0,0,0);
        acc[rt][lt] = __builtin_amdgcn_mfma_f32_16x16x32_bf16(ah[rt], bm, acc[rt][lt], 0,0,0);
        acc[rt][lt] = __builtin_amdgcn_mfma_f32_16x16x32_bf16(am[rt], bh, acc[rt][lt], 0,0,0);
        acc[rt][lt] = __builtin_amdgcn_mfma_f32_16x16x32_bf16(am[rt], bm, acc[rt][lt], 0,0,0);
      }
    }
  }
  #pragma unroll
  for (int rt = 0; rt < 4; ++rt)
    #pragma unroll
    for (int lt = 0; lt < 2; ++lt)
      #pragma unroll
      for (int r = 0; r < 4; ++r)
        out[(r0 + 16*rt + 4*grp + r) * DM + cb*128 + w*32 + lt*16 + q16] = acc[rt][lt][r];
}

extern "C" void kernel_launch(void* const* d_in, const int* in_sizes, int n_in,
                              void* d_out, int out_size, void* d_ws, size_t ws_size,
                              hipStream_t stream) {
  const float* x   = (const float*)d_in[0];
  const float* Wq  = (const float*)d_in[1];
  const float* WkT = (const float*)d_in[2];
  const float* Wo  = (const float*)d_in[3];
  const float* Wv  = (const float*)d_in[4];
  float* out = (float*)d_out;
  char*  ob  = (char*)d_out;   // scratch until out_mfma overwrites it
  char*  wb  = (char*)d_ws;    // race-free scratch for the final kernel

  ushort* Qhp = (ushort*)(ob + D_QH);
  ushort* Qmp = (ushort*)(ob + D_QM);
  ushort* Qlp = (ushort*)(ob + D_QL);
  ushort* Khp = (ushort*)(ob + D_KH);
  ushort* Kmp = (ushort*)(ob + D_KM);
  ushort* Klp = (ushort*)(ob + D_KL);
  ushort* UTb = (ushort*)(ob + D_UTB);
  float*  Pyp = (float*)(ob + D_PY);
  float*  Pmp = (float*)(ob + D_PM);
  float*  Plp = (float*)(ob + D_PL);
  ushort* WTh = (ushort*)(ob + D_WTH);
  ushort* WTm = (ushort*)(ob + D_WTM);

  ushort* Yhp  = (ushort*)(wb + S_YH);
  ushort* Ymp  = (ushort*)(wb + S_YM);
  ushort* WvTh = (ushort*)(wb + S_WVH);
  ushort* WvTm = (ushort*)(wb + S_WVM);

  hipLaunchKernelGGL(wsplit_kernel, dim3(1024), dim3(256), 0, stream,
                     Wq, WkT, Wo, Wv, WTh, WTm, WvTh, WvTm);
  hipLaunchKernelGGL(proj_mfma_kernel, dim3(128, 3), dim3(256), 0, stream,
                     x, WTh, WTm, Qhp, Qmp, Qlp, Khp, Kmp, Klp, UTb);
  hipLaunchKernelGGL(attn_kernel, dim3(64, 8), dim3(256), 0, stream,
                     Qhp, Qmp, Qlp, Khp, Kmp, Klp, UTb, Pmp, Plp, Pyp);
  hipLaunchKernelGGL(combine_kernel, dim3(1024), dim3(256), 0, stream,
                     Pmp, Plp, Pyp, Yhp, Ymp);
  hipLaunchKernelGGL(out_mfma_kernel, dim3(64, 8), dim3(256), 0, stream,
                     Yhp, Ymp, WvTh, WvTm, out);
}

// Round 21
// 58.479 us; speedup vs baseline: 2.4487x; 1.0709x over previous
//
#include <hip/hip_runtime.h>
#include <hip/hip_bf16.h>
#include <math.h>

#define DM    1024
#define DH    64
#define NCTX  4096
#define NCH   8        // key-chunks per q-group

typedef __attribute__((ext_vector_type(8))) short bf16x8;
typedef __attribute__((ext_vector_type(4))) float f32x4;

// ---- d_out scratch (16 MiB): written by wsplit/proj, consumed by proj/attn;
// the final kernel reads ONLY d_ws and overwrites d_out (race-free).
#define D_QH   0
#define D_QM   524288
#define D_QL   1048576
#define D_KH   1572864
#define D_KM   2097152
#define D_KL   2621440
#define D_UTB  3145728
#define D_PY   3670016    // fallback-path partials live here
#define D_PM   12058624
#define D_PL   12189696
#define D_WTH  12320768
#define D_WTM  12713984   // end 13107200

// ---- d_ws layout. WvT digits always at 0. Primary path (ws >= 8.5 MiB,
// evidenced by 256 MiB poison fills): partials in ws -> fused combine+out.
#define S_WVH  0          // 128 KiB bf16 WvT^t high [1024][64]
#define S_WVM  131072     // 128 KiB
#define S_PM   262144     // 128 KiB f32 [NCH][NCTX]
#define S_PL   393216     // 128 KiB
#define S_PY   524288     // 8 MiB f32 [NCH][NCTX][DH]
#define S_END  8912896
// Fallback path (r20-proven): Y digit arrays in ws
#define S_YH   262144     // 512 KiB
#define S_YM   786432     // 512 KiB (end 1310720 < 4456448 proven)

__device__ __forceinline__ ushort f2bf(float x) {
  __hip_bfloat16 h = __float2bfloat16(x);
  return __builtin_bit_cast(ushort, h);
}
__device__ __forceinline__ float bf2f(ushort u) {
  __hip_bfloat16 h = __builtin_bit_cast(__hip_bfloat16, u);
  return __bfloat162float(h);
}

// async global->LDS, 16B/lane: LDS dest wave-uniform base + lane*16;
// global src per-lane (pre-swizzled source, linear LDS dest -- rule #21).
typedef __attribute__((address_space(1))) const unsigned int gas_u32;
typedef __attribute__((address_space(3))) unsigned int las_u32;
__device__ __forceinline__ void gload_lds16(const void* g, void* l) {
  __builtin_amdgcn_global_load_lds((gas_u32*)g, (las_u32*)l, 16, 0, 0);
}

// ---------------- W -> WT digit split (r20-validated, unchanged) ----------------
__global__ __launch_bounds__(256) void wsplit_kernel(
    const float* __restrict__ Wq, const float* __restrict__ WkT,
    const float* __restrict__ Wo, const float* __restrict__ Wv,
    ushort* __restrict__ WTh, ushort* __restrict__ WTm,
    ushort* __restrict__ WvTh, ushort* __restrict__ WvTm)
{
  int gid = blockIdx.x * 256 + threadIdx.x;
  int mat = gid >> 16;
  int idx = gid & 65535;
  if (mat == 3) {
    float v = Wv[idx];                 // Wv[h][c], coalesced read
    int h = idx >> 10, c = idx & 1023;
    int oidx = c * 64 + h;             // WvT^t[c][h]
    ushort h16 = f2bf(v);
    WvTh[oidx] = h16;
    WvTm[oidx] = f2bf(v - bf2f(h16));
    return;
  }
  float v; int oidx;
  if (mat == 1) {
    v = WkT[idx];
    oidx = 65536 + idx;
  } else {
    int k = idx >> 6, h = idx & 63;
    v = (mat == 0 ? Wq : Wo)[idx];
    oidx = mat * 65536 + h * 1024 + k;
  }
  ushort h16 = f2bf(v);
  float rem = v - bf2f(h16);
  WTh[oidx] = h16;
  WTm[oidx] = f2bf(rem);
}

// ---------------- projections via MFMA: 2-phase pipelined (r20-validated) ------
__global__ __launch_bounds__(256, 2) void proj_mfma_kernel(
    const float* __restrict__ x,
    const ushort* __restrict__ WTh, const ushort* __restrict__ WTm,
    ushort* __restrict__ Qh, ushort* __restrict__ Qm, ushort* __restrict__ Ql,
    ushort* __restrict__ Kh, ushort* __restrict__ Km, ushort* __restrict__ Kl,
    ushort* __restrict__ UTb)
{
  __shared__ __align__(16) ushort xsh[32*128], xsm[32*128];
  __shared__ __align__(16) ushort wsh[2][64*128], wsm[2][64*128];

  const int tid  = threadIdx.x;
  const int lane = tid & 63;
  const int w    = tid >> 6;
  const int q16  = lane & 15;
  const int grp  = lane >> 4;
  const int r0   = blockIdx.x * 32;
  const int mat  = blockIdx.y;
  const ushort* __restrict__ wh = WTh + mat * 65536;
  const ushort* __restrict__ wm = WTm + mat * 65536;

  const int rw  = (w & 1) * 16;
  const int ct0 = (w >> 1) * 2;

  const int xrowl = tid >> 4, xslot = tid & 15;

  auto stage_w = [&](int b, int s) {
    const int kp0 = s * 128;
    #pragma unroll
    for (int u = 0; u < 4; ++u) {
      int ubase = u * 256 + w * 64;
      int unit  = ubase + lane;
      int row   = unit >> 4, slotp = unit & 15;
      int ssrc  = slotp ^ (row & 15);
      int gsrc  = row * DM + kp0 + ssrc * 8;
      gload_lds16(&wh[gsrc], &wsh[b][ubase * 8]);
      gload_lds16(&wm[gsrc], &wsm[b][ubase * 8]);
    }
  };
  auto xload = [&](int s, float4& a0, float4& a1, float4& b0, float4& b1) {
    const int kp0 = s * 128;
    const float* s0 = &x[(r0 + xrowl) * DM + kp0 + xslot * 8];
    const float* s1 = &x[(r0 + xrowl + 16) * DM + kp0 + xslot * 8];
    a0 = *(const float4*)&s0[0]; a1 = *(const float4*)&s0[4];
    b0 = *(const float4*)&s1[0]; b1 = *(const float4*)&s1[4];
  };
  auto xsplit_write = [&](float4 a0, float4 a1, float4 b0, float4 b1) {
    float xv0[8] = {a0.x,a0.y,a0.z,a0.w,a1.x,a1.y,a1.z,a1.w};
    float xv1[8] = {b0.x,b0.y,b0.z,b0.w,b1.x,b1.y,b1.z,b1.w};
    bf16x8 hv0, mv0, hv1, mv1;
    #pragma unroll
    for (int e = 0; e < 8; ++e) {
      ushort h0 = f2bf(xv0[e]);
      hv0[e] = (short)h0;  mv0[e] = (short)f2bf(xv0[e] - bf2f(h0));
      ushort h1 = f2bf(xv1[e]);
      hv1[e] = (short)h1;  mv1[e] = (short)f2bf(xv1[e] - bf2f(h1));
    }
    int d0 = xrowl * 128 + ((xslot ^ (xrowl & 15)) << 3);
    int r1 = xrowl + 16;
    int d1 = r1 * 128 + ((xslot ^ (r1 & 15)) << 3);
    *(bf16x8*)&xsh[d0] = hv0;  *(bf16x8*)&xsm[d0] = mv0;
    *(bf16x8*)&xsh[d1] = hv1;  *(bf16x8*)&xsm[d1] = mv1;
  };

  f32x4 acc[2] = {{0,0,0,0},{0,0,0,0}};

  {
    float4 a0, a1, b0, b1;
    xload(0, a0, a1, b0, b1);
    xsplit_write(a0, a1, b0, b1);
    stage_w(0, 0);
  }
  __syncthreads();

  int cur = 0;
  for (int stg = 0; stg < 8; ++stg) {
    float4 na0, na1, nb0, nb1;
    if (stg < 7) {
      xload(stg + 1, na0, na1, nb0, nb1);
      stage_w(cur ^ 1, stg + 1);
    }
    #pragma unroll
    for (int ksub = 0; ksub < 4; ++ksub) {
      const int s = ksub * 4 + grp;
      const int xrow = rw + q16;
      bf16x8 xh8 = *(const bf16x8*)&xsh[xrow * 128 + ((s ^ (xrow & 15)) << 3)];
      bf16x8 xm8 = *(const bf16x8*)&xsm[xrow * 128 + ((s ^ (xrow & 15)) << 3)];
      #pragma unroll
      for (int i = 0; i < 2; ++i) {
        const int wrow = (ct0 + i) * 16 + q16;
        const int woff = wrow * 128 + ((s ^ (wrow & 15)) << 3);
        bf16x8 bh = *(const bf16x8*)&wsh[cur][woff];
        bf16x8 bm = *(const bf16x8*)&wsm[cur][woff];
        if (mat == 2) {
          acc[i] = __builtin_amdgcn_mfma_f32_16x16x32_bf16(bh, xh8, acc[i], 0,0,0);
          acc[i] = __builtin_amdgcn_mfma_f32_16x16x32_bf16(bh, xm8, acc[i], 0,0,0);
          acc[i] = __builtin_amdgcn_mfma_f32_16x16x32_bf16(bm, xh8, acc[i], 0,0,0);
          acc[i] = __builtin_amdgcn_mfma_f32_16x16x32_bf16(bm, xm8, acc[i], 0,0,0);
        } else {
          acc[i] = __builtin_amdgcn_mfma_f32_16x16x32_bf16(xh8, bh, acc[i], 0,0,0);
          acc[i] = __builtin_amdgcn_mfma_f32_16x16x32_bf16(xh8, bm, acc[i], 0,0,0);
          acc[i] = __builtin_amdgcn_mfma_f32_16x16x32_bf16(xm8, bh, acc[i], 0,0,0);
          acc[i] = __builtin_amdgcn_mfma_f32_16x16x32_bf16(xm8, bm, acc[i], 0,0,0);
        }
      }
    }
    __syncthreads();
    if (stg < 7) xsplit_write(na0, na1, nb0, nb1);
    __syncthreads();
    cur ^= 1;
  }

  if (mat == 2) {
    #pragma unroll
    for (int i = 0; i < 2; ++i)
      #pragma unroll
      for (int r = 0; r < 4; ++r)
        UTb[((ct0 + i)*16 + 4*grp + r) * NCTX + r0 + rw + q16] = f2bf(acc[i][r]);
  } else {
    ushort* __restrict__ Dh = (mat == 0) ? Qh : Kh;
    ushort* __restrict__ Dm = (mat == 0) ? Qm : Km;
    ushort* __restrict__ Dl = (mat == 0) ? Ql : Kl;
    #pragma unroll
    for (int i = 0; i < 2; ++i)
      #pragma unroll
      for (int r = 0; r < 4; ++r) {
        float v = acc[i][r];
        ushort h = f2bf(v); float fh = bf2f(h);
        ushort m = f2bf(v - fh); float fm = bf2f(m);
        ushort l = f2bf(v - fh - fm);
        int idx = (r0 + rw + 4*grp + r) * DH + (ct0 + i)*16 + q16;
        Dh[idx] = h; Dm[idx] = m; Dl[idx] = l;
      }
  }
}

// ---------------- MFMA flash attention: 2-phase double-buffered (r20-validated) --
__global__ __launch_bounds__(256, 2) void attn_kernel(
    const ushort* __restrict__ Qh, const ushort* __restrict__ Qm, const ushort* __restrict__ Ql,
    const ushort* __restrict__ Kh, const ushort* __restrict__ Km, const ushort* __restrict__ Kl,
    const ushort* __restrict__ UTb,
    float* __restrict__ Pm, float* __restrict__ Pl, float* __restrict__ Py)
{
  __shared__ ushort Ksh[2][3][64*64];
  __shared__ ushort Ush[2][64*64];
  __shared__ __align__(16) ushort ps[4][16*72];

  const int tid  = threadIdx.x;
  const int lane = tid & 63;
  const int w    = tid >> 6;
  ushort* psw = ps[w];
  const int q16  = lane & 15;
  const int grp  = lane >> 4;
  const int colb = grp * 8;

  const int qq    = blockIdx.x;
  const int c     = blockIdx.y;
  const int gbase = 252 - 4 * qq;
  const int g     = gbase + w;
  const int gmax  = gbase + 3;
  const int T     = ((16*gmax + 15) >> 6) + 1;
  const int t0 = (c * T) >> 3, t1 = ((c+1) * T) >> 3;
  const int Town = ((16*g + 15) >> 6) + 1;
  const int q0 = 16 * g;
  const int q  = q0 + q16;

  auto stage = [&](int b, int t) {
    const int j0 = t * 64;
    #pragma unroll
    for (int it = 0; it < 2; ++it) {
      int ubase = it * 256 + w * 64;
      int unit  = ubase + lane;
      int row   = unit >> 3, slotp = unit & 7;
      int c8    = slotp ^ (row & 7);
      int src   = (j0 + row) * DH + c8 * 8;
      gload_lds16(&Kh[src], &Ksh[b][0][ubase * 8]);
      gload_lds16(&Km[src], &Ksh[b][1][ubase * 8]);
      gload_lds16(&Kl[src], &Ksh[b][2][ubase * 8]);
      gload_lds16(&UTb[row * NCTX + j0 + c8 * 8], &Ush[b][ubase * 8]);
    }
  };

  bf16x8 fqh[2], fqm[2], fql[2];
  #pragma unroll
  for (int ks = 0; ks < 2; ++ks) {
    int off = (q0 + q16)*DH + 32*ks + colb;
    fqh[ks] = *(const bf16x8*)&Qh[off];
    fqm[ks] = *(const bf16x8*)&Qm[off];
    fql[ks] = *(const bf16x8*)&Ql[off];
  }

  float mrun = -3.0e38f, lrun = 0.f;
  f32x4 yacc[4] = {{0,0,0,0},{0,0,0,0},{0,0,0,0},{0,0,0,0}};

  if (t0 < t1) stage(0, t0);
  __syncthreads();

  int cur = 0;
  for (int t = t0; t < t1; ++t) {
    if (t + 1 < t1) stage(cur ^ 1, t + 1);
    if (t < Town) {
      const int j0 = t * 64;
      f32x4 sa[4] = {{0,0,0,0},{0,0,0,0},{0,0,0,0},{0,0,0,0}};
      #pragma unroll
      for (int ks = 0; ks < 2; ++ks) {
        #pragma unroll
        for (int st = 0; st < 4; ++st) {
          int row = 16*st + q16;
          int off = row * 64 + (((4*ks + grp) ^ (row & 7)) << 3);
          bf16x8 kh = *(const bf16x8*)&Ksh[cur][0][off];
          bf16x8 km = *(const bf16x8*)&Ksh[cur][1][off];
          bf16x8 kl = *(const bf16x8*)&Ksh[cur][2][off];
          sa[st] = __builtin_amdgcn_mfma_f32_16x16x32_bf16(kh, fqh[ks], sa[st], 0,0,0);
          sa[st] = __builtin_amdgcn_mfma_f32_16x16x32_bf16(kh, fqm[ks], sa[st], 0,0,0);
          sa[st] = __builtin_amdgcn_mfma_f32_16x16x32_bf16(km, fqh[ks], sa[st], 0,0,0);
          sa[st] = __builtin_amdgcn_mfma_f32_16x16x32_bf16(km, fqm[ks], sa[st], 0,0,0);
          sa[st] = __builtin_amdgcn_mfma_f32_16x16x32_bf16(kh, fql[ks], sa[st], 0,0,0);
          sa[st] = __builtin_amdgcn_mfma_f32_16x16x32_bf16(kl, fqh[ks], sa[st], 0,0,0);
        }
      }
      #pragma unroll
      for (int st = 0; st < 4; ++st)
        #pragma unroll
        for (int r = 0; r < 4; ++r) {
          int key = j0 + 16*st + 4*grp + r;
          if (key > q) sa[st][r] = -3.0e38f;
        }
      float mx = sa[0][0];
      #pragma unroll
      for (int st = 0; st < 4; ++st)
        #pragma unroll
        for (int r = 0; r < 4; ++r) mx = fmaxf(mx, sa[st][r]);
      mx = fmaxf(mx, __shfl_xor(mx, 16));
      mx = fmaxf(mx, __shfl_xor(mx, 32));
      float mnew  = fmaxf(mrun, mx);
      float alpha = __expf(mrun - mnew);
      float ts = 0.f;
      ushort pb[16];
      #pragma unroll
      for (int st = 0; st < 4; ++st)
        #pragma unroll
        for (int r = 0; r < 4; ++r) {
          float p = __expf(sa[st][r] - mnew);
          ts += p;
          pb[st*4 + r] = f2bf(p);
        }
      ts += __shfl_xor(ts, 16);
      ts += __shfl_xor(ts, 32);
      lrun = lrun * alpha + ts;
      mrun = mnew;
      float ar[4];
      #pragma unroll
      for (int r = 0; r < 4; ++r) ar[r] = __shfl(alpha, 4*grp + r, 64);
      #pragma unroll
      for (int dt = 0; dt < 4; ++dt) {
        yacc[dt][0] *= ar[0]; yacc[dt][1] *= ar[1];
        yacc[dt][2] *= ar[2]; yacc[dt][3] *= ar[3];
      }
      #pragma unroll
      for (int st = 0; st < 4; ++st) {
        uint2 v;
        v.x = (uint)pb[st*4+0] | ((uint)pb[st*4+1] << 16);
        v.y = (uint)pb[st*4+2] | ((uint)pb[st*4+3] << 16);
        *(uint2*)&psw[q16*72 + 16*st + 4*grp] = v;
      }
      __threadfence_block();
      __builtin_amdgcn_sched_barrier(0);
      #pragma unroll
      for (int ks = 0; ks < 2; ++ks) {
        bf16x8 pa = *(const bf16x8*)&psw[q16*72 + 32*ks + colb];
        #pragma unroll
        for (int dt = 0; dt < 4; ++dt) {
          int row = 16*dt + q16;
          int off = row * 64 + (((4*ks + grp) ^ (row & 7)) << 3);
          bf16x8 ub = *(const bf16x8*)&Ush[cur][off];
          yacc[dt] = __builtin_amdgcn_mfma_f32_16x16x32_bf16(pa, ub, yacc[dt], 0,0,0);
        }
      }
    }
    __syncthreads();
    cur ^= 1;
  }
  if (grp == 0) {
    Pm[c * NCTX + q] = mrun;
    Pl[c * NCTX + q] = lrun;
  }
  #pragma unroll
  for (int dt = 0; dt < 4; ++dt)
    #pragma unroll
    for (int r = 0; r < 4; ++r)
      Py[(c * NCTX + q0 + 4*grp + r) * DH + 16*dt + q16] = yacc[dt][r];
}

// ---------------- PRIMARY: fused combine + out = Y @ W_vT via MFMA -------------
// Reads ONLY d_ws (Pm/Pl/Py/WvT), writes d_out -> race-free.
// Math = r19 launch_once-verified combine scales + Y build + MFMA phase.
__global__ __launch_bounds__(256, 3) void out_fused_kernel(
    const float* __restrict__ Pm, const float* __restrict__ Pl,
    const float* __restrict__ Py,
    const ushort* __restrict__ WvTh, const ushort* __restrict__ WvTm,
    float* __restrict__ out)
{
  __shared__ __align__(16) ushort Yh[64*64], Ym[64*64];     // 8 KiB each
  __shared__ __align__(16) ushort Wsh[128*64], Wsm[128*64]; // 16 KiB each
  __shared__ float sden[NCH][64];
  __shared__ float invd[64];

  const int tid  = threadIdx.x;
  const int lane = tid & 63;
  const int w    = tid >> 6;
  const int q16  = lane & 15;
  const int grp  = lane >> 4;
  const int r0   = blockIdx.x * 64;
  const int cb   = blockIdx.y;          // 0..7 (128 cols each)

  // stage WvT^t[cb*128 .. +127][64] digits (async, pre-swizzled source)
  #pragma unroll
  for (int u = 0; u < 4; ++u) {
    int ubase = u * 256 + w * 64;       // wave-uniform
    int unit  = ubase + lane;
    int row   = unit >> 3, slotp = unit & 7;
    int c8    = slotp ^ (row & 7);
    int src   = (cb * 128 + row) * 64 + c8 * 8;
    gload_lds16(&WvTh[src], &Wsh[ubase * 8]);
    gload_lds16(&WvTm[src], &Wsm[ubase * 8]);
  }
  // combine scales (validated math)
  if (tid < 64) {
    int rrow = r0 + tid;
    float mv[NCH]; float M = -3.0e38f;
    #pragma unroll
    for (int c = 0; c < NCH; ++c) {
      mv[c] = Pm[c*NCTX + rrow];
      M = fmaxf(M, mv[c]);
    }
    float den = 0.f;
    #pragma unroll
    for (int c = 0; c < NCH; ++c) {
      float s = __expf(mv[c] - M);
      sden[c][tid] = s;
      den += s * Pl[c*NCTX + rrow];
    }
    invd[tid] = 1.0f / den;
  }
  __syncthreads();   // drains gload (vmcnt) + sden visible

  // build Y tile [64 rows][64 h] -> 2-digit bf16, XOR-swizzled (r19-verified)
  #pragma unroll
  for (int it = 0; it < 4; ++it) {
    int idx = it * 256 + tid;
    int h4 = idx & 15, rr = idx >> 4;
    int rrow = r0 + rr;
    float nx = 0.f, ny = 0.f, nz = 0.f, nw = 0.f;
    #pragma unroll
    for (int c = 0; c < NCH; ++c) {
      float s = sden[c][rr];
      float4 p4 = *(const float4*)&Py[(c*NCTX + rrow)*DH + h4*4];
      nx += s*p4.x; ny += s*p4.y; nz += s*p4.z; nw += s*p4.w;
    }
    float inv = invd[rr];
    float yv[4] = {nx*inv, ny*inv, nz*inv, nw*inv};
    ushort hv[4], mv4[4];
    #pragma unroll
    for (int e = 0; e < 4; ++e) {
      ushort h = f2bf(yv[e]);
      hv[e] = h;
      mv4[e] = f2bf(yv[e] - bf2f(h));
    }
    int off = rr*64 + (((h4 >> 1) ^ (rr & 7)) << 3) + (h4 & 1) * 4;
    uint2 vh, vm;
    vh.x = (uint)hv[0] | ((uint)hv[1] << 16);
    vh.y = (uint)hv[2] | ((uint)hv[3] << 16);
    vm.x = (uint)mv4[0] | ((uint)mv4[1] << 16);
    vm.y = (uint)mv4[2] | ((uint)mv4[3] << 16);
    *(uint2*)&Yh[off] = vh;
    *(uint2*)&Ym[off] = vm;
  }
  __syncthreads();

  // MFMA: D[row = 16rt+4grp+r][col = w*32 + lt*16 + q16] (r19/r20-validated)
  f32x4 acc[4][2] = {};
  #pragma unroll
  for (int ks = 0; ks < 2; ++ks) {
    bf16x8 ah[4], am[4];
    #pragma unroll
    for (int rt = 0; rt < 4; ++rt) {
      int row = 16*rt + q16;
      int off = row*64 + (((4*ks + grp) ^ (row & 7)) << 3);
      ah[rt] = *(const bf16x8*)&Yh[off];
      am[rt] = *(const bf16x8*)&Ym[off];
    }
    #pragma unroll
    for (int lt = 0; lt < 2; ++lt) {
      int crow = w*32 + lt*16 + q16;    // local col 0..127
      int off  = crow*64 + (((4*ks + grp) ^ (crow & 7)) << 3);
      bf16x8 bh = *(const bf16x8*)&Wsh[off];
      bf16x8 bm = *(const bf16x8*)&Wsm[off];
      #pragma unroll
      for (int rt = 0; rt < 4; ++rt) {
        acc[rt][lt] = __builtin_amdgcn_mfma_f32_16x16x32_bf16(ah[rt], bh, acc[rt][lt], 0,0,0);
        acc[rt][lt] = __builtin_amdgcn_mfma_f32_16x16x32_bf16(ah[rt], bm, acc[rt][lt], 0,0,0);
        acc[rt][lt] = __builtin_amdgcn_mfma_f32_16x16x32_bf16(am[rt], bh, acc[rt][lt], 0,0,0);
        acc[rt][lt] = __builtin_amdgcn_mfma_f32_16x16x32_bf16(am[rt], bm, acc[rt][lt], 0,0,0);
      }
    }
  }
  #pragma unroll
  for (int rt = 0; rt < 4; ++rt)
    #pragma unroll
    for (int lt = 0; lt < 2; ++lt)
      #pragma unroll
      for (int r = 0; r < 4; ++r)
        out[(r0 + 16*rt + 4*grp + r) * DM + cb*128 + w*32 + lt*16 + q16] = acc[rt][lt][r];
}

// ---------------- FALLBACK path (r20-proven): combine -> ws digit arrays -------
__global__ __launch_bounds__(256) void combine_kernel(
    const float* __restrict__ Pm, const float* __restrict__ Pl,
    const float* __restrict__ Py,
    ushort* __restrict__ Yh, ushort* __restrict__ Ym)
{
  int idx = blockIdx.x * 256 + threadIdx.x;
  int r = idx >> 6, d = idx & 63;
  float mv[NCH];
  float M = -3.0e38f;
  #pragma unroll
  for (int c = 0; c < NCH; ++c) {
    mv[c] = Pm[c*NCTX + r];
    M = fmaxf(M, mv[c]);
  }
  float num = 0.f, den = 0.f;
  #pragma unroll
  for (int c = 0; c < NCH; ++c) {
    float s = __expf(mv[c] - M);
    den += s * Pl[c*NCTX + r];
    num += s * Py[(c*NCTX + r)*DH + d];
  }
  float y = num / den;
  ushort h = f2bf(y);
  Yh[idx] = h;
  Ym[idx] = f2bf(y - bf2f(h));
}

// ---------------- FALLBACK: out = Y @ W_vT via MFMA (reads ws only, r20) -------
__global__ __launch_bounds__(256, 3) void out_mfma_kernel(
    const ushort* __restrict__ Yh_g, const ushort* __restrict__ Ym_g,
    const ushort* __restrict__ WvTh, const ushort* __restrict__ WvTm,
    float* __restrict__ out)
{
  __shared__ __align__(16) ushort Yh[64*64], Ym[64*64];
  __shared__ __align__(16) ushort Wsh[128*64], Wsm[128*64];

  const int tid  = threadIdx.x;
  const int lane = tid & 63;
  const int w    = tid >> 6;
  const int q16  = lane & 15;
  const int grp  = lane >> 4;
  const int r0   = blockIdx.x * 64;
  const int cb   = blockIdx.y;

  #pragma unroll
  for (int it = 0; it < 2; ++it) {
    int ubase = it * 256 + w * 64;
    int unit  = ubase + lane;
    int row   = unit >> 3, slotp = unit & 7;
    int c8    = slotp ^ (row & 7);
    int src   = (r0 + row) * 64 + c8 * 8;
    gload_lds16(&Yh_g[src], &Yh[ubase * 8]);
    gload_lds16(&Ym_g[src], &Ym[ubase * 8]);
  }
  #pragma unroll
  for (int u = 0; u < 4; ++u) {
    int ubase = u * 256 + w * 64;
    int unit  = ubase + lane;
    int row   = unit >> 3, slotp = unit & 7;
    int c8    = slotp ^ (row & 7);
    int src   = (cb * 128 + row) * 64 + c8 * 8;
    gload_lds16(&WvTh[src], &Wsh[ubase * 8]);
    gload_lds16(&WvTm[src], &Wsm[ubase * 8]);
  }
  __syncthreads();

  f32x4 acc[4][2] = {};
  #pragma unroll
  for (int ks = 0; ks < 2; ++ks) {
    bf16x8 ah[4], am[4];
    #pragma unroll
    for (int rt = 0; rt < 4; ++rt) {
      int row = 16*rt + q16;
      int off = row*64 + (((4*ks + grp) ^ (row & 7)) << 3);
      ah[rt] = *(const bf16x8*)&Yh[off];
      am[rt] = *(const bf16x8*)&Ym[off];
    }
    #pragma unroll
    for (int lt = 0; lt < 2; ++lt) {
      int crow = w*32 + lt*16 + q16;
      int off  = crow*64 + (((4*ks + grp) ^ (crow & 7)) << 3);
      bf16x8 bh = *(const bf16x8*)&Wsh[off];
      bf16x8 bm = *(const bf16x8*)&Wsm[off];
      #pragma unroll
      for (int rt = 0; rt < 4; ++rt) {
        acc[rt][lt] = __builtin_amdgcn_mfma_f32_16x16x32_bf16(ah[rt], bh, acc[rt][lt], 0,0,0);
        acc[rt][lt] = __builtin_amdgcn_mfma_f32_16x16x32_bf16(ah[rt], bm, acc[rt][lt], 0,0,0);
        acc[rt][lt] = __builtin_amdgcn_mfma_f32_16x16x32_bf16(am[rt], bh, acc[rt][lt], 0,0,0);
        acc[rt][lt] = __builtin_amdgcn_mfma_f32_16x16x32_bf16(am[rt], bm, acc[rt][lt], 0,0,0);
      }
    }
  }
  #pragma unroll
  for (int rt = 0; rt < 4; ++rt)
    #pragma unroll
    for (int lt = 0; lt < 2; ++lt)
      #pragma unroll
      for (int r = 0; r < 4; ++r)
        out[(r0 + 16*rt + 4*grp + r) * DM + cb*128 + w*32 + lt*16 + q16] = acc[rt][lt][r];
}

extern "C" void kernel_launch(void* const* d_in, const int* in_sizes, int n_in,
                              void* d_out, int out_size, void* d_ws, size_t ws_size,
                              hipStream_t stream) {
  const float* x   = (const float*)d_in[0];
  const float* Wq  = (const float*)d_in[1];
  const float* WkT = (const float*)d_in[2];
  const float* Wo  = (const float*)d_in[3];
  const float* Wv  = (const float*)d_in[4];
  float* out = (float*)d_out;
  char*  ob  = (char*)d_out;   // scratch until the final kernel overwrites it
  char*  wb  = (char*)d_ws;    // race-free scratch for the final kernel

  ushort* Qhp = (ushort*)(ob + D_QH);
  ushort* Qmp = (ushort*)(ob + D_QM);
  ushort* Qlp = (ushort*)(ob + D_QL);
  ushort* Khp = (ushort*)(ob + D_KH);
  ushort* Kmp = (ushort*)(ob + D_KM);
  ushort* Klp = (ushort*)(ob + D_KL);
  ushort* UTb = (ushort*)(ob + D_UTB);
  ushort* WTh = (ushort*)(ob + D_WTH);
  ushort* WTm = (ushort*)(ob + D_WTM);

  ushort* WvTh = (ushort*)(wb + S_WVH);
  ushort* WvTm = (ushort*)(wb + S_WVM);

  const bool big_ws = (ws_size >= (size_t)S_END);   // constant per process

  float* Pmp = big_ws ? (float*)(wb + S_PM) : (float*)(ob + D_PM);
  float* Plp = big_ws ? (float*)(wb + S_PL) : (float*)(ob + D_PL);
  float* Pyp = big_ws ? (float*)(wb + S_PY) : (float*)(ob + D_PY);

  hipLaunchKernelGGL(wsplit_kernel, dim3(1024), dim3(256), 0, stream,
                     Wq, WkT, Wo, Wv, WTh, WTm, WvTh, WvTm);
  hipLaunchKernelGGL(proj_mfma_kernel, dim3(128, 3), dim3(256), 0, stream,
                     x, WTh, WTm, Qhp, Qmp, Qlp, Khp, Kmp, Klp, UTb);
  hipLaunchKernelGGL(attn_kernel, dim3(64, 8), dim3(256), 0, stream,
                     Qhp, Qmp, Qlp, Khp, Kmp, Klp, UTb, Pmp, Plp, Pyp);
  if (big_ws) {
    hipLaunchKernelGGL(out_fused_kernel, dim3(64, 8), dim3(256), 0, stream,
                       Pmp, Plp, Pyp, WvTh, WvTm, out);
  } else {
    ushort* Yhp = (ushort*)(wb + S_YH);
    ushort* Ymp = (ushort*)(wb + S_YM);
    hipLaunchKernelGGL(combine_kernel, dim3(1024), dim3(256), 0, stream,
                       Pmp, Plp, Pyp, Yhp, Ymp);
    hipLaunchKernelGGL(out_mfma_kernel, dim3(64, 8), dim3(256), 0, stream,
                       Yhp, Ymp, WvTh, WvTm, out);
  }
}

// Round 22
// 55.126 us; speedup vs baseline: 2.5976x; 1.0608x over previous
//
#include <hip/hip_runtime.h>
#include <hip/hip_bf16.h>
#include <math.h>

#define DM    1024
#define DH    64
#define NCTX  4096
#define NCH   8        // key-chunks per q-group

typedef __attribute__((ext_vector_type(8))) _Float16 f16x8;
typedef __attribute__((ext_vector_type(4))) float f32x4;

// ---- d_out scratch (16 MiB): written by wsplit/proj, consumed by proj/attn;
// the final kernel reads ONLY d_ws and overwrites d_out (race-free).
#define D_QH   0
#define D_QM   524288
#define D_KH   1572864
#define D_KM   2097152
#define D_UTB  3145728
#define D_PY   3670016    // fallback-path partials live here
#define D_PM   12058624
#define D_PL   12189696
#define D_WTH  12320768
#define D_WTM  12713984   // end 13107200

// ---- d_ws layout. WvT digits always at 0. Primary path (ws >= 8.5 MiB):
// partials in ws -> fused combine+out reads only ws.
#define S_WVH  0          // 128 KiB fp16 WvT^t high [1024][64]
#define S_WVM  131072     // 128 KiB
#define S_PM   262144     // 128 KiB f32 [NCH][NCTX]
#define S_PL   393216     // 128 KiB
#define S_PY   524288     // 8 MiB f32 [NCH][NCTX][DH]
#define S_END  8912896
// Fallback path: Y digit arrays in ws
#define S_YH   262144     // 512 KiB
#define S_YM   786432     // 512 KiB (end 1310720 < 4456448 proven)

__device__ __forceinline__ ushort f2h(float x) {
  _Float16 h = (_Float16)x;
  return __builtin_bit_cast(ushort, h);
}
__device__ __forceinline__ float h2f(ushort u) {
  return (float)__builtin_bit_cast(_Float16, u);
}

// async global->LDS, 16B/lane: LDS dest wave-uniform base + lane*16;
// global src per-lane (pre-swizzled source, linear LDS dest -- rule #21).
typedef __attribute__((address_space(1))) const unsigned int gas_u32;
typedef __attribute__((address_space(3))) unsigned int las_u32;
__device__ __forceinline__ void gload_lds16(const void* g, void* l) {
  __builtin_amdgcn_global_load_lds((gas_u32*)g, (las_u32*)l, 16, 0, 0);
}

// ---------------- W -> WT fp16 2-digit split (structure r21-validated) ----------
__global__ __launch_bounds__(256) void wsplit_kernel(
    const float* __restrict__ Wq, const float* __restrict__ WkT,
    const float* __restrict__ Wo, const float* __restrict__ Wv,
    ushort* __restrict__ WTh, ushort* __restrict__ WTm,
    ushort* __restrict__ WvTh, ushort* __restrict__ WvTm)
{
  int gid = blockIdx.x * 256 + threadIdx.x;
  int mat = gid >> 16;
  int idx = gid & 65535;
  if (mat == 3) {
    float v = Wv[idx];                 // Wv[h][c], coalesced read
    int h = idx >> 10, c = idx & 1023;
    int oidx = c * 64 + h;             // WvT^t[c][h]
    ushort h16 = f2h(v);
    WvTh[oidx] = h16;
    WvTm[oidx] = f2h(v - h2f(h16));
    return;
  }
  float v; int oidx;
  if (mat == 1) {
    v = WkT[idx];
    oidx = 65536 + idx;
  } else {
    int k = idx >> 6, h = idx & 63;
    v = (mat == 0 ? Wq : Wo)[idx];
    oidx = mat * 65536 + h * 1024 + k;
  }
  ushort h16 = f2h(v);
  float rem = v - h2f(h16);
  WTh[oidx] = h16;
  WTm[oidx] = f2h(rem);
}

// ---------------- projections via MFMA: fp16 2-digit, 3 products ----------------
// Structure = r21-validated 2-phase pipeline; dtype fp16, xm*wm dropped (2^-22).
__global__ __launch_bounds__(256, 2) void proj_mfma_kernel(
    const float* __restrict__ x,
    const ushort* __restrict__ WTh, const ushort* __restrict__ WTm,
    ushort* __restrict__ Qh, ushort* __restrict__ Qm,
    ushort* __restrict__ Kh, ushort* __restrict__ Km,
    ushort* __restrict__ UTb)
{
  __shared__ __align__(16) ushort xsh[32*128], xsm[32*128];
  __shared__ __align__(16) ushort wsh[2][64*128], wsm[2][64*128];

  const int tid  = threadIdx.x;
  const int lane = tid & 63;
  const int w    = tid >> 6;
  const int q16  = lane & 15;
  const int grp  = lane >> 4;
  const int r0   = blockIdx.x * 32;
  const int mat  = blockIdx.y;
  const ushort* __restrict__ wh = WTh + mat * 65536;
  const ushort* __restrict__ wm = WTm + mat * 65536;

  const int rw  = (w & 1) * 16;
  const int ct0 = (w >> 1) * 2;

  const int xrowl = tid >> 4, xslot = tid & 15;

  auto stage_w = [&](int b, int s) {
    const int kp0 = s * 128;
    #pragma unroll
    for (int u = 0; u < 4; ++u) {
      int ubase = u * 256 + w * 64;
      int unit  = ubase + lane;
      int row   = unit >> 4, slotp = unit & 15;
      int ssrc  = slotp ^ (row & 15);
      int gsrc  = row * DM + kp0 + ssrc * 8;
      gload_lds16(&wh[gsrc], &wsh[b][ubase * 8]);
      gload_lds16(&wm[gsrc], &wsm[b][ubase * 8]);
    }
  };
  auto xload = [&](int s, float4& a0, float4& a1, float4& b0, float4& b1) {
    const int kp0 = s * 128;
    const float* s0 = &x[(r0 + xrowl) * DM + kp0 + xslot * 8];
    const float* s1 = &x[(r0 + xrowl + 16) * DM + kp0 + xslot * 8];
    a0 = *(const float4*)&s0[0]; a1 = *(const float4*)&s0[4];
    b0 = *(const float4*)&s1[0]; b1 = *(const float4*)&s1[4];
  };
  auto xsplit_write = [&](float4 a0, float4 a1, float4 b0, float4 b1) {
    float xv0[8] = {a0.x,a0.y,a0.z,a0.w,a1.x,a1.y,a1.z,a1.w};
    float xv1[8] = {b0.x,b0.y,b0.z,b0.w,b1.x,b1.y,b1.z,b1.w};
    ushort hv0[8], mv0[8], hv1[8], mv1[8];
    #pragma unroll
    for (int e = 0; e < 8; ++e) {
      ushort h0 = f2h(xv0[e]);
      hv0[e] = h0;  mv0[e] = f2h(xv0[e] - h2f(h0));
      ushort h1 = f2h(xv1[e]);
      hv1[e] = h1;  mv1[e] = f2h(xv1[e] - h2f(h1));
    }
    int d0 = xrowl * 128 + ((xslot ^ (xrowl & 15)) << 3);
    int r1 = xrowl + 16;
    int d1 = r1 * 128 + ((xslot ^ (r1 & 15)) << 3);
    #pragma unroll
    for (int e = 0; e < 8; ++e) {
      xsh[d0+e] = hv0[e]; xsm[d0+e] = mv0[e];
      xsh[d1+e] = hv1[e]; xsm[d1+e] = mv1[e];
    }
  };

  f32x4 acc[2] = {{0,0,0,0},{0,0,0,0}};

  {
    float4 a0, a1, b0, b1;
    xload(0, a0, a1, b0, b1);
    xsplit_write(a0, a1, b0, b1);
    stage_w(0, 0);
  }
  __syncthreads();

  int cur = 0;
  for (int stg = 0; stg < 8; ++stg) {
    float4 na0, na1, nb0, nb1;
    if (stg < 7) {
      xload(stg + 1, na0, na1, nb0, nb1);
      stage_w(cur ^ 1, stg + 1);
    }
    #pragma unroll
    for (int ksub = 0; ksub < 4; ++ksub) {
      const int s = ksub * 4 + grp;
      const int xrow = rw + q16;
      f16x8 xh8 = *(const f16x8*)&xsh[xrow * 128 + ((s ^ (xrow & 15)) << 3)];
      f16x8 xm8 = *(const f16x8*)&xsm[xrow * 128 + ((s ^ (xrow & 15)) << 3)];
      #pragma unroll
      for (int i = 0; i < 2; ++i) {
        const int wrow = (ct0 + i) * 16 + q16;
        const int woff = wrow * 128 + ((s ^ (wrow & 15)) << 3);
        f16x8 bh = *(const f16x8*)&wsh[cur][woff];
        f16x8 bm = *(const f16x8*)&wsm[cur][woff];
        if (mat == 2) {   // A = W, B = x (validated operand pattern)
          acc[i] = __builtin_amdgcn_mfma_f32_16x16x32_f16(bh, xh8, acc[i], 0,0,0);
          acc[i] = __builtin_amdgcn_mfma_f32_16x16x32_f16(bh, xm8, acc[i], 0,0,0);
          acc[i] = __builtin_amdgcn_mfma_f32_16x16x32_f16(bm, xh8, acc[i], 0,0,0);
        } else {          // A = x, B = W
          acc[i] = __builtin_amdgcn_mfma_f32_16x16x32_f16(xh8, bh, acc[i], 0,0,0);
          acc[i] = __builtin_amdgcn_mfma_f32_16x16x32_f16(xh8, bm, acc[i], 0,0,0);
          acc[i] = __builtin_amdgcn_mfma_f32_16x16x32_f16(xm8, bh, acc[i], 0,0,0);
        }
      }
    }
    __syncthreads();
    if (stg < 7) xsplit_write(na0, na1, nb0, nb1);
    __syncthreads();
    cur ^= 1;
  }

  if (mat == 2) {
    #pragma unroll
    for (int i = 0; i < 2; ++i)
      #pragma unroll
      for (int r = 0; r < 4; ++r)
        UTb[((ct0 + i)*16 + 4*grp + r) * NCTX + r0 + rw + q16] = f2h(acc[i][r]);
  } else {
    ushort* __restrict__ Dh = (mat == 0) ? Qh : Kh;
    ushort* __restrict__ Dm = (mat == 0) ? Qm : Km;
    #pragma unroll
    for (int i = 0; i < 2; ++i)
      #pragma unroll
      for (int r = 0; r < 4; ++r) {
        float v = acc[i][r];
        ushort h = f2h(v);
        ushort m = f2h(v - h2f(h));
        int idx = (r0 + rw + 4*grp + r) * DH + (ct0 + i)*16 + q16;
        Dh[idx] = h; Dm[idx] = m;
      }
  }
}

// ---------------- MFMA flash attention: fp16 2-digit scores (3 products) --------
// Structure = r21-validated 2-phase double-buffered scaffold; K staged 2 digits.
__global__ __launch_bounds__(256, 2) void attn_kernel(
    const ushort* __restrict__ Qh, const ushort* __restrict__ Qm,
    const ushort* __restrict__ Kh, const ushort* __restrict__ Km,
    const ushort* __restrict__ UTb,
    float* __restrict__ Pm, float* __restrict__ Pl, float* __restrict__ Py)
{
  __shared__ ushort Ksh[2][2][64*64];              // 32 KiB
  __shared__ ushort Ush[2][64*64];                 // 16 KiB
  __shared__ __align__(16) ushort ps[4][16*72];    //  9 KiB

  const int tid  = threadIdx.x;
  const int lane = tid & 63;
  const int w    = tid >> 6;
  ushort* psw = ps[w];
  const int q16  = lane & 15;
  const int grp  = lane >> 4;
  const int colb = grp * 8;

  const int qq    = blockIdx.x;
  const int c     = blockIdx.y;
  const int gbase = 252 - 4 * qq;
  const int g     = gbase + w;
  const int gmax  = gbase + 3;
  const int T     = ((16*gmax + 15) >> 6) + 1;
  const int t0 = (c * T) >> 3, t1 = ((c+1) * T) >> 3;
  const int Town = ((16*g + 15) >> 6) + 1;
  const int q0 = 16 * g;
  const int q  = q0 + q16;

  auto stage = [&](int b, int t) {
    const int j0 = t * 64;
    #pragma unroll
    for (int it = 0; it < 2; ++it) {
      int ubase = it * 256 + w * 64;
      int unit  = ubase + lane;
      int row   = unit >> 3, slotp = unit & 7;
      int c8    = slotp ^ (row & 7);
      int src   = (j0 + row) * DH + c8 * 8;
      gload_lds16(&Kh[src], &Ksh[b][0][ubase * 8]);
      gload_lds16(&Km[src], &Ksh[b][1][ubase * 8]);
      gload_lds16(&UTb[row * NCTX + j0 + c8 * 8], &Ush[b][ubase * 8]);
    }
  };

  f16x8 fqh[2], fqm[2];
  #pragma unroll
  for (int ks = 0; ks < 2; ++ks) {
    int off = (q0 + q16)*DH + 32*ks + colb;
    fqh[ks] = *(const f16x8*)&Qh[off];
    fqm[ks] = *(const f16x8*)&Qm[off];
  }

  float mrun = -3.0e38f, lrun = 0.f;
  f32x4 yacc[4] = {{0,0,0,0},{0,0,0,0},{0,0,0,0},{0,0,0,0}};

  if (t0 < t1) stage(0, t0);
  __syncthreads();

  int cur = 0;
  for (int t = t0; t < t1; ++t) {
    if (t + 1 < t1) stage(cur ^ 1, t + 1);
    if (t < Town) {
      const int j0 = t * 64;
      f32x4 sa[4] = {{0,0,0,0},{0,0,0,0},{0,0,0,0},{0,0,0,0}};
      #pragma unroll
      for (int ks = 0; ks < 2; ++ks) {
        #pragma unroll
        for (int st = 0; st < 4; ++st) {
          int row = 16*st + q16;
          int off = row * 64 + (((4*ks + grp) ^ (row & 7)) << 3);
          f16x8 kh = *(const f16x8*)&Ksh[cur][0][off];
          f16x8 km = *(const f16x8*)&Ksh[cur][1][off];
          sa[st] = __builtin_amdgcn_mfma_f32_16x16x32_f16(kh, fqh[ks], sa[st], 0,0,0);
          sa[st] = __builtin_amdgcn_mfma_f32_16x16x32_f16(kh, fqm[ks], sa[st], 0,0,0);
          sa[st] = __builtin_amdgcn_mfma_f32_16x16x32_f16(km, fqh[ks], sa[st], 0,0,0);
        }
      }
      #pragma unroll
      for (int st = 0; st < 4; ++st)
        #pragma unroll
        for (int r = 0; r < 4; ++r) {
          int key = j0 + 16*st + 4*grp + r;
          if (key > q) sa[st][r] = -3.0e38f;
        }
      float mx = sa[0][0];
      #pragma unroll
      for (int st = 0; st < 4; ++st)
        #pragma unroll
        for (int r = 0; r < 4; ++r) mx = fmaxf(mx, sa[st][r]);
      mx = fmaxf(mx, __shfl_xor(mx, 16));
      mx = fmaxf(mx, __shfl_xor(mx, 32));
      float mnew  = fmaxf(mrun, mx);
      float alpha = __expf(mrun - mnew);
      float ts = 0.f;
      ushort pb[16];
      #pragma unroll
      for (int st = 0; st < 4; ++st)
        #pragma unroll
        for (int r = 0; r < 4; ++r) {
          float p = __expf(sa[st][r] - mnew);
          ts += p;
          pb[st*4 + r] = f2h(p);
        }
      ts += __shfl_xor(ts, 16);
      ts += __shfl_xor(ts, 32);
      lrun = lrun * alpha + ts;
      mrun = mnew;
      float ar[4];
      #pragma unroll
      for (int r = 0; r < 4; ++r) ar[r] = __shfl(alpha, 4*grp + r, 64);
      #pragma unroll
      for (int dt = 0; dt < 4; ++dt) {
        yacc[dt][0] *= ar[0]; yacc[dt][1] *= ar[1];
        yacc[dt][2] *= ar[2]; yacc[dt][3] *= ar[3];
      }
      #pragma unroll
      for (int st = 0; st < 4; ++st) {
        uint2 v;
        v.x = (uint)pb[st*4+0] | ((uint)pb[st*4+1] << 16);
        v.y = (uint)pb[st*4+2] | ((uint)pb[st*4+3] << 16);
        *(uint2*)&psw[q16*72 + 16*st + 4*grp] = v;
      }
      __threadfence_block();
      __builtin_amdgcn_sched_barrier(0);
      #pragma unroll
      for (int ks = 0; ks < 2; ++ks) {
        f16x8 pa = *(const f16x8*)&psw[q16*72 + 32*ks + colb];
        #pragma unroll
        for (int dt = 0; dt < 4; ++dt) {
          int row = 16*dt + q16;
          int off = row * 64 + (((4*ks + grp) ^ (row & 7)) << 3);
          f16x8 ub = *(const f16x8*)&Ush[cur][off];
          yacc[dt] = __builtin_amdgcn_mfma_f32_16x16x32_f16(pa, ub, yacc[dt], 0,0,0);
        }
      }
    }
    __syncthreads();
    cur ^= 1;
  }
  if (grp == 0) {
    Pm[c * NCTX + q] = mrun;
    Pl[c * NCTX + q] = lrun;
  }
  #pragma unroll
  for (int dt = 0; dt < 4; ++dt)
    #pragma unroll
    for (int r = 0; r < 4; ++r)
      Py[(c * NCTX + q0 + 4*grp + r) * DH + 16*dt + q16] = yacc[dt][r];
}

// ---------------- PRIMARY: fused combine + out = Y @ W_vT via fp16 MFMA ---------
__global__ __launch_bounds__(256, 3) void out_fused_kernel(
    const float* __restrict__ Pm, const float* __restrict__ Pl,
    const float* __restrict__ Py,
    const ushort* __restrict__ WvTh, const ushort* __restrict__ WvTm,
    float* __restrict__ out)
{
  __shared__ __align__(16) ushort Yh[64*64], Ym[64*64];
  __shared__ __align__(16) ushort Wsh[128*64], Wsm[128*64];
  __shared__ float sden[NCH][64];
  __shared__ float invd[64];

  const int tid  = threadIdx.x;
  const int lane = tid & 63;
  const int w    = tid >> 6;
  const int q16  = lane & 15;
  const int grp  = lane >> 4;
  const int r0   = blockIdx.x * 64;
  const int cb   = blockIdx.y;

  #pragma unroll
  for (int u = 0; u < 4; ++u) {
    int ubase = u * 256 + w * 64;
    int unit  = ubase + lane;
    int row   = unit >> 3, slotp = unit & 7;
    int c8    = slotp ^ (row & 7);
    int src   = (cb * 128 + row) * 64 + c8 * 8;
    gload_lds16(&WvTh[src], &Wsh[ubase * 8]);
    gload_lds16(&WvTm[src], &Wsm[ubase * 8]);
  }
  if (tid < 64) {
    int rrow = r0 + tid;
    float mv[NCH]; float M = -3.0e38f;
    #pragma unroll
    for (int c = 0; c < NCH; ++c) {
      mv[c] = Pm[c*NCTX + rrow];
      M = fmaxf(M, mv[c]);
    }
    float den = 0.f;
    #pragma unroll
    for (int c = 0; c < NCH; ++c) {
      float s = __expf(mv[c] - M);
      sden[c][tid] = s;
      den += s * Pl[c*NCTX + rrow];
    }
    invd[tid] = 1.0f / den;
  }
  __syncthreads();

  #pragma unroll
  for (int it = 0; it < 4; ++it) {
    int idx = it * 256 + tid;
    int h4 = idx & 15, rr = idx >> 4;
    int rrow = r0 + rr;
    float nx = 0.f, ny = 0.f, nz = 0.f, nw = 0.f;
    #pragma unroll
    for (int c = 0; c < NCH; ++c) {
      float s = sden[c][rr];
      float4 p4 = *(const float4*)&Py[(c*NCTX + rrow)*DH + h4*4];
      nx += s*p4.x; ny += s*p4.y; nz += s*p4.z; nw += s*p4.w;
    }
    float inv = invd[rr];
    float yv[4] = {nx*inv, ny*inv, nz*inv, nw*inv};
    ushort hv[4], mv4[4];
    #pragma unroll
    for (int e = 0; e < 4; ++e) {
      ushort h = f2h(yv[e]);
      hv[e] = h;
      mv4[e] = f2h(yv[e] - h2f(h));
    }
    int off = rr*64 + (((h4 >> 1) ^ (rr & 7)) << 3) + (h4 & 1) * 4;
    uint2 vh, vm;
    vh.x = (uint)hv[0] | ((uint)hv[1] << 16);
    vh.y = (uint)hv[2] | ((uint)hv[3] << 16);
    vm.x = (uint)mv4[0] | ((uint)mv4[1] << 16);
    vm.y = (uint)mv4[2] | ((uint)mv4[3] << 16);
    *(uint2*)&Yh[off] = vh;
    *(uint2*)&Ym[off] = vm;
  }
  __syncthreads();

  f32x4 acc[4][2] = {};
  #pragma unroll
  for (int ks = 0; ks < 2; ++ks) {
    f16x8 ah[4], am[4];
    #pragma unroll
    for (int rt = 0; rt < 4; ++rt) {
      int row = 16*rt + q16;
      int off = row*64 + (((4*ks + grp) ^ (row & 7)) << 3);
      ah[rt] = *(const f16x8*)&Yh[off];
      am[rt] = *(const f16x8*)&Ym[off];
    }
    #pragma unroll
    for (int lt = 0; lt < 2; ++lt) {
      int crow = w*32 + lt*16 + q16;
      int off  = crow*64 + (((4*ks + grp) ^ (crow & 7)) << 3);
      f16x8 bh = *(const f16x8*)&Wsh[off];
      f16x8 bm = *(const f16x8*)&Wsm[off];
      #pragma unroll
      for (int rt = 0; rt < 4; ++rt) {
        acc[rt][lt] = __builtin_amdgcn_mfma_f32_16x16x32_f16(ah[rt], bh, acc[rt][lt], 0,0,0);
        acc[rt][lt] = __builtin_amdgcn_mfma_f32_16x16x32_f16(ah[rt], bm, acc[rt][lt], 0,0,0);
        acc[rt][lt] = __builtin_amdgcn_mfma_f32_16x16x32_f16(am[rt], bh, acc[rt][lt], 0,0,0);
      }
    }
  }
  #pragma unroll
  for (int rt = 0; rt < 4; ++rt)
    #pragma unroll
    for (int lt = 0; lt < 2; ++lt)
      #pragma unroll
      for (int r = 0; r < 4; ++r)
        out[(r0 + 16*rt + 4*grp + r) * DM + cb*128 + w*32 + lt*16 + q16] = acc[rt][lt][r];
}

// ---------------- FALLBACK path: combine -> ws digit arrays --------------------
__global__ __launch_bounds__(256) void combine_kernel(
    const float* __restrict__ Pm, const float* __restrict__ Pl,
    const float* __restrict__ Py,
    ushort* __restrict__ Yh, ushort* __restrict__ Ym)
{
  int idx = blockIdx.x * 256 + threadIdx.x;
  int r = idx >> 6, d = idx & 63;
  float mv[NCH];
  float M = -3.0e38f;
  #pragma unroll
  for (int c = 0; c < NCH; ++c) {
    mv[c] = Pm[c*NCTX + r];
    M = fmaxf(M, mv[c]);
  }
  float num = 0.f, den = 0.f;
  #pragma unroll
  for (int c = 0; c < NCH; ++c) {
    float s = __expf(mv[c] - M);
    den += s * Pl[c*NCTX + r];
    num += s * Py[(c*NCTX + r)*DH + d];
  }
  float y = num / den;
  ushort h = f2h(y);
  Yh[idx] = h;
  Ym[idx] = f2h(y - h2f(h));
}

// ---------------- FALLBACK: out = Y @ W_vT via fp16 MFMA (reads ws only) -------
__global__ __launch_bounds__(256, 3) void out_mfma_kernel(
    const ushort* __restrict__ Yh_g, const ushort* __restrict__ Ym_g,
    const ushort* __restrict__ WvTh, const ushort* __restrict__ WvTm,
    float* __restrict__ out)
{
  __shared__ __align__(16) ushort Yh[64*64], Ym[64*64];
  __shared__ __align__(16) ushort Wsh[128*64], Wsm[128*64];

  const int tid  = threadIdx.x;
  const int lane = tid & 63;
  const int w    = tid >> 6;
  const int q16  = lane & 15;
  const int grp  = lane >> 4;
  const int r0   = blockIdx.x * 64;
  const int cb   = blockIdx.y;

  #pragma unroll
  for (int it = 0; it < 2; ++it) {
    int ubase = it * 256 + w * 64;
    int unit  = ubase + lane;
    int row   = unit >> 3, slotp = unit & 7;
    int c8    = slotp ^ (row & 7);
    int src   = (r0 + row) * 64 + c8 * 8;
    gload_lds16(&Yh_g[src], &Yh[ubase * 8]);
    gload_lds16(&Ym_g[src], &Ym[ubase * 8]);
  }
  #pragma unroll
  for (int u = 0; u < 4; ++u) {
    int ubase = u * 256 + w * 64;
    int unit  = ubase + lane;
    int row   = unit >> 3, slotp = unit & 7;
    int c8    = slotp ^ (row & 7);
    int src   = (cb * 128 + row) * 64 + c8 * 8;
    gload_lds16(&WvTh[src], &Wsh[ubase * 8]);
    gload_lds16(&WvTm[src], &Wsm[ubase * 8]);
  }
  __syncthreads();

  f32x4 acc[4][2] = {};
  #pragma unroll
  for (int ks = 0; ks < 2; ++ks) {
    f16x8 ah[4], am[4];
    #pragma unroll
    for (int rt = 0; rt < 4; ++rt) {
      int row = 16*rt + q16;
      int off = row*64 + (((4*ks + grp) ^ (row & 7)) << 3);
      ah[rt] = *(const f16x8*)&Yh[off];
      am[rt] = *(const f16x8*)&Ym[off];
    }
    #pragma unroll
    for (int lt = 0; lt < 2; ++lt) {
      int crow = w*32 + lt*16 + q16;
      int off  = crow*64 + (((4*ks + grp) ^ (crow & 7)) << 3);
      f16x8 bh = *(const f16x8*)&Wsh[off];
      f16x8 bm = *(const f16x8*)&Wsm[off];
      #pragma unroll
      for (int rt = 0; rt < 4; ++rt) {
        acc[rt][lt] = __builtin_amdgcn_mfma_f32_16x16x32_f16(ah[rt], bh, acc[rt][lt], 0,0,0);
        acc[rt][lt] = __builtin_amdgcn_mfma_f32_16x16x32_f16(ah[rt], bm, acc[rt][lt], 0,0,0);
        acc[rt][lt] = __builtin_amdgcn_mfma_f32_16x16x32_f16(am[rt], bh, acc[rt][lt], 0,0,0);
      }
    }
  }
  #pragma unroll
  for (int rt = 0; rt < 4; ++rt)
    #pragma unroll
    for (int lt = 0; lt < 2; ++lt)
      #pragma unroll
      for (int r = 0; r < 4; ++r)
        out[(r0 + 16*rt + 4*grp + r) * DM + cb*128 + w*32 + lt*16 + q16] = acc[rt][lt][r];
}

extern "C" void kernel_launch(void* const* d_in, const int* in_sizes, int n_in,
                              void* d_out, int out_size, void* d_ws, size_t ws_size,
                              hipStream_t stream) {
  const float* x   = (const float*)d_in[0];
  const float* Wq  = (const float*)d_in[1];
  const float* WkT = (const float*)d_in[2];
  const float* Wo  = (const float*)d_in[3];
  const float* Wv  = (const float*)d_in[4];
  float* out = (float*)d_out;
  char*  ob  = (char*)d_out;   // scratch until the final kernel overwrites it
  char*  wb  = (char*)d_ws;    // race-free scratch for the final kernel

  ushort* Qhp = (ushort*)(ob + D_QH);
  ushort* Qmp = (ushort*)(ob + D_QM);
  ushort* Khp = (ushort*)(ob + D_KH);
  ushort* Kmp = (ushort*)(ob + D_KM);
  ushort* UTb = (ushort*)(ob + D_UTB);
  ushort* WTh = (ushort*)(ob + D_WTH);
  ushort* WTm = (ushort*)(ob + D_WTM);

  ushort* WvTh = (ushort*)(wb + S_WVH);
  ushort* WvTm = (ushort*)(wb + S_WVM);

  const bool big_ws = (ws_size >= (size_t)S_END);   // constant per process

  float* Pmp = big_ws ? (float*)(wb + S_PM) : (float*)(ob + D_PM);
  float* Plp = big_ws ? (float*)(wb + S_PL) : (float*)(ob + D_PL);
  float* Pyp = big_ws ? (float*)(wb + S_PY) : (float*)(ob + D_PY);

  hipLaunchKernelGGL(wsplit_kernel, dim3(1024), dim3(256), 0, stream,
                     Wq, WkT, Wo, Wv, WTh, WTm, WvTh, WvTm);
  hipLaunchKernelGGL(proj_mfma_kernel, dim3(128, 3), dim3(256), 0, stream,
                     x, WTh, WTm, Qhp, Qmp, Khp, Kmp, UTb);
  hipLaunchKernelGGL(attn_kernel, dim3(64, 8), dim3(256), 0, stream,
                     Qhp, Qmp, Khp, Kmp, UTb, Pmp, Plp, Pyp);
  if (big_ws) {
    hipLaunchKernelGGL(out_fused_kernel, dim3(64, 8), dim3(256), 0, stream,
                       Pmp, Plp, Pyp, WvTh, WvTm, out);
  } else {
    ushort* Yhp = (ushort*)(wb + S_YH);
    ushort* Ymp = (ushort*)(wb + S_YM);
    hipLaunchKernelGGL(combine_kernel, dim3(1024), dim3(256), 0, stream,
                       Pmp, Plp, Pyp, Yhp, Ymp);
    hipLaunchKernelGGL(out_mfma_kernel, dim3(64, 8), dim3(256), 0, stream,
                       Yhp, Ymp, WvTh, WvTm, out);
  }
}